// Round 19
// baseline (7065.947 us; speedup 1.0000x reference)
//
#include <hip/hip_runtime.h>
#include <hip/hip_bf16.h>

typedef unsigned short u16;
typedef __bf16 bf16x8 __attribute__((ext_vector_type(8)));
typedef float   f32x4 __attribute__((ext_vector_type(4)));
typedef unsigned short u16x8 __attribute__((ext_vector_type(8)));

#define NTOK  16384
#define HID_  1280
#define NHEAD 16
#define HD    80
#define INTER_ 3456
#define NGRP  4096
#define ODIM  2048
#define BIGD  5120

static __device__ __forceinline__ u16 f2bf(float f) {
  __hip_bfloat16 h = __float2bfloat16(f);
  return __builtin_bit_cast(u16, h);
}
static __device__ __forceinline__ float bf2f(u16 u) {
  return __bfloat162float(__builtin_bit_cast(__hip_bfloat16, u));
}
static __device__ __forceinline__ float gelu_tanh(float x) {
  float y = 0.7978845608028654f * (x + 0.044715f * x * x * x);
  float t = 1.0f - 2.0f / (1.0f + __expf(2.0f * y));   // tanh(y)
  return 0.5f * x * (1.0f + t);
}

// async global->LDS, 16B per lane, dest = wave-uniform base + lane*16
static __device__ __forceinline__ void gload_lds16(const u16* g, u16* l) {
  __builtin_amdgcn_global_load_lds(
      (const __attribute__((address_space(1))) unsigned int*)g,
      (__attribute__((address_space(3))) unsigned int*)l, 16, 0, 0);
}

// ---------------------------------------------------------------- gathers
__global__ __launch_bounds__(256) void gather_pv_k(
    const float* __restrict__ pv, const int* __restrict__ wi, u16* __restrict__ out) {
  int t = blockIdx.x * 256 + threadIdx.x;          // NTOK*384 float4 groups
  if (t >= NTOK * 384) return;
  int i = t / 384, c4 = t - i * 384;
  int s = wi[i >> 2] * 4 + (i & 3);
  float4 v = *(const float4*)(pv + (size_t)s * 1536 + c4 * 4);
  uint2 r;
  r.x = (unsigned)f2bf(v.x) | ((unsigned)f2bf(v.y) << 16);
  r.y = (unsigned)f2bf(v.z) | ((unsigned)f2bf(v.w) << 16);
  *(uint2*)(out + (size_t)i * 1536 + c4 * 4) = r;
}

__global__ __launch_bounds__(256) void gather_cs_k(
    const float* __restrict__ ci, const float* __restrict__ si,
    const int* __restrict__ wi, float* __restrict__ co, float* __restrict__ so) {
  int t = blockIdx.x * 256 + threadIdx.x;          // NTOK*20 float4 groups
  if (t >= NTOK * 20) return;
  int i = t / 20, c4 = t - i * 20;
  int s = wi[i >> 2] * 4 + (i & 3);
  *(float4*)(co + (size_t)i * 80 + c4 * 4) = *(const float4*)(ci + (size_t)s * 80 + c4 * 4);
  *(float4*)(so + (size_t)i * 80 + c4 * 4) = *(const float4*)(si + (size_t)s * 80 + c4 * 4);
}

// ---------------------------------------------------------------- weight f32[K][N] -> bf16[N][K]
__global__ __launch_bounds__(256) void twt_k(
    const float* __restrict__ W, u16* __restrict__ Wt, int K, int N) {
  __shared__ u16 t[32][33];
  int bn = blockIdx.x * 32, bk = blockIdx.y * 32;
  int tx = threadIdx.x & 31, ty = threadIdx.x >> 5;   // ty 0..7
  #pragma unroll
  for (int r = 0; r < 4; r++) {
    int k = bk + ty + r * 8;
    t[tx][ty + r * 8] = f2bf(W[(size_t)k * N + bn + tx]);
  }
  __syncthreads();
  #pragma unroll
  for (int r = 0; r < 4; r++) {
    int n = bn + ty + r * 8;
    Wt[(size_t)n * K + bk + tx] = t[ty + r * 8][tx];
  }
}

// weight f32[K][N] -> bf16 interleaved rows: Wt[(2n+ph)][K]
__global__ __launch_bounds__(256) void twt2_k(
    const float* __restrict__ W, u16* __restrict__ Wt, int K, int N, int ph) {
  __shared__ u16 t[32][33];
  int bn = blockIdx.x * 32, bk = blockIdx.y * 32;
  int tx = threadIdx.x & 31, ty = threadIdx.x >> 5;
  #pragma unroll
  for (int r = 0; r < 4; r++) {
    int k = bk + ty + r * 8;
    t[tx][ty + r * 8] = f2bf(W[(size_t)k * N + bn + tx]);
  }
  __syncthreads();
  #pragma unroll
  for (int r = 0; r < 4; r++) {
    int n = bn + ty + r * 8;
    Wt[(size_t)(2 * n + ph) * K + bk + tx] = t[ty + r * 8][tx];
  }
}

// interleave biases: o[2i]=g[i], o[2i+1]=u[i]
__global__ __launch_bounds__(256) void bi_k(
    const float* __restrict__ g, const float* __restrict__ u, float* __restrict__ o, int n) {
  int i = blockIdx.x * 256 + threadIdx.x;
  if (i < n) { o[2 * i] = g[i]; o[2 * i + 1] = u[i]; }
}

// ---------------------------------------------------------------- rmsnorm (bf16 in -> bf16 out), 8-wide vectorized
__global__ __launch_bounds__(256) void rmsnorm_k(
    const u16* __restrict__ x, const float* __restrict__ w, u16* __restrict__ out, int D) {
  int row = blockIdx.x;
  const uint4* xr = (const uint4*)(x + (size_t)row * D);   // 8 bf16 per uint4
  int D8 = D >> 3;
  float ss = 0.f;
  for (int c = threadIdx.x; c < D8; c += 256) {
    uint4 v = xr[c];
    const unsigned vv[4] = {v.x, v.y, v.z, v.w};
    #pragma unroll
    for (int e = 0; e < 4; e++) {
      float a = bf2f((u16)(vv[e] & 0xffff));
      float b = bf2f((u16)(vv[e] >> 16));
      ss += a * a + b * b;
    }
  }
  #pragma unroll
  for (int d = 1; d < 64; d <<= 1) ss += __shfl_xor(ss, d, 64);
  __shared__ float part[4];
  if ((threadIdx.x & 63) == 0) part[threadIdx.x >> 6] = ss;
  __syncthreads();
  float tot = part[0] + part[1] + part[2] + part[3];
  float scale = rsqrtf(tot / (float)D + 1e-6f);
  u16* orow = out + (size_t)row * D;
  const float4* wr = (const float4*)w;
  for (int c = threadIdx.x; c < D8; c += 256) {
    uint4 v = xr[c];
    float4 w0 = wr[c * 2], w1 = wr[c * 2 + 1];
    const unsigned vv[4] = {v.x, v.y, v.z, v.w};
    const float wf[8] = {w0.x, w0.y, w0.z, w0.w, w1.x, w1.y, w1.z, w1.w};
    uint4 r;
    unsigned rr[4];
    #pragma unroll
    for (int e = 0; e < 4; e++) {
      float a = bf2f((u16)(vv[e] & 0xffff)) * scale * wf[e * 2];
      float b = bf2f((u16)(vv[e] >> 16)) * scale * wf[e * 2 + 1];
      rr[e] = (unsigned)f2bf(a) | ((unsigned)f2bf(b) << 16);
    }
    r.x = rr[0]; r.y = rr[1]; r.z = rr[2]; r.w = rr[3];
    *(uint4*)(orow + c * 8) = r;
  }
}

// ---------------------------------------------------------------- 8-phase GEMM, tile TM x 256 (TM=256 or 128)
// C = A(bf16 [M][K]) @ Bt(bf16 [N][K])^T + bias. 512 threads, 8 waves (2M x 4N).
// FRAGMENT-READ DEDUP + READ/MFMA OVERLAP: each LDS fragment read once per
// K-tile; reads are issued immediately AFTER the previous quadrant's MFMA
// cluster (post-MFMA placement), so they execute under the MFMA window and are
// waited by the NEXT phase's lgkmcnt(0). Availability boundaries identical to
// r15 (each read group follows the same SYNC1 that guaranteed it before).
// TM=256: 2 LDS buffers, 4 phases/K-tile; vmcnt {6,6,6,6}; tail MFMA.
//   p0: MFMA(A1,B1 of t-1), then read A0,B0(t) | p1: MFMA(A0,B0), read A1(t)
//   p2: MFMA(A1,B0), read B1(t)               | p3: MFMA(A0,B1), no reads
// TM=128: 3 LDS buffers, lean 2 phases/K-tile (1 vmcnt + 2 barriers):
//   pA: stage alpha(t+2); lgkm0(waits 12 reads from pB(t-1)); MFMA x2; read B1(t)
//   pB: stage beta(t+2); vmcnt(6); bar; lgkm0(waits B1); MFMA x2;
//       read A0,A1,B0 of t+1 (avail: vmcnt(6) leaves alpha/beta(t+2) ->
//       alpha(t+1),beta(t+1) complete); bar.
//   Prologue stages tiles 0,1; vmcnt(6)+bar; reads tile 0's A0,A1,B0.
// LDS: A/B XOR-swizzled 16B chunks: LDS[r][c] = G[r][c ^ (r&7)], linear
//   gload_lds dest + pre-swizzled source. XCD-chunked bijective tile remap, bn-fast.
// MODE 0: bf16 store; 1: f32; 3: gelu->bf16; 4: f32 scatter rows;
// MODE 6: fused gate/up (interleaved B rows; silu(gate)*up -> bf16 out[R][N/2]);
// MODE 7: bf16 residual RMW: h[R][Cc] = bf16(bf2f(h) + v)
template <int MODE, int TM>
__global__ __launch_bounds__(512, 2) void gemm8_k(
    const u16* __restrict__ A, const u16* __restrict__ Bt, const float* __restrict__ bias,
    void* __restrict__ outp, const int* __restrict__ rowmap, const u16* __restrict__ gatebuf,
    int nbn, int N, int K) {
  constexpr int MF = TM / 64;                 // A frags per half (4 or 2)
  constexpr unsigned ABUFSZ = (unsigned)TM * 128u;   // bytes per A buf
  constexpr int NBUF = (TM == 256) ? 2 : 3;
  constexpr unsigned BBASE = (unsigned)NBUF * ABUFSZ;
  __shared__ __align__(16) u16 LDS[(TM == 256) ? 65536 : 73728];
  const int tid = threadIdx.x;
  const int w = tid >> 6, lane = tid & 63;
  const int wm = w >> 2, wn = w & 3;
  const int lr = lane & 15, lk = lane >> 4, lrm = lr & 7;
  const int NT = K >> 6;
  const size_t Kb = (size_t)K * 2;
  const int l8 = lane >> 3, l7 = lane & 7;
  const int schunk = l7 ^ l8;                 // pre-swizzled source chunk

  // -------- bijective XCD-chunked tile decode (m204), bn-fast in-chunk
  const int nwg = gridDim.x;
  const int q8 = nwg >> 3, r8 = nwg & 7;
  const int xcd = blockIdx.x & 7, ord = blockIdx.x >> 3;
  const int id = (xcd < r8 ? xcd * (q8 + 1) : r8 * (q8 + 1) + (xcd - r8) * q8) + ord;
  const int bn = id % nbn, bm = id / nbn;

  const unsigned wm16lr = (unsigned)(wm * 16 + lr) * 128u;
  const unsigned wn16lr = (unsigned)(wn * 16 + lr) * 128u;
  unsigned ch[2];
  ch[0] = (unsigned)(((lk) ^ lrm) << 4);
  ch[1] = (unsigned)(((4 + lk) ^ lrm) << 4);
  const char* LB = (const char*)&LDS[0];

  f32x4 acc[2 * MF][4];
  #pragma unroll
  for (int f = 0; f < 2 * MF; f++)
    #pragma unroll
    for (int n = 0; n < 4; n++) { acc[f][n][0]=0.f; acc[f][n][1]=0.f; acc[f][n][2]=0.f; acc[f][n][3]=0.f; }

  const char* Ab = (const char*)A;
  const char* Bb = (const char*)Bt;
  u16* LDSp = &LDS[0];

  // persistent fragment registers (dedup: each LDS fragment read once per K-tile)
  bf16x8 afE[MF][2], afO[MF][2], bfE[2][2], bfO[2][2];

  // stage one half-tile. isB: operand; half: 0/1; tt: K-tile; bb: lds buf
  auto STAGE = [&](int isB, int half, int tt, int bb) {
    long k0b = (long)tt * 128;
    if (!isB) {
      if constexpr (TM == 256) {
        int rb = bm * 256 + half * 128;
        #pragma unroll
        for (int i = 0; i < 2; i++) {
          int r0 = half * 128 + i * 64 + w * 8;
          int gr = rb + i * 64 + w * 8 + l8;
          const char* src = Ab + (size_t)gr * Kb + k0b + schunk * 16;
          unsigned dst = (unsigned)bb * ABUFSZ + (unsigned)r0 * 128u;
          gload_lds16((const u16*)src, LDSp + dst / 2);
        }
      } else {
        int r0 = half * 64 + w * 8;
        int gr = bm * 128 + half * 64 + w * 8 + l8;
        const char* src = Ab + (size_t)gr * Kb + k0b + schunk * 16;
        unsigned dst = (unsigned)bb * ABUFSZ + (unsigned)r0 * 128u;
        gload_lds16((const u16*)src, LDSp + dst / 2);
      }
    } else {
      int rb = bn * 256 + half * 128;
      #pragma unroll
      for (int i = 0; i < 2; i++) {
        int r0 = half * 128 + i * 64 + w * 8;
        int gr = rb + i * 64 + w * 8 + l8;
        if (gr >= N) gr = N - 1;
        const char* src = Bb + (size_t)gr * Kb + k0b + schunk * 16;
        unsigned dst = BBASE + (unsigned)bb * 32768u + (unsigned)r0 * 128u;
        gload_lds16((const u16*)src, LDSp + dst / 2);
      }
    }
  };

#define QREAD_A(DST, MH, ABUF)                                                      \
    _Pragma("unroll") for (int f = 0; f < MF; f++) {                                \
      _Pragma("unroll") for (int kk = 0; kk < 2; kk++) {                            \
        unsigned ad = (ABUF) + (unsigned)((MH) * MF + f) * 4096u + wm16lr + ch[kk]; \
        DST[f][kk] = *(const bf16x8*)(LB + ad);                                     \
      }                                                                             \
    }

#define QREAD_B(DST, NH, BBUF)                                                      \
    _Pragma("unroll") for (int n = 0; n < 2; n++) {                                 \
      _Pragma("unroll") for (int kk = 0; kk < 2; kk++) {                            \
        unsigned ad = BBASE + (BBUF) + (unsigned)((NH) * 2 + n) * 8192u + wn16lr + ch[kk]; \
        DST[n][kk] = *(const bf16x8*)(LB + ad);                                     \
      }                                                                             \
    }

#define QMFMA(AF, BF, MH, NH)                                                       \
    __builtin_amdgcn_s_setprio(1);                                                  \
    _Pragma("unroll") for (int kk = 0; kk < 2; kk++) {                              \
      _Pragma("unroll") for (int f = 0; f < MF; f++) {                              \
        _Pragma("unroll") for (int n = 0; n < 2; n++) {                             \
          acc[(MH) * MF + f][(NH) * 2 + n] = __builtin_amdgcn_mfma_f32_16x16x32_bf16( \
              AF[f][kk], BF[n][kk], acc[(MH) * MF + f][(NH) * 2 + n], 0, 0, 0);     \
        }                                                                           \
      }                                                                             \
    }                                                                               \
    __builtin_amdgcn_s_setprio(0);

#define SYNC1(VM)                                                                   \
    asm volatile("s_waitcnt vmcnt(" #VM ")" ::: "memory");                          \
    __builtin_amdgcn_s_barrier();                                                   \
    asm volatile("s_waitcnt lgkmcnt(0)" ::: "memory");                              \
    __builtin_amdgcn_sched_barrier(0);

#define LGKM0                                                                       \
    asm volatile("s_waitcnt lgkmcnt(0)" ::: "memory");                              \
    __builtin_amdgcn_sched_barrier(0);

#define SYNC2                                                                       \
    __builtin_amdgcn_s_barrier();                                                   \
    __builtin_amdgcn_sched_barrier(0);

  if constexpr (TM == 256) {
    // prologue: stage tile 0 fully into buf 0 (events: A0,B0,A1,B1)
    STAGE(0, 0, 0, 0);
    STAGE(1, 0, 0, 0);
    STAGE(0, 1, 0, 0);
    STAGE(1, 1, 0, 0);
    for (int t = 0; t < NT; t++) {
      const unsigned aob  = (unsigned)(t & 1) * ABUFSZ;
      const unsigned bob  = (unsigned)(t & 1) * 32768u;
      const int bb1 = (t + 1) & 1;
      const int tn = (t + 1 < NT) ? (t + 1) : 0;       // clamp dummy stage source
      // ---- phase 0: MFMA (A1,B1) of t-1; then read A0,B0 of t (overlap MFMA)
      {
        STAGE(0, 0, tn, bb1);
        SYNC1(6)
        if (t > 0) { QMFMA(afO, bfO, 1, 1) }
        QREAD_A(afE, 0, aob)
        QREAD_B(bfE, 0, bob)
        SYNC2
      }
      // ---- phase 1: MFMA (A0,B0); read A1 of t
      {
        STAGE(1, 0, tn, bb1);
        SYNC1(6)
        QMFMA(afE, bfE, 0, 0)
        QREAD_A(afO, 1, aob)
        SYNC2
      }
      // ---- phase 2: MFMA (A1,B0); read B1 of t
      {
        STAGE(0, 1, tn, bb1);
        SYNC1(6)
        QMFMA(afO, bfE, 1, 0)
        QREAD_B(bfO, 1, bob)
        SYNC2
      }
      // ---- phase 3: MFMA (A0,B1)
      {
        STAGE(1, 1, tn, bb1);
        SYNC1(6)
        QMFMA(afE, bfO, 0, 1)
        SYNC2
      }
    }
    // tail: (A1,B1) of tile NT-1 (afO/bfO read at p1/p2, waited at p3's lgkm0)
    QMFMA(afO, bfO, 1, 1)
  } else {
    // TM=128: 3-buffer rotation, lean 2-phase, post-MFMA read overlap.
    // prologue: tile 0 -> buf 0, tile 1 -> buf 1; drain tiles 0; read tile 0 frags.
    STAGE(0, 0, 0, 0);
    STAGE(1, 0, 0, 0);
    STAGE(0, 1, 0, 0);
    STAGE(1, 1, 0, 0);
    STAGE(0, 0, 1, 1);
    STAGE(1, 0, 1, 1);
    STAGE(0, 1, 1, 1);
    STAGE(1, 1, 1, 1);
    asm volatile("s_waitcnt vmcnt(6)" ::: "memory");
    __builtin_amdgcn_s_barrier();
    __builtin_amdgcn_sched_barrier(0);
    QREAD_A(afE, 0, 0u)
    QREAD_A(afO, 1, 0u)
    QREAD_B(bfE, 0, 0u)
    int cb = 0;                                        // buf of tile t
    for (int t = 0; t < NT; t++) {
      const unsigned aob = (unsigned)cb * ABUFSZ;
      const unsigned bob = (unsigned)cb * 32768u;
      int nb = cb + 1; if (nb == 3) nb = 0;            // buf of tile t+1
      const unsigned aobn = (unsigned)nb * ABUFSZ;
      const unsigned bobn = (unsigned)nb * 32768u;
      int sb = cb + 2; if (sb >= 3) sb -= 3;           // buf of tile t+2 (== buf of t-1)
      const int tn = (t + 2 < NT) ? (t + 2) : t;       // clamp dummy stage source
      // ---- phase A: stage alpha(t+2); MFMA (A0+A1)xB0; read B1(t) under MFMA
      STAGE(0, 0, tn, sb);
      STAGE(1, 0, tn, sb);
      LGKM0
      QMFMA(afE, bfE, 0, 0)
      QMFMA(afO, bfE, 1, 0)
      QREAD_B(bfO, 1, bob)
      // ---- phase B: stage beta(t+2); vmcnt(6); bar; MFMA (A0+A1)xB1;
      //      read A0,A1,B0 of t+1 under MFMA (alpha/beta(t+1) complete here)
      STAGE(0, 1, tn, sb);
      STAGE(1, 1, tn, sb);
      asm volatile("s_waitcnt vmcnt(6)" ::: "memory");
      __builtin_amdgcn_s_barrier();
      LGKM0
      QMFMA(afE, bfO, 0, 1)
      QMFMA(afO, bfO, 1, 1)
      QREAD_A(afE, 0, aobn)
      QREAD_A(afO, 1, aobn)
      QREAD_B(bfE, 0, bobn)
      SYNC2
      cb++; if (cb == 3) cb = 0;
    }
  }
#undef QREAD_A
#undef QREAD_B
#undef QMFMA
#undef SYNC1
#undef LGKM0
#undef SYNC2

  // epilogue
  #pragma unroll
  for (int nf = 0; nf < 4; nf++) {
    int Cc = bn * 256 + nf * 64 + wn * 16 + lr;
    bool ok = (Cc < N);
    float bv = (bias && ok) ? bias[Cc] : 0.f;
    #pragma unroll
    for (int mf = 0; mf < 2 * MF; mf++) {
      #pragma unroll
      for (int j = 0; j < 4; j++) {
        int R = bm * TM + mf * 32 + wm * 16 + lk * 4 + j;
        float v = acc[mf][nf][j] + bv;
        if (MODE == 6) {
          float vp = __shfl_xor(v, 1, 64);   // partner column (Cc^1)
          if ((lr & 1) == 0) {
            float s = v / (1.f + __expf(-v));   // silu(gate)
            ((u16*)outp)[(size_t)R * (N >> 1) + (Cc >> 1)] = f2bf(s * vp);
          }
        } else if (ok) {
          if (MODE == 0) {
            ((u16*)outp)[(size_t)R * N + Cc] = f2bf(v);
          } else if (MODE == 1) {
            ((float*)outp)[(size_t)R * N + Cc] = v;
          } else if (MODE == 3) {
            ((u16*)outp)[(size_t)R * N + Cc] = f2bf(gelu_tanh(v));
          } else if (MODE == 4) {
            int orow = rowmap[R];
            ((float*)outp)[(size_t)orow * N + Cc] = v;
          } else if (MODE == 7) {
            u16* hp = (u16*)outp + (size_t)R * N + Cc;
            *hp = f2bf(bf2f(*hp) + v);
          }
        }
      }
    }
  }
}

// ---------------------------------------------------------------- windowed attention with fused RoPE
__global__ __launch_bounds__(256, 2) void attn_k(
    const u16* __restrict__ qkv, u16* __restrict__ outO,
    const float* __restrict__ cosr, const float* __restrict__ sinr) {
  __shared__ u16 Qs[64 * 104];
  __shared__ u16 Ks[64 * 104];
  __shared__ u16 Vt[80 * 72];
  __shared__ u16 Ps[64 * 72];
  const int w = blockIdx.x, hd = blockIdx.y;
  const int tid = threadIdx.x;
  const u16* base = qkv + (size_t)w * 64 * 3840 + hd * 80;

  // RoPE staging: one thread per (row, c<40) pair computes both rotated halves
  for (int idx = tid; idx < 64 * 40; idx += 256) {
    int r = idx / 40, c = idx - r * 40;
    int tokg = w * 64 + r;
    const float* cr = cosr + (size_t)tokg * 80;
    const float* sr = sinr + (size_t)tokg * 80;
    float c0 = cr[c], c1 = cr[c + 40], s0 = sr[c], s1 = sr[c + 40];
    const u16* rp = base + (size_t)r * 3840;
    float q0 = bf2f(rp[c]), q1 = bf2f(rp[c + 40]);
    float k0 = bf2f(rp[1280 + c]), k1 = bf2f(rp[1280 + c + 40]);
    Qs[r * 104 + c]      = f2bf(q0 * c0 - q1 * s0);
    Qs[r * 104 + c + 40] = f2bf(q1 * c1 + q0 * s1);
    Ks[r * 104 + c]      = f2bf(k0 * c0 - k1 * s0);
    Ks[r * 104 + c + 40] = f2bf(k1 * c1 + k0 * s1);
  }
  for (int idx = tid; idx < 64 * 16; idx += 256) {
    int r = idx >> 4, c = 80 + (idx & 15);
    Qs[r * 104 + c] = 0;
    Ks[r * 104 + c] = 0;
  }
  for (int idx = tid; idx < 80 * 64; idx += 256) {
    int d = idx >> 6, kt = idx & 63;
    Vt[d * 72 + kt] = base[(size_t)kt * 3840 + 2560 + d];
  }
  __syncthreads();

  const int lane = tid & 63, wv = tid >> 6;
  const int lr = lane & 15, lk = lane >> 4;
  const float sc = 0.11180339887498949f;  // 80^-0.5

  f32x4 sfrag[4];
  #pragma unroll
  for (int f = 0; f < 4; f++) { sfrag[f][0]=0.f; sfrag[f][1]=0.f; sfrag[f][2]=0.f; sfrag[f][3]=0.f; }
  bf16x8 aq[3];
  #pragma unroll
  for (int ks = 0; ks < 3; ks++) aq[ks] = *(const bf16x8*)&Qs[(wv * 16 + lr) * 104 + ks * 32 + lk * 8];
  #pragma unroll
  for (int fn = 0; fn < 4; fn++) {
    #pragma unroll
    for (int ks = 0; ks < 3; ks++) {
      bf16x8 bk = *(const bf16x8*)&Ks[(fn * 16 + lr) * 104 + ks * 32 + lk * 8];
      sfrag[fn] = __builtin_amdgcn_mfma_f32_16x16x32_bf16(aq[ks], bk, sfrag[fn], 0, 0, 0);
    }
  }

  float inv[4];
  #pragma unroll
  for (int j = 0; j < 4; j++) {
    float mx = -1e30f;
    #pragma unroll
    for (int fn = 0; fn < 4; fn++) mx = fmaxf(mx, sfrag[fn][j] * sc);
    #pragma unroll
    for (int d = 1; d < 16; d <<= 1) mx = fmaxf(mx, __shfl_xor(mx, d, 64));
    float sum = 0.f;
    #pragma unroll
    for (int fn = 0; fn < 4; fn++) {
      float e = __expf(sfrag[fn][j] * sc - mx);
      Ps[(wv * 16 + lk * 4 + j) * 72 + fn * 16 + lr] = f2bf(e);
      sum += e;
    }
    #pragma unroll
    for (int d = 1; d < 16; d <<= 1) sum += __shfl_xor(sum, d, 64);
    inv[j] = 1.0f / sum;
  }
  __syncthreads();

  bf16x8 ap[2];
  #pragma unroll
  for (int ks = 0; ks < 2; ks++) ap[ks] = *(const bf16x8*)&Ps[(wv * 16 + lr) * 72 + ks * 32 + lk * 8];
  f32x4 of[5];
  #pragma unroll
  for (int f = 0; f < 5; f++) { of[f][0]=0.f; of[f][1]=0.f; of[f][2]=0.f; of[f][3]=0.f; }
  #pragma unroll
  for (int fn2 = 0; fn2 < 5; fn2++) {
    #pragma unroll
    for (int ks = 0; ks < 2; ks++) {
      bf16x8 bv = *(const bf16x8*)&Vt[(fn2 * 16 + lr) * 72 + ks * 32 + lk * 8];
      of[fn2] = __builtin_amdgcn_mfma_f32_16x16x32_bf16(ap[ks], bv, of[fn2], 0, 0, 0);
    }
  }

  #pragma unroll
  for (int fn2 = 0; fn2 < 5; fn2++) {
    #pragma unroll
    for (int j = 0; j < 4; j++) {
      int q = wv * 16 + lk * 4 + j;
      int d = fn2 * 16 + lr;
      outO[((size_t)(w * 64 + q)) * 1280 + hd * 80 + d] = f2bf(of[fn2][j] * inv[j]);
    }
  }
}

// ---------------------------------------------------------------- host
extern "C" void kernel_launch(void* const* d_in, const int* in_sizes, int n_in,
                              void* d_out, int out_size, void* d_ws, size_t ws_size,
                              hipStream_t stream) {
  (void)in_sizes; (void)n_in; (void)out_size; (void)ws_size;
  const float* pv   = (const float*)d_in[0];
  const float* cosi = (const float*)d_in[1];
  const float* sini = (const float*)d_in[2];
  const int*   wi   = (const int*)d_in[3];
  const float* Wp   = (const float*)d_in[4];
  const float* n1w  = (const float*)d_in[5];
  const float* qkvw = (const float*)d_in[6];
  const float* qkvb = (const float*)d_in[7];
  const float* pw   = (const float*)d_in[8];
  const float* pb   = (const float*)d_in[9];
  const float* n2w  = (const float*)d_in[10];
  const float* gw   = (const float*)d_in[11];
  const float* gb   = (const float*)d_in[12];
  const float* uw   = (const float*)d_in[13];
  const float* ub   = (const float*)d_in[14];
  const float* dw   = (const float*)d_in[15];
  const float* db   = (const float*)d_in[16];
  const float* mnw  = (const float*)d_in[17];
  const float* ml1w = (const float*)d_in[18];
  const float* ml1b = (const float*)d_in[19];
  const float* ml2w = (const float*)d_in[20];
  const float* ml2b = (const float*)d_in[21];
  const float* dnw  = (const float*)d_in[22];
  const float* dl1w = (const float*)d_in[23];
  const float* dl1b = (const float*)d_in[24];
  const float* dl2w = (const float*)d_in[25];
  const float* dl2b = (const float*)d_in[26];
  float* outv = (float*)d_out;
  char* ws = (char*)d_ws;

  size_t off = 0;
  u16*  h     = (u16*)(ws + off);  off += (size_t)NTOK * HID_ * 2;       // 42MB (bf16 residual)
  float* cosr = (float*)(ws + off); off += (size_t)NTOK * 80 * 4;
  float* sinr = (float*)(ws + off); off += (size_t)NTOK * 80 * 4;
  u16*  xb    = (u16*)(ws + off);  off += (size_t)NTOK * HID_ * 2;       // 42MB
  u16*  bufA  = (u16*)(ws + off);  off += (size_t)NTOK * 3840 * 2;       // 126MB
  u16*  bufB  = (u16*)(ws + off);  off += (size_t)NTOK * INTER_ * 2;     // 113MB
  u16*  bufC  = (u16*)(ws + off);  off += (size_t)NTOK * HID_ * 2;       // 42MB
  u16*  Wt    = (u16*)(ws + off);  off += (size_t)BIGD * BIGD * 2;       // 52.5MB
  float* ibuf = (float*)(ws + off); off += (size_t)2 * INTER_ * 4;       // 27KB

  dim3 B256(256), B512(512);
  #define TW(src, K_, N_) twt_k<<<dim3((N_) / 32, (K_) / 32), B256, 0, stream>>>((src), Wt, (K_), (N_))
  #define G8(MODE, TM_, Abuf, bias_, out_, rmap_, gate_, M_, N_, K_)                      \
    gemm8_k<MODE, TM_><<<dim3(((M_) / (TM_)) * (((N_) + 255) / 256)), B512, 0, stream>>>( \
        (Abuf), Wt, (bias_), (out_), (rmap_), (gate_), (((N_) + 255) / 256), (N_), (K_))

  // gather pixel rows + cos/sin
  gather_pv_k<<<(NTOK * 384 + 255) / 256, B256, 0, stream>>>(pv, wi, bufA);
  gather_cs_k<<<(NTOK * 20 + 255) / 256, B256, 0, stream>>>(cosi, sini, wi, cosr, sinr);

  // h = pv_g @ W_patch   (bf16 residual stream)
  TW(Wp, 1536, HID_);
  G8(0, 128, bufA, nullptr, h, nullptr, nullptr, NTOK, HID_, 1536);

  for (int i = 0; i < 6; i++) {
    // attn
    rmsnorm_k<<<NTOK, B256, 0, stream>>>(h, n1w + (size_t)i * HID_, xb, HID_);
    TW(qkvw + (size_t)i * HID_ * 3840, HID_, 3840);
    G8(0, 256, xb, qkvb + (size_t)i * 3840, bufA, nullptr, nullptr, NTOK, 3840, HID_);
    attn_k<<<dim3(256, 16), B256, 0, stream>>>(bufA, bufC, cosr, sinr);
    TW(pw + (size_t)i * HID_ * HID_, HID_, HID_);
    G8(7, 128, bufC, pb + (size_t)i * HID_, h, nullptr, nullptr, NTOK, HID_, HID_);
    // mlp: fused gate+up via interleaved weight columns (even=gate, odd=up)
    rmsnorm_k<<<NTOK, B256, 0, stream>>>(h, n2w + (size_t)i * HID_, xb, HID_);
    twt2_k<<<dim3(INTER_ / 32, HID_ / 32), B256, 0, stream>>>(
        gw + (size_t)i * HID_ * INTER_, Wt, HID_, INTER_, 0);
    twt2_k<<<dim3(INTER_ / 32, HID_ / 32), B256, 0, stream>>>(
        uw + (size_t)i * HID_ * INTER_, Wt, HID_, INTER_, 1);
    bi_k<<<(INTER_ + 255) / 256, B256, 0, stream>>>(
        gb + (size_t)i * INTER_, ub + (size_t)i * INTER_, ibuf, INTER_);
    G8(6, 256, xb, ibuf, bufA, nullptr, nullptr, NTOK, 2 * INTER_, HID_);
    TW(dw + (size_t)i * INTER_ * HID_, INTER_, HID_);
    G8(7, 128, bufA, db + (size_t)i * HID_, h, nullptr, nullptr, NTOK, HID_, INTER_);
    // deepstack mergers after layers 2 and 4
    if (i == 2 || i == 4) {
      int j = (i == 2) ? 0 : 1;
      rmsnorm_k<<<NGRP, B256, 0, stream>>>(h, dnw + (size_t)j * BIGD, bufC, BIGD);
      TW(dl1w + (size_t)j * BIGD * BIGD, BIGD, BIGD);
      G8(3, 128, bufC, dl1b + (size_t)j * BIGD, bufA, nullptr, nullptr, NGRP, BIGD, BIGD);
      TW(dl2w + (size_t)j * BIGD * ODIM, BIGD, ODIM);
      G8(4, 128, bufA, dl2b + (size_t)j * ODIM, outv + (size_t)(1 + j) * NGRP * ODIM,
         wi, nullptr, NGRP, ODIM, BIGD);
    }
  }

  // final merger -> plane 0
  rmsnorm_k<<<NTOK, B256, 0, stream>>>(h, mnw, bufC, HID_);
  TW(ml1w, BIGD, BIGD);
  G8(3, 128, bufC, ml1b, bufA, nullptr, nullptr, NGRP, BIGD, BIGD);
  TW(ml2w, BIGD, ODIM);
  G8(4, 128, bufA, ml2b, outv, wi, nullptr, NGRP, ODIM, BIGD);
  #undef TW
  #undef G8
}

// Round 20
// 6969.348 us; speedup vs baseline: 1.0139x; 1.0139x over previous
//
#include <hip/hip_runtime.h>
#include <hip/hip_bf16.h>

typedef unsigned short u16;
typedef __bf16 bf16x8 __attribute__((ext_vector_type(8)));
typedef float   f32x4 __attribute__((ext_vector_type(4)));
typedef unsigned short u16x8 __attribute__((ext_vector_type(8)));

#define NTOK  16384
#define HID_  1280
#define NHEAD 16
#define HD    80
#define INTER_ 3456
#define NGRP  4096
#define ODIM  2048
#define BIGD  5120

static __device__ __forceinline__ u16 f2bf(float f) {
  __hip_bfloat16 h = __float2bfloat16(f);
  return __builtin_bit_cast(u16, h);
}
static __device__ __forceinline__ float bf2f(u16 u) {
  return __bfloat162float(__builtin_bit_cast(__hip_bfloat16, u));
}
static __device__ __forceinline__ float gelu_tanh(float x) {
  float y = 0.7978845608028654f * (x + 0.044715f * x * x * x);
  float t = 1.0f - 2.0f / (1.0f + __expf(2.0f * y));   // tanh(y)
  return 0.5f * x * (1.0f + t);
}

// async global->LDS, 16B per lane, dest = wave-uniform base + lane*16
static __device__ __forceinline__ void gload_lds16(const u16* g, u16* l) {
  __builtin_amdgcn_global_load_lds(
      (const __attribute__((address_space(1))) unsigned int*)g,
      (__attribute__((address_space(3))) unsigned int*)l, 16, 0, 0);
}

// ---------------------------------------------------------------- gathers
__global__ __launch_bounds__(256) void gather_pv_k(
    const float* __restrict__ pv, const int* __restrict__ wi, u16* __restrict__ out) {
  int t = blockIdx.x * 256 + threadIdx.x;          // NTOK*384 float4 groups
  if (t >= NTOK * 384) return;
  int i = t / 384, c4 = t - i * 384;
  int s = wi[i >> 2] * 4 + (i & 3);
  float4 v = *(const float4*)(pv + (size_t)s * 1536 + c4 * 4);
  uint2 r;
  r.x = (unsigned)f2bf(v.x) | ((unsigned)f2bf(v.y) << 16);
  r.y = (unsigned)f2bf(v.z) | ((unsigned)f2bf(v.w) << 16);
  *(uint2*)(out + (size_t)i * 1536 + c4 * 4) = r;
}

__global__ __launch_bounds__(256) void gather_cs_k(
    const float* __restrict__ ci, const float* __restrict__ si,
    const int* __restrict__ wi, float* __restrict__ co, float* __restrict__ so) {
  int t = blockIdx.x * 256 + threadIdx.x;          // NTOK*20 float4 groups
  if (t >= NTOK * 20) return;
  int i = t / 20, c4 = t - i * 20;
  int s = wi[i >> 2] * 4 + (i & 3);
  *(float4*)(co + (size_t)i * 80 + c4 * 4) = *(const float4*)(ci + (size_t)s * 80 + c4 * 4);
  *(float4*)(so + (size_t)i * 80 + c4 * 4) = *(const float4*)(si + (size_t)s * 80 + c4 * 4);
}

// ---------------------------------------------------------------- weight f32[K][N] -> bf16[N][K]
__global__ __launch_bounds__(256) void twt_k(
    const float* __restrict__ W, u16* __restrict__ Wt, int K, int N) {
  __shared__ u16 t[32][33];
  int bn = blockIdx.x * 32, bk = blockIdx.y * 32;
  int tx = threadIdx.x & 31, ty = threadIdx.x >> 5;   // ty 0..7
  #pragma unroll
  for (int r = 0; r < 4; r++) {
    int k = bk + ty + r * 8;
    t[tx][ty + r * 8] = f2bf(W[(size_t)k * N + bn + tx]);
  }
  __syncthreads();
  #pragma unroll
  for (int r = 0; r < 4; r++) {
    int n = bn + ty + r * 8;
    Wt[(size_t)n * K + bk + tx] = t[ty + r * 8][tx];
  }
}

// weight f32[K][N] -> bf16 interleaved rows: Wt[(2n+ph)][K]
__global__ __launch_bounds__(256) void twt2_k(
    const float* __restrict__ W, u16* __restrict__ Wt, int K, int N, int ph) {
  __shared__ u16 t[32][33];
  int bn = blockIdx.x * 32, bk = blockIdx.y * 32;
  int tx = threadIdx.x & 31, ty = threadIdx.x >> 5;
  #pragma unroll
  for (int r = 0; r < 4; r++) {
    int k = bk + ty + r * 8;
    t[tx][ty + r * 8] = f2bf(W[(size_t)k * N + bn + tx]);
  }
  __syncthreads();
  #pragma unroll
  for (int r = 0; r < 4; r++) {
    int n = bn + ty + r * 8;
    Wt[(size_t)(2 * n + ph) * K + bk + tx] = t[ty + r * 8][tx];
  }
}

// ---------------------------------------------------------------- rmsnorm (bf16 in -> bf16 out), 8-wide vectorized
__global__ __launch_bounds__(256) void rmsnorm_k(
    const u16* __restrict__ x, const float* __restrict__ w, u16* __restrict__ out, int D) {
  int row = blockIdx.x;
  const uint4* xr = (const uint4*)(x + (size_t)row * D);   // 8 bf16 per uint4
  int D8 = D >> 3;
  float ss = 0.f;
  for (int c = threadIdx.x; c < D8; c += 256) {
    uint4 v = xr[c];
    const unsigned vv[4] = {v.x, v.y, v.z, v.w};
    #pragma unroll
    for (int e = 0; e < 4; e++) {
      float a = bf2f((u16)(vv[e] & 0xffff));
      float b = bf2f((u16)(vv[e] >> 16));
      ss += a * a + b * b;
    }
  }
  #pragma unroll
  for (int d = 1; d < 64; d <<= 1) ss += __shfl_xor(ss, d, 64);
  __shared__ float part[4];
  if ((threadIdx.x & 63) == 0) part[threadIdx.x >> 6] = ss;
  __syncthreads();
  float tot = part[0] + part[1] + part[2] + part[3];
  float scale = rsqrtf(tot / (float)D + 1e-6f);
  u16* orow = out + (size_t)row * D;
  const float4* wr = (const float4*)w;
  for (int c = threadIdx.x; c < D8; c += 256) {
    uint4 v = xr[c];
    float4 w0 = wr[c * 2], w1 = wr[c * 2 + 1];
    const unsigned vv[4] = {v.x, v.y, v.z, v.w};
    const float wf[8] = {w0.x, w0.y, w0.z, w0.w, w1.x, w1.y, w1.z, w1.w};
    uint4 r;
    unsigned rr[4];
    #pragma unroll
    for (int e = 0; e < 4; e++) {
      float a = bf2f((u16)(vv[e] & 0xffff)) * scale * wf[e * 2];
      float b = bf2f((u16)(vv[e] >> 16)) * scale * wf[e * 2 + 1];
      rr[e] = (unsigned)f2bf(a) | ((unsigned)f2bf(b) << 16);
    }
    r.x = rr[0]; r.y = rr[1]; r.z = rr[2]; r.w = rr[3];
    *(uint4*)(orow + c * 8) = r;
  }
}

// ---------------------------------------------------------------- 8-phase GEMM, tile TM x 256 (TM=256 or 128)
// C = A(bf16 [M][K]) @ Bt(bf16 [N][K])^T + bias. 512 threads, 8 waves (2M x 4N).
// FRAGMENT-READ DEDUP (r18-proven schedule): each LDS fragment read once per
// K-tile; reads issued early, covered by the previous phase's vmcnt+barrier.
// Stage addressing HOISTED: per-lane global base pointers precomputed; each
// STAGE is base + tt*128 (no per-call 64-bit multiply).
// TM=256: 2 LDS buffers, 4 phases/K-tile; vmcnt {6,6,6,6}; tail MFMA.
// TM=128: 3 LDS buffers, lean 2 phases/K-tile (1 vmcnt + 2 barriers; r15-proven).
// LDS: A/B XOR-swizzled 16B chunks: LDS[r][c] = G[r][c ^ (r&7)], linear
//   gload_lds dest + pre-swizzled source. XCD-chunked bijective tile remap, bn-fast.
// MODE 0: bf16 store; 1: f32; 3: gelu->bf16; 4: f32 scatter rows;
// MODE 6: fused gate/up (interleaved B rows; even col=gate, odd=up; bias from
//   bias(gate)/bias2(up) by parity; silu(gate)*up -> bf16 out[R][N/2]);
// MODE 7: bf16 residual RMW: h[R][Cc] = bf16(bf2f(h) + v)
template <int MODE, int TM>
__global__ __launch_bounds__(512, 2) void gemm8_k(
    const u16* __restrict__ A, const u16* __restrict__ Bt, const float* __restrict__ bias,
    const float* __restrict__ bias2, void* __restrict__ outp, const int* __restrict__ rowmap,
    int nbn, int N, int K) {
  constexpr int MF = TM / 64;                 // A frags per half (4 or 2)
  constexpr unsigned ABUFSZ = (unsigned)TM * 128u;   // bytes per A buf
  constexpr int NBUF = (TM == 256) ? 2 : 3;
  constexpr unsigned BBASE = (unsigned)NBUF * ABUFSZ;
  __shared__ __align__(16) u16 LDS[(TM == 256) ? 65536 : 73728];
  const int tid = threadIdx.x;
  const int w = tid >> 6, lane = tid & 63;
  const int wm = w >> 2, wn = w & 3;
  const int lr = lane & 15, lk = lane >> 4, lrm = lr & 7;
  const int NT = K >> 6;
  const size_t Kb = (size_t)K * 2;
  const int l8 = lane >> 3, l7 = lane & 7;
  const int schunk = l7 ^ l8;                 // pre-swizzled source chunk

  // -------- bijective XCD-chunked tile decode (m204), bn-fast in-chunk
  const int nwg = gridDim.x;
  const int q8 = nwg >> 3, r8 = nwg & 7;
  const int xcd = blockIdx.x & 7, ord = blockIdx.x >> 3;
  const int id = (xcd < r8 ? xcd * (q8 + 1) : r8 * (q8 + 1) + (xcd - r8) * q8) + ord;
  const int bn = id % nbn, bm = id / nbn;

  const unsigned wm16lr = (unsigned)(wm * 16 + lr) * 128u;
  const unsigned wn16lr = (unsigned)(wn * 16 + lr) * 128u;
  unsigned ch[2];
  ch[0] = (unsigned)(((lk) ^ lrm) << 4);
  ch[1] = (unsigned)(((4 + lk) ^ lrm) << 4);
  const char* LB = (const char*)&LDS[0];

  f32x4 acc[2 * MF][4];
  #pragma unroll
  for (int f = 0; f < 2 * MF; f++)
    #pragma unroll
    for (int n = 0; n < 4; n++) { acc[f][n][0]=0.f; acc[f][n][1]=0.f; acc[f][n][2]=0.f; acc[f][n][3]=0.f; }

  const char* Ab = (const char*)A;
  const char* Bb = (const char*)Bt;
  u16* LDSp = &LDS[0];

  // hoisted per-lane global base pointers (src = base + tt*128)
  const char* aSrc[2][2];
  const char* bSrc[2][2];
  #pragma unroll
  for (int half = 0; half < 2; half++) {
    if constexpr (TM == 256) {
      #pragma unroll
      for (int i = 0; i < 2; i++) {
        int gr = bm * 256 + half * 128 + i * 64 + w * 8 + l8;
        aSrc[half][i] = Ab + (size_t)gr * Kb + schunk * 16;
      }
    } else {
      int gr = bm * 128 + half * 64 + w * 8 + l8;
      aSrc[half][0] = Ab + (size_t)gr * Kb + schunk * 16;
      aSrc[half][1] = aSrc[half][0];
    }
    #pragma unroll
    for (int i = 0; i < 2; i++) {
      int gr = bn * 256 + half * 128 + i * 64 + w * 8 + l8;
      if (gr >= N) gr = N - 1;
      bSrc[half][i] = Bb + (size_t)gr * Kb + schunk * 16;
    }
  }

  // persistent fragment registers (dedup: each LDS fragment read once per K-tile)
  bf16x8 afE[MF][2], afO[MF][2], bfE[2][2], bfO[2][2];

  // stage one half-tile. isB: operand; half: 0/1; tt: K-tile; bb: lds buf
  auto STAGE = [&](int isB, int half, int tt, int bb) {
    long k0b = (long)tt * 128;
    if (!isB) {
      if constexpr (TM == 256) {
        #pragma unroll
        for (int i = 0; i < 2; i++) {
          int r0 = half * 128 + i * 64 + w * 8;
          unsigned dst = (unsigned)bb * ABUFSZ + (unsigned)r0 * 128u;
          gload_lds16((const u16*)(aSrc[half][i] + k0b), LDSp + dst / 2);
        }
      } else {
        int r0 = half * 64 + w * 8;
        unsigned dst = (unsigned)bb * ABUFSZ + (unsigned)r0 * 128u;
        gload_lds16((const u16*)(aSrc[half][0] + k0b), LDSp + dst / 2);
      }
    } else {
      #pragma unroll
      for (int i = 0; i < 2; i++) {
        int r0 = half * 128 + i * 64 + w * 8;
        unsigned dst = BBASE + (unsigned)bb * 32768u + (unsigned)r0 * 128u;
        gload_lds16((const u16*)(bSrc[half][i] + k0b), LDSp + dst / 2);
      }
    }
  };

#define QREAD_A(DST, MH, ABUF)                                                      \
    _Pragma("unroll") for (int f = 0; f < MF; f++) {                                \
      _Pragma("unroll") for (int kk = 0; kk < 2; kk++) {                            \
        unsigned ad = (ABUF) + (unsigned)((MH) * MF + f) * 4096u + wm16lr + ch[kk]; \
        DST[f][kk] = *(const bf16x8*)(LB + ad);                                     \
      }                                                                             \
    }

#define QREAD_B(DST, NH, BBUF)                                                      \
    _Pragma("unroll") for (int n = 0; n < 2; n++) {                                 \
      _Pragma("unroll") for (int kk = 0; kk < 2; kk++) {                            \
        unsigned ad = BBASE + (BBUF) + (unsigned)((NH) * 2 + n) * 8192u + wn16lr + ch[kk]; \
        DST[n][kk] = *(const bf16x8*)(LB + ad);                                     \
      }                                                                             \
    }

#define QMFMA(AF, BF, MH, NH)                                                       \
    __builtin_amdgcn_s_setprio(1);                                                  \
    _Pragma("unroll") for (int kk = 0; kk < 2; kk++) {                              \
      _Pragma("unroll") for (int f = 0; f < MF; f++) {                              \
        _Pragma("unroll") for (int n = 0; n < 2; n++) {                             \
          acc[(MH) * MF + f][(NH) * 2 + n] = __builtin_amdgcn_mfma_f32_16x16x32_bf16( \
              AF[f][kk], BF[n][kk], acc[(MH) * MF + f][(NH) * 2 + n], 0, 0, 0);     \
        }                                                                           \
      }                                                                             \
    }                                                                               \
    __builtin_amdgcn_s_setprio(0);

#define SYNC1(VM)                                                                   \
    asm volatile("s_waitcnt vmcnt(" #VM ")" ::: "memory");                          \
    __builtin_amdgcn_s_barrier();                                                   \
    asm volatile("s_waitcnt lgkmcnt(0)" ::: "memory");                              \
    __builtin_amdgcn_sched_barrier(0);

#define LGKM0                                                                       \
    asm volatile("s_waitcnt lgkmcnt(0)" ::: "memory");                              \
    __builtin_amdgcn_sched_barrier(0);

#define SYNC2                                                                       \
    __builtin_amdgcn_s_barrier();                                                   \
    __builtin_amdgcn_sched_barrier(0);

  if constexpr (TM == 256) {
    // prologue: stage tile 0 fully into buf 0 (events: A0,B0,A1,B1)
    STAGE(0, 0, 0, 0);
    STAGE(1, 0, 0, 0);
    STAGE(0, 1, 0, 0);
    STAGE(1, 1, 0, 0);
    for (int t = 0; t < NT; t++) {
      const unsigned aob  = (unsigned)(t & 1) * ABUFSZ;
      const unsigned bob  = (unsigned)(t & 1) * 32768u;
      const int bb1 = (t + 1) & 1;
      const int tn = (t + 1 < NT) ? (t + 1) : 0;       // clamp dummy stage source
      // ---- phase 0: (A1,B1) of tile t-1 — no LDS reads
      {
        STAGE(0, 0, tn, bb1);
        SYNC1(6)
        if (t > 0) { QMFMA(afO, bfO, 1, 1) }
        SYNC2
      }
      // ---- phase 1: (A0,B0)
      {
        QREAD_A(afE, 0, aob)
        QREAD_B(bfE, 0, bob)
        STAGE(1, 0, tn, bb1);
        SYNC1(6)
        QMFMA(afE, bfE, 0, 0)
        SYNC2
      }
      // ---- phase 2: (A1,B0)
      {
        QREAD_A(afO, 1, aob)
        STAGE(0, 1, tn, bb1);
        SYNC1(6)
        QMFMA(afO, bfE, 1, 0)
        SYNC2
      }
      // ---- phase 3: (A0,B1)
      {
        QREAD_B(bfO, 1, bob)
        STAGE(1, 1, tn, bb1);
        SYNC1(6)
        QMFMA(afE, bfO, 0, 1)
        SYNC2
      }
    }
    // tail: (A1,B1) of tile NT-1
    QMFMA(afO, bfO, 1, 1)
  } else {
    // TM=128: 3-buffer rotation, lean 2-phase. Stage tile t+2 during tile t.
    // prologue: tile 0 -> buf 0, tile 1 -> buf 1 (12 loads); drain tile 0.
    STAGE(0, 0, 0, 0);
    STAGE(1, 0, 0, 0);
    STAGE(0, 1, 0, 0);
    STAGE(1, 1, 0, 0);
    STAGE(0, 0, 1, 1);
    STAGE(1, 0, 1, 1);
    STAGE(0, 1, 1, 1);
    STAGE(1, 1, 1, 1);
    asm volatile("s_waitcnt vmcnt(6)" ::: "memory");
    __builtin_amdgcn_s_barrier();
    __builtin_amdgcn_sched_barrier(0);
    int cb = 0;                                        // buf of tile t
    for (int t = 0; t < NT; t++) {
      const unsigned aob = (unsigned)cb * ABUFSZ;
      const unsigned bob = (unsigned)cb * 32768u;
      int sb = cb + 2; if (sb >= 3) sb -= 3;           // buf of tile t+2 (== buf of t-1)
      const int tn = (t + 2 < NT) ? (t + 2) : t;       // clamp dummy stage source
      // ---- phase A: read A0,A1,B0 of t; stage alpha(t+2); MFMA (A0+A1)xB0
      QREAD_A(afE, 0, aob)
      QREAD_A(afO, 1, aob)
      QREAD_B(bfE, 0, bob)
      STAGE(0, 0, tn, sb);
      STAGE(1, 0, tn, sb);
      LGKM0
      QMFMA(afE, bfE, 0, 0)
      QMFMA(afO, bfE, 1, 0)
      // ---- phase B: read B1 of t; stage beta(t+2); vmcnt(6); bar; MFMA (A0+A1)xB1
      QREAD_B(bfO, 1, bob)
      STAGE(0, 1, tn, sb);
      STAGE(1, 1, tn, sb);
      asm volatile("s_waitcnt vmcnt(6)" ::: "memory");
      __builtin_amdgcn_s_barrier();
      LGKM0
      QMFMA(afE, bfO, 0, 1)
      QMFMA(afO, bfO, 1, 1)
      SYNC2
      cb++; if (cb == 3) cb = 0;
    }
  }
#undef QREAD_A
#undef QREAD_B
#undef QMFMA
#undef SYNC1
#undef LGKM0
#undef SYNC2

  // epilogue
  #pragma unroll
  for (int nf = 0; nf < 4; nf++) {
    int Cc = bn * 256 + nf * 64 + wn * 16 + lr;
    bool ok = (Cc < N);
    float bv = 0.f;
    if (MODE == 6) {
      bv = ((lr & 1) == 0) ? bias[Cc >> 1] : bias2[Cc >> 1];
    } else if (bias && ok) {
      bv = bias[Cc];
    }
    #pragma unroll
    for (int mf = 0; mf < 2 * MF; mf++) {
      #pragma unroll
      for (int j = 0; j < 4; j++) {
        int R = bm * TM + mf * 32 + wm * 16 + lk * 4 + j;
        float v = acc[mf][nf][j] + bv;
        if (MODE == 6) {
          float vp = __shfl_xor(v, 1, 64);   // partner column (Cc^1)
          if ((lr & 1) == 0) {
            float s = v / (1.f + __expf(-v));   // silu(gate)
            ((u16*)outp)[(size_t)R * (N >> 1) + (Cc >> 1)] = f2bf(s * vp);
          }
        } else if (ok) {
          if (MODE == 0) {
            ((u16*)outp)[(size_t)R * N + Cc] = f2bf(v);
          } else if (MODE == 1) {
            ((float*)outp)[(size_t)R * N + Cc] = v;
          } else if (MODE == 3) {
            ((u16*)outp)[(size_t)R * N + Cc] = f2bf(gelu_tanh(v));
          } else if (MODE == 4) {
            int orow = rowmap[R];
            ((float*)outp)[(size_t)orow * N + Cc] = v;
          } else if (MODE == 7) {
            u16* hp = (u16*)outp + (size_t)R * N + Cc;
            *hp = f2bf(bf2f(*hp) + v);
          }
        }
      }
    }
  }
}

// ---------------------------------------------------------------- windowed attention with fused RoPE
__global__ __launch_bounds__(256, 2) void attn_k(
    const u16* __restrict__ qkv, u16* __restrict__ outO,
    const float* __restrict__ cosr, const float* __restrict__ sinr) {
  __shared__ u16 Qs[64 * 104];
  __shared__ u16 Ks[64 * 104];
  __shared__ u16 Vt[80 * 72];
  __shared__ u16 Ps[64 * 72];
  const int w = blockIdx.x, hd = blockIdx.y;
  const int tid = threadIdx.x;
  const u16* base = qkv + (size_t)w * 64 * 3840 + hd * 80;

  // RoPE staging: one thread per (row, c<40) pair computes both rotated halves
  for (int idx = tid; idx < 64 * 40; idx += 256) {
    int r = idx / 40, c = idx - r * 40;
    int tokg = w * 64 + r;
    const float* cr = cosr + (size_t)tokg * 80;
    const float* sr = sinr + (size_t)tokg * 80;
    float c0 = cr[c], c1 = cr[c + 40], s0 = sr[c], s1 = sr[c + 40];
    const u16* rp = base + (size_t)r * 3840;
    float q0 = bf2f(rp[c]), q1 = bf2f(rp[c + 40]);
    float k0 = bf2f(rp[1280 + c]), k1 = bf2f(rp[1280 + c + 40]);
    Qs[r * 104 + c]      = f2bf(q0 * c0 - q1 * s0);
    Qs[r * 104 + c + 40] = f2bf(q1 * c1 + q0 * s1);
    Ks[r * 104 + c]      = f2bf(k0 * c0 - k1 * s0);
    Ks[r * 104 + c + 40] = f2bf(k1 * c1 + k0 * s1);
  }
  for (int idx = tid; idx < 64 * 16; idx += 256) {
    int r = idx >> 4, c = 80 + (idx & 15);
    Qs[r * 104 + c] = 0;
    Ks[r * 104 + c] = 0;
  }
  for (int idx = tid; idx < 80 * 64; idx += 256) {
    int d = idx >> 6, kt = idx & 63;
    Vt[d * 72 + kt] = base[(size_t)kt * 3840 + 2560 + d];
  }
  __syncthreads();

  const int lane = tid & 63, wv = tid >> 6;
  const int lr = lane & 15, lk = lane >> 4;
  const float sc = 0.11180339887498949f;  // 80^-0.5

  f32x4 sfrag[4];
  #pragma unroll
  for (int f = 0; f < 4; f++) { sfrag[f][0]=0.f; sfrag[f][1]=0.f; sfrag[f][2]=0.f; sfrag[f][3]=0.f; }
  bf16x8 aq[3];
  #pragma unroll
  for (int ks = 0; ks < 3; ks++) aq[ks] = *(const bf16x8*)&Qs[(wv * 16 + lr) * 104 + ks * 32 + lk * 8];
  #pragma unroll
  for (int fn = 0; fn < 4; fn++) {
    #pragma unroll
    for (int ks = 0; ks < 3; ks++) {
      bf16x8 bk = *(const bf16x8*)&Ks[(fn * 16 + lr) * 104 + ks * 32 + lk * 8];
      sfrag[fn] = __builtin_amdgcn_mfma_f32_16x16x32_bf16(aq[ks], bk, sfrag[fn], 0, 0, 0);
    }
  }

  float inv[4];
  #pragma unroll
  for (int j = 0; j < 4; j++) {
    float mx = -1e30f;
    #pragma unroll
    for (int fn = 0; fn < 4; fn++) mx = fmaxf(mx, sfrag[fn][j] * sc);
    #pragma unroll
    for (int d = 1; d < 16; d <<= 1) mx = fmaxf(mx, __shfl_xor(mx, d, 64));
    float sum = 0.f;
    #pragma unroll
    for (int fn = 0; fn < 4; fn++) {
      float e = __expf(sfrag[fn][j] * sc - mx);
      Ps[(wv * 16 + lk * 4 + j) * 72 + fn * 16 + lr] = f2bf(e);
      sum += e;
    }
    #pragma unroll
    for (int d = 1; d < 16; d <<= 1) sum += __shfl_xor(sum, d, 64);
    inv[j] = 1.0f / sum;
  }
  __syncthreads();

  bf16x8 ap[2];
  #pragma unroll
  for (int ks = 0; ks < 2; ks++) ap[ks] = *(const bf16x8*)&Ps[(wv * 16 + lr) * 72 + ks * 32 + lk * 8];
  f32x4 of[5];
  #pragma unroll
  for (int f = 0; f < 5; f++) { of[f][0]=0.f; of[f][1]=0.f; of[f][2]=0.f; of[f][3]=0.f; }
  #pragma unroll
  for (int fn2 = 0; fn2 < 5; fn2++) {
    #pragma unroll
    for (int ks = 0; ks < 2; ks++) {
      bf16x8 bv = *(const bf16x8*)&Vt[(fn2 * 16 + lr) * 72 + ks * 32 + lk * 8];
      of[fn2] = __builtin_amdgcn_mfma_f32_16x16x32_bf16(ap[ks], bv, of[fn2], 0, 0, 0);
    }
  }

  #pragma unroll
  for (int fn2 = 0; fn2 < 5; fn2++) {
    #pragma unroll
    for (int j = 0; j < 4; j++) {
      int q = wv * 16 + lk * 4 + j;
      int d = fn2 * 16 + lr;
      outO[((size_t)(w * 64 + q)) * 1280 + hd * 80 + d] = f2bf(of[fn2][j] * inv[j]);
    }
  }
}

// ---------------------------------------------------------------- host
extern "C" void kernel_launch(void* const* d_in, const int* in_sizes, int n_in,
                              void* d_out, int out_size, void* d_ws, size_t ws_size,
                              hipStream_t stream) {
  (void)in_sizes; (void)n_in; (void)out_size; (void)ws_size;
  const float* pv   = (const float*)d_in[0];
  const float* cosi = (const float*)d_in[1];
  const float* sini = (const float*)d_in[2];
  const int*   wi   = (const int*)d_in[3];
  const float* Wp   = (const float*)d_in[4];
  const float* n1w  = (const float*)d_in[5];
  const float* qkvw = (const float*)d_in[6];
  const float* qkvb = (const float*)d_in[7];
  const float* pw   = (const float*)d_in[8];
  const float* pb   = (const float*)d_in[9];
  const float* n2w  = (const float*)d_in[10];
  const float* gw   = (const float*)d_in[11];
  const float* gb   = (const float*)d_in[12];
  const float* uw   = (const float*)d_in[13];
  const float* ub   = (const float*)d_in[14];
  const float* dw   = (const float*)d_in[15];
  const float* db   = (const float*)d_in[16];
  const float* mnw  = (const float*)d_in[17];
  const float* ml1w = (const float*)d_in[18];
  const float* ml1b = (const float*)d_in[19];
  const float* ml2w = (const float*)d_in[20];
  const float* ml2b = (const float*)d_in[21];
  const float* dnw  = (const float*)d_in[22];
  const float* dl1w = (const float*)d_in[23];
  const float* dl1b = (const float*)d_in[24];
  const float* dl2w = (const float*)d_in[25];
  const float* dl2b = (const float*)d_in[26];
  float* outv = (float*)d_out;
  char* ws = (char*)d_ws;

  size_t off = 0;
  u16*  h     = (u16*)(ws + off);  off += (size_t)NTOK * HID_ * 2;       // 42MB (bf16 residual)
  float* cosr = (float*)(ws + off); off += (size_t)NTOK * 80 * 4;
  float* sinr = (float*)(ws + off); off += (size_t)NTOK * 80 * 4;
  u16*  xb    = (u16*)(ws + off);  off += (size_t)NTOK * HID_ * 2;       // 42MB
  u16*  bufA  = (u16*)(ws + off);  off += (size_t)NTOK * 3840 * 2;       // 126MB
  u16*  bufB  = (u16*)(ws + off);  off += (size_t)NTOK * INTER_ * 2;     // 113MB
  u16*  bufC  = (u16*)(ws + off);  off += (size_t)NTOK * HID_ * 2;       // 42MB
  u16*  Wt    = (u16*)(ws + off);  off += (size_t)BIGD * BIGD * 2;       // 52.5MB

  dim3 B256(256), B512(512);
  #define TW(src, K_, N_) twt_k<<<dim3((N_) / 32, (K_) / 32), B256, 0, stream>>>((src), Wt, (K_), (N_))
  #define G8(MODE, TM_, Abuf, bias_, bias2_, out_, rmap_, M_, N_, K_)                     \
    gemm8_k<MODE, TM_><<<dim3(((M_) / (TM_)) * (((N_) + 255) / 256)), B512, 0, stream>>>( \
        (Abuf), Wt, (bias_), (bias2_), (out_), (rmap_), (((N_) + 255) / 256), (N_), (K_))

  // gather pixel rows + cos/sin
  gather_pv_k<<<(NTOK * 384 + 255) / 256, B256, 0, stream>>>(pv, wi, bufA);
  gather_cs_k<<<(NTOK * 20 + 255) / 256, B256, 0, stream>>>(cosi, sini, wi, cosr, sinr);

  // h = pv_g @ W_patch   (bf16 residual stream)
  TW(Wp, 1536, HID_);
  G8(0, 128, bufA, nullptr, nullptr, h, nullptr, NTOK, HID_, 1536);

  for (int i = 0; i < 6; i++) {
    // attn
    rmsnorm_k<<<NTOK, B256, 0, stream>>>(h, n1w + (size_t)i * HID_, xb, HID_);
    TW(qkvw + (size_t)i * HID_ * 3840, HID_, 3840);
    G8(0, 256, xb, qkvb + (size_t)i * 3840, nullptr, bufA, nullptr, NTOK, 3840, HID_);
    attn_k<<<dim3(256, 16), B256, 0, stream>>>(bufA, bufC, cosr, sinr);
    TW(pw + (size_t)i * HID_ * HID_, HID_, HID_);
    G8(7, 128, bufC, pb + (size_t)i * HID_, nullptr, h, nullptr, NTOK, HID_, HID_);
    // mlp: fused gate+up via interleaved weight columns (even=gate, odd=up)
    rmsnorm_k<<<NTOK, B256, 0, stream>>>(h, n2w + (size_t)i * HID_, xb, HID_);
    twt2_k<<<dim3(INTER_ / 32, HID_ / 32), B256, 0, stream>>>(
        gw + (size_t)i * HID_ * INTER_, Wt, HID_, INTER_, 0);
    twt2_k<<<dim3(INTER_ / 32, HID_ / 32), B256, 0, stream>>>(
        uw + (size_t)i * HID_ * INTER_, Wt, HID_, INTER_, 1);
    G8(6, 256, xb, gb + (size_t)i * INTER_, ub + (size_t)i * INTER_, bufA, nullptr,
       NTOK, 2 * INTER_, HID_);
    TW(dw + (size_t)i * INTER_ * HID_, INTER_, HID_);
    G8(7, 128, bufA, db + (size_t)i * HID_, nullptr, h, nullptr, NTOK, HID_, INTER_);
    // deepstack mergers after layers 2 and 4
    if (i == 2 || i == 4) {
      int j = (i == 2) ? 0 : 1;
      rmsnorm_k<<<NGRP, B256, 0, stream>>>(h, dnw + (size_t)j * BIGD, bufC, BIGD);
      TW(dl1w + (size_t)j * BIGD * BIGD, BIGD, BIGD);
      G8(3, 128, bufC, dl1b + (size_t)j * BIGD, nullptr, bufA, nullptr, NGRP, BIGD, BIGD);
      TW(dl2w + (size_t)j * BIGD * ODIM, BIGD, ODIM);
      G8(4, 128, bufA, dl2b + (size_t)j * ODIM, nullptr,
         outv + (size_t)(1 + j) * NGRP * ODIM, wi, NGRP, ODIM, BIGD);
    }
  }

  // final merger -> plane 0
  rmsnorm_k<<<NTOK, B256, 0, stream>>>(h, mnw, bufC, HID_);
  TW(ml1w, BIGD, BIGD);
  G8(3, 128, bufC, ml1b, nullptr, bufA, nullptr, NGRP, BIGD, BIGD);
  TW(ml2w, BIGD, ODIM);
  G8(4, 128, bufA, ml2b, nullptr, outv, wi, NGRP, ODIM, BIGD);
  #undef TW
  #undef G8
}

// Round 21
// 6897.535 us; speedup vs baseline: 1.0244x; 1.0104x over previous
//
#include <hip/hip_runtime.h>
#include <hip/hip_bf16.h>

typedef unsigned short u16;
typedef __bf16 bf16x8 __attribute__((ext_vector_type(8)));
typedef float   f32x4 __attribute__((ext_vector_type(4)));
typedef unsigned short u16x8 __attribute__((ext_vector_type(8)));

#define NTOK  16384
#define HID_  1280
#define NHEAD 16
#define HD    80
#define INTER_ 3456
#define NGRP  4096
#define ODIM  2048
#define BIGD  5120

static __device__ __forceinline__ u16 f2bf(float f) {
  __hip_bfloat16 h = __float2bfloat16(f);
  return __builtin_bit_cast(u16, h);
}
static __device__ __forceinline__ float bf2f(u16 u) {
  return __bfloat162float(__builtin_bit_cast(__hip_bfloat16, u));
}
static __device__ __forceinline__ float gelu_tanh(float x) {
  float y = 0.7978845608028654f * (x + 0.044715f * x * x * x);
  float t = 1.0f - 2.0f / (1.0f + __expf(2.0f * y));   // tanh(y)
  return 0.5f * x * (1.0f + t);
}

// async global->LDS, 16B per lane, dest = wave-uniform base + lane*16
static __device__ __forceinline__ void gload_lds16(const u16* g, u16* l) {
  __builtin_amdgcn_global_load_lds(
      (const __attribute__((address_space(1))) unsigned int*)g,
      (__attribute__((address_space(3))) unsigned int*)l, 16, 0, 0);
}

// ---------------------------------------------------------------- gathers
__global__ __launch_bounds__(256) void gather_pv_k(
    const float* __restrict__ pv, const int* __restrict__ wi, u16* __restrict__ out) {
  int t = blockIdx.x * 256 + threadIdx.x;          // NTOK*384 float4 groups
  if (t >= NTOK * 384) return;
  int i = t / 384, c4 = t - i * 384;
  int s = wi[i >> 2] * 4 + (i & 3);
  float4 v = *(const float4*)(pv + (size_t)s * 1536 + c4 * 4);
  uint2 r;
  r.x = (unsigned)f2bf(v.x) | ((unsigned)f2bf(v.y) << 16);
  r.y = (unsigned)f2bf(v.z) | ((unsigned)f2bf(v.w) << 16);
  *(uint2*)(out + (size_t)i * 1536 + c4 * 4) = r;
}

__global__ __launch_bounds__(256) void gather_cs_k(
    const float* __restrict__ ci, const float* __restrict__ si,
    const int* __restrict__ wi, float* __restrict__ co, float* __restrict__ so) {
  int t = blockIdx.x * 256 + threadIdx.x;          // NTOK*20 float4 groups
  if (t >= NTOK * 20) return;
  int i = t / 20, c4 = t - i * 20;
  int s = wi[i >> 2] * 4 + (i & 3);
  *(float4*)(co + (size_t)i * 80 + c4 * 4) = *(const float4*)(ci + (size_t)s * 80 + c4 * 4);
  *(float4*)(so + (size_t)i * 80 + c4 * 4) = *(const float4*)(si + (size_t)s * 80 + c4 * 4);
}

// ---------------------------------------------------------------- weight f32[K][N] -> bf16[N][K]
__global__ __launch_bounds__(256) void twt_k(
    const float* __restrict__ W, u16* __restrict__ Wt, int K, int N) {
  __shared__ u16 t[32][33];
  int bn = blockIdx.x * 32, bk = blockIdx.y * 32;
  int tx = threadIdx.x & 31, ty = threadIdx.x >> 5;   // ty 0..7
  #pragma unroll
  for (int r = 0; r < 4; r++) {
    int k = bk + ty + r * 8;
    t[tx][ty + r * 8] = f2bf(W[(size_t)k * N + bn + tx]);
  }
  __syncthreads();
  #pragma unroll
  for (int r = 0; r < 4; r++) {
    int n = bn + ty + r * 8;
    Wt[(size_t)n * K + bk + tx] = t[ty + r * 8][tx];
  }
}

// weight f32[K][N] -> bf16 interleaved rows: Wt[(2n+ph)][K]
__global__ __launch_bounds__(256) void twt2_k(
    const float* __restrict__ W, u16* __restrict__ Wt, int K, int N, int ph) {
  __shared__ u16 t[32][33];
  int bn = blockIdx.x * 32, bk = blockIdx.y * 32;
  int tx = threadIdx.x & 31, ty = threadIdx.x >> 5;
  #pragma unroll
  for (int r = 0; r < 4; r++) {
    int k = bk + ty + r * 8;
    t[tx][ty + r * 8] = f2bf(W[(size_t)k * N + bn + tx]);
  }
  __syncthreads();
  #pragma unroll
  for (int r = 0; r < 4; r++) {
    int n = bn + ty + r * 8;
    Wt[(size_t)(2 * n + ph) * K + bk + tx] = t[ty + r * 8][tx];
  }
}

// ---------------------------------------------------------------- rmsnorm (bf16 in -> bf16 out), 8-wide vectorized
__global__ __launch_bounds__(256) void rmsnorm_k(
    const u16* __restrict__ x, const float* __restrict__ w, u16* __restrict__ out, int D) {
  int row = blockIdx.x;
  const uint4* xr = (const uint4*)(x + (size_t)row * D);   // 8 bf16 per uint4
  int D8 = D >> 3;
  float ss = 0.f;
  for (int c = threadIdx.x; c < D8; c += 256) {
    uint4 v = xr[c];
    const unsigned vv[4] = {v.x, v.y, v.z, v.w};
    #pragma unroll
    for (int e = 0; e < 4; e++) {
      float a = bf2f((u16)(vv[e] & 0xffff));
      float b = bf2f((u16)(vv[e] >> 16));
      ss += a * a + b * b;
    }
  }
  #pragma unroll
  for (int d = 1; d < 64; d <<= 1) ss += __shfl_xor(ss, d, 64);
  __shared__ float part[4];
  if ((threadIdx.x & 63) == 0) part[threadIdx.x >> 6] = ss;
  __syncthreads();
  float tot = part[0] + part[1] + part[2] + part[3];
  float scale = rsqrtf(tot / (float)D + 1e-6f);
  u16* orow = out + (size_t)row * D;
  const float4* wr = (const float4*)w;
  for (int c = threadIdx.x; c < D8; c += 256) {
    uint4 v = xr[c];
    float4 w0 = wr[c * 2], w1 = wr[c * 2 + 1];
    const unsigned vv[4] = {v.x, v.y, v.z, v.w};
    const float wf[8] = {w0.x, w0.y, w0.z, w0.w, w1.x, w1.y, w1.z, w1.w};
    uint4 r;
    unsigned rr[4];
    #pragma unroll
    for (int e = 0; e < 4; e++) {
      float a = bf2f((u16)(vv[e] & 0xffff)) * scale * wf[e * 2];
      float b = bf2f((u16)(vv[e] >> 16)) * scale * wf[e * 2 + 1];
      rr[e] = (unsigned)f2bf(a) | ((unsigned)f2bf(b) << 16);
    }
    r.x = rr[0]; r.y = rr[1]; r.z = rr[2]; r.w = rr[3];
    *(uint4*)(orow + c * 8) = r;
  }
}

// ---------------------------------------------------------------- 8-phase GEMM, tile TM x 256 (TM=256 or 128)
// C = A(bf16 [M][K]) @ Bt(bf16 [N][K])^T + bias. 512 threads, 8 waves (2M x 4N).
// FRAGMENT-READ DEDUP (r18-proven schedule); hoisted stage addressing (r20).
// SUPERTILE tile ordering: id -> (super, bn, bmi), bm = super*SB + bmi, so
// temporally-adjacent blocks cover SB bm-rows x same bn -> each B panel is
// fetched once per SB rows (L2-miss traffic for B divided by SB). Bijective
// when SB | nbm. A panels (SB x 0.3-0.9MB) + B panel fit the 4MB per-XCD L2.
// TM=256: 2 LDS buffers, 4 phases/K-tile; vmcnt {6,6,6,6}; tail MFMA.
// TM=128: 3 LDS buffers, lean 2 phases/K-tile (1 vmcnt + 2 barriers).
// LDS: A/B XOR-swizzled 16B chunks; linear gload_lds dest + pre-swizzled source.
// MODE 0: bf16 store; 1: f32; 3: gelu->bf16; 4: f32 scatter rows;
// MODE 6: fused gate/up (interleaved B rows; silu(gate)*up -> bf16 out[R][N/2]);
// MODE 7: bf16 residual RMW: h[R][Cc] = bf16(bf2f(h) + v)
template <int MODE, int TM>
__global__ __launch_bounds__(512, 2) void gemm8_k(
    const u16* __restrict__ A, const u16* __restrict__ Bt, const float* __restrict__ bias,
    const float* __restrict__ bias2, void* __restrict__ outp, const int* __restrict__ rowmap,
    int nbn, int sb, int N, int K) {
  constexpr int MF = TM / 64;                 // A frags per half (4 or 2)
  constexpr unsigned ABUFSZ = (unsigned)TM * 128u;   // bytes per A buf
  constexpr int NBUF = (TM == 256) ? 2 : 3;
  constexpr unsigned BBASE = (unsigned)NBUF * ABUFSZ;
  __shared__ __align__(16) u16 LDS[(TM == 256) ? 65536 : 73728];
  const int tid = threadIdx.x;
  const int w = tid >> 6, lane = tid & 63;
  const int wm = w >> 2, wn = w & 3;
  const int lr = lane & 15, lk = lane >> 4, lrm = lr & 7;
  const int NT = K >> 6;
  const size_t Kb = (size_t)K * 2;
  const int l8 = lane >> 3, l7 = lane & 7;
  const int schunk = l7 ^ l8;                 // pre-swizzled source chunk

  // -------- bijective XCD-chunked tile decode (m204)
  const int nwg = gridDim.x;
  const int q8 = nwg >> 3, r8 = nwg & 7;
  const int xcd = blockIdx.x & 7, ord = blockIdx.x >> 3;
  const int id = (xcd < r8 ? xcd * (q8 + 1) : r8 * (q8 + 1) + (xcd - r8) * q8) + ord;
  // -------- supertile decode: (super, bn, bmi); bm = super*sb + bmi
  const int spt = sb * nbn;
  const int super = id / spt;
  const int rem = id - super * spt;
  const int bn = rem / sb;
  const int bm = super * sb + (rem - bn * sb);

  const unsigned wm16lr = (unsigned)(wm * 16 + lr) * 128u;
  const unsigned wn16lr = (unsigned)(wn * 16 + lr) * 128u;
  unsigned ch[2];
  ch[0] = (unsigned)(((lk) ^ lrm) << 4);
  ch[1] = (unsigned)(((4 + lk) ^ lrm) << 4);
  const char* LB = (const char*)&LDS[0];

  f32x4 acc[2 * MF][4];
  #pragma unroll
  for (int f = 0; f < 2 * MF; f++)
    #pragma unroll
    for (int n = 0; n < 4; n++) { acc[f][n][0]=0.f; acc[f][n][1]=0.f; acc[f][n][2]=0.f; acc[f][n][3]=0.f; }

  const char* Ab = (const char*)A;
  const char* Bb = (const char*)Bt;
  u16* LDSp = &LDS[0];

  // hoisted per-lane global base pointers (src = base + tt*128)
  const char* aSrc[2][2];
  const char* bSrc[2][2];
  #pragma unroll
  for (int half = 0; half < 2; half++) {
    if constexpr (TM == 256) {
      #pragma unroll
      for (int i = 0; i < 2; i++) {
        int gr = bm * 256 + half * 128 + i * 64 + w * 8 + l8;
        aSrc[half][i] = Ab + (size_t)gr * Kb + schunk * 16;
      }
    } else {
      int gr = bm * 128 + half * 64 + w * 8 + l8;
      aSrc[half][0] = Ab + (size_t)gr * Kb + schunk * 16;
      aSrc[half][1] = aSrc[half][0];
    }
    #pragma unroll
    for (int i = 0; i < 2; i++) {
      int gr = bn * 256 + half * 128 + i * 64 + w * 8 + l8;
      if (gr >= N) gr = N - 1;
      bSrc[half][i] = Bb + (size_t)gr * Kb + schunk * 16;
    }
  }

  // persistent fragment registers (dedup: each LDS fragment read once per K-tile)
  bf16x8 afE[MF][2], afO[MF][2], bfE[2][2], bfO[2][2];

  // stage one half-tile. isB: operand; half: 0/1; tt: K-tile; bb: lds buf
  auto STAGE = [&](int isB, int half, int tt, int bb) {
    long k0b = (long)tt * 128;
    if (!isB) {
      if constexpr (TM == 256) {
        #pragma unroll
        for (int i = 0; i < 2; i++) {
          int r0 = half * 128 + i * 64 + w * 8;
          unsigned dst = (unsigned)bb * ABUFSZ + (unsigned)r0 * 128u;
          gload_lds16((const u16*)(aSrc[half][i] + k0b), LDSp + dst / 2);
        }
      } else {
        int r0 = half * 64 + w * 8;
        unsigned dst = (unsigned)bb * ABUFSZ + (unsigned)r0 * 128u;
        gload_lds16((const u16*)(aSrc[half][0] + k0b), LDSp + dst / 2);
      }
    } else {
      #pragma unroll
      for (int i = 0; i < 2; i++) {
        int r0 = half * 128 + i * 64 + w * 8;
        unsigned dst = BBASE + (unsigned)bb * 32768u + (unsigned)r0 * 128u;
        gload_lds16((const u16*)(bSrc[half][i] + k0b), LDSp + dst / 2);
      }
    }
  };

#define QREAD_A(DST, MH, ABUF)                                                      \
    _Pragma("unroll") for (int f = 0; f < MF; f++) {                                \
      _Pragma("unroll") for (int kk = 0; kk < 2; kk++) {                            \
        unsigned ad = (ABUF) + (unsigned)((MH) * MF + f) * 4096u + wm16lr + ch[kk]; \
        DST[f][kk] = *(const bf16x8*)(LB + ad);                                     \
      }                                                                             \
    }

#define QREAD_B(DST, NH, BBUF)                                                      \
    _Pragma("unroll") for (int n = 0; n < 2; n++) {                                 \
      _Pragma("unroll") for (int kk = 0; kk < 2; kk++) {                            \
        unsigned ad = BBASE + (BBUF) + (unsigned)((NH) * 2 + n) * 8192u + wn16lr + ch[kk]; \
        DST[n][kk] = *(const bf16x8*)(LB + ad);                                     \
      }                                                                             \
    }

#define QMFMA(AF, BF, MH, NH)                                                       \
    __builtin_amdgcn_s_setprio(1);                                                  \
    _Pragma("unroll") for (int kk = 0; kk < 2; kk++) {                              \
      _Pragma("unroll") for (int f = 0; f < MF; f++) {                              \
        _Pragma("unroll") for (int n = 0; n < 2; n++) {                             \
          acc[(MH) * MF + f][(NH) * 2 + n] = __builtin_amdgcn_mfma_f32_16x16x32_bf16( \
              AF[f][kk], BF[n][kk], acc[(MH) * MF + f][(NH) * 2 + n], 0, 0, 0);     \
        }                                                                           \
      }                                                                             \
    }                                                                               \
    __builtin_amdgcn_s_setprio(0);

#define SYNC1(VM)                                                                   \
    asm volatile("s_waitcnt vmcnt(" #VM ")" ::: "memory");                          \
    __builtin_amdgcn_s_barrier();                                                   \
    asm volatile("s_waitcnt lgkmcnt(0)" ::: "memory");                              \
    __builtin_amdgcn_sched_barrier(0);

#define LGKM0                                                                       \
    asm volatile("s_waitcnt lgkmcnt(0)" ::: "memory");                              \
    __builtin_amdgcn_sched_barrier(0);

#define SYNC2                                                                       \
    __builtin_amdgcn_s_barrier();                                                   \
    __builtin_amdgcn_sched_barrier(0);

  if constexpr (TM == 256) {
    // prologue: stage tile 0 fully into buf 0 (events: A0,B0,A1,B1)
    STAGE(0, 0, 0, 0);
    STAGE(1, 0, 0, 0);
    STAGE(0, 1, 0, 0);
    STAGE(1, 1, 0, 0);
    for (int t = 0; t < NT; t++) {
      const unsigned aob  = (unsigned)(t & 1) * ABUFSZ;
      const unsigned bob  = (unsigned)(t & 1) * 32768u;
      const int bb1 = (t + 1) & 1;
      const int tn = (t + 1 < NT) ? (t + 1) : 0;       // clamp dummy stage source
      // ---- phase 0: (A1,B1) of tile t-1 — no LDS reads
      {
        STAGE(0, 0, tn, bb1);
        SYNC1(6)
        if (t > 0) { QMFMA(afO, bfO, 1, 1) }
        SYNC2
      }
      // ---- phase 1: (A0,B0)
      {
        QREAD_A(afE, 0, aob)
        QREAD_B(bfE, 0, bob)
        STAGE(1, 0, tn, bb1);
        SYNC1(6)
        QMFMA(afE, bfE, 0, 0)
        SYNC2
      }
      // ---- phase 2: (A1,B0)
      {
        QREAD_A(afO, 1, aob)
        STAGE(0, 1, tn, bb1);
        SYNC1(6)
        QMFMA(afO, bfE, 1, 0)
        SYNC2
      }
      // ---- phase 3: (A0,B1)
      {
        QREAD_B(bfO, 1, bob)
        STAGE(1, 1, tn, bb1);
        SYNC1(6)
        QMFMA(afE, bfO, 0, 1)
        SYNC2
      }
    }
    // tail: (A1,B1) of tile NT-1
    QMFMA(afO, bfO, 1, 1)
  } else {
    // TM=128: 3-buffer rotation, lean 2-phase. Stage tile t+2 during tile t.
    // prologue: tile 0 -> buf 0, tile 1 -> buf 1 (12 loads); drain tile 0.
    STAGE(0, 0, 0, 0);
    STAGE(1, 0, 0, 0);
    STAGE(0, 1, 0, 0);
    STAGE(1, 1, 0, 0);
    STAGE(0, 0, 1, 1);
    STAGE(1, 0, 1, 1);
    STAGE(0, 1, 1, 1);
    STAGE(1, 1, 1, 1);
    asm volatile("s_waitcnt vmcnt(6)" ::: "memory");
    __builtin_amdgcn_s_barrier();
    __builtin_amdgcn_sched_barrier(0);
    int cb = 0;                                        // buf of tile t
    for (int t = 0; t < NT; t++) {
      const unsigned aob = (unsigned)cb * ABUFSZ;
      const unsigned bob = (unsigned)cb * 32768u;
      int sbuf = cb + 2; if (sbuf >= 3) sbuf -= 3;     // buf of tile t+2 (== buf of t-1)
      const int tn = (t + 2 < NT) ? (t + 2) : t;       // clamp dummy stage source
      // ---- phase A: read A0,A1,B0 of t; stage alpha(t+2); MFMA (A0+A1)xB0
      QREAD_A(afE, 0, aob)
      QREAD_A(afO, 1, aob)
      QREAD_B(bfE, 0, bob)
      STAGE(0, 0, tn, sbuf);
      STAGE(1, 0, tn, sbuf);
      LGKM0
      QMFMA(afE, bfE, 0, 0)
      QMFMA(afO, bfE, 1, 0)
      // ---- phase B: read B1 of t; stage beta(t+2); vmcnt(6); bar; MFMA (A0+A1)xB1
      QREAD_B(bfO, 1, bob)
      STAGE(0, 1, tn, sbuf);
      STAGE(1, 1, tn, sbuf);
      asm volatile("s_waitcnt vmcnt(6)" ::: "memory");
      __builtin_amdgcn_s_barrier();
      LGKM0
      QMFMA(afE, bfO, 0, 1)
      QMFMA(afO, bfO, 1, 1)
      SYNC2
      cb++; if (cb == 3) cb = 0;
    }
  }
#undef QREAD_A
#undef QREAD_B
#undef QMFMA
#undef SYNC1
#undef LGKM0
#undef SYNC2

  // epilogue
  #pragma unroll
  for (int nf = 0; nf < 4; nf++) {
    int Cc = bn * 256 + nf * 64 + wn * 16 + lr;
    bool ok = (Cc < N);
    float bv = 0.f;
    if (MODE == 6) {
      bv = ((lr & 1) == 0) ? bias[Cc >> 1] : bias2[Cc >> 1];
    } else if (bias && ok) {
      bv = bias[Cc];
    }
    #pragma unroll
    for (int mf = 0; mf < 2 * MF; mf++) {
      #pragma unroll
      for (int j = 0; j < 4; j++) {
        int R = bm * TM + mf * 32 + wm * 16 + lk * 4 + j;
        float v = acc[mf][nf][j] + bv;
        if (MODE == 6) {
          float vp = __shfl_xor(v, 1, 64);   // partner column (Cc^1)
          if ((lr & 1) == 0) {
            float s = v / (1.f + __expf(-v));   // silu(gate)
            ((u16*)outp)[(size_t)R * (N >> 1) + (Cc >> 1)] = f2bf(s * vp);
          }
        } else if (ok) {
          if (MODE == 0) {
            ((u16*)outp)[(size_t)R * N + Cc] = f2bf(v);
          } else if (MODE == 1) {
            ((float*)outp)[(size_t)R * N + Cc] = v;
          } else if (MODE == 3) {
            ((u16*)outp)[(size_t)R * N + Cc] = f2bf(gelu_tanh(v));
          } else if (MODE == 4) {
            int orow = rowmap[R];
            ((float*)outp)[(size_t)orow * N + Cc] = v;
          } else if (MODE == 7) {
            u16* hp = (u16*)outp + (size_t)R * N + Cc;
            *hp = f2bf(bf2f(*hp) + v);
          }
        }
      }
    }
  }
}

// ---------------------------------------------------------------- windowed attention with fused RoPE
__global__ __launch_bounds__(256, 2) void attn_k(
    const u16* __restrict__ qkv, u16* __restrict__ outO,
    const float* __restrict__ cosr, const float* __restrict__ sinr) {
  __shared__ u16 Qs[64 * 104];
  __shared__ u16 Ks[64 * 104];
  __shared__ u16 Vt[80 * 72];
  __shared__ u16 Ps[64 * 72];
  const int w = blockIdx.x, hd = blockIdx.y;
  const int tid = threadIdx.x;
  const u16* base = qkv + (size_t)w * 64 * 3840 + hd * 80;

  // RoPE staging: one thread per (row, c<40) pair computes both rotated halves
  for (int idx = tid; idx < 64 * 40; idx += 256) {
    int r = idx / 40, c = idx - r * 40;
    int tokg = w * 64 + r;
    const float* cr = cosr + (size_t)tokg * 80;
    const float* sr = sinr + (size_t)tokg * 80;
    float c0 = cr[c], c1 = cr[c + 40], s0 = sr[c], s1 = sr[c + 40];
    const u16* rp = base + (size_t)r * 3840;
    float q0 = bf2f(rp[c]), q1 = bf2f(rp[c + 40]);
    float k0 = bf2f(rp[1280 + c]), k1 = bf2f(rp[1280 + c + 40]);
    Qs[r * 104 + c]      = f2bf(q0 * c0 - q1 * s0);
    Qs[r * 104 + c + 40] = f2bf(q1 * c1 + q0 * s1);
    Ks[r * 104 + c]      = f2bf(k0 * c0 - k1 * s0);
    Ks[r * 104 + c + 40] = f2bf(k1 * c1 + k0 * s1);
  }
  for (int idx = tid; idx < 64 * 16; idx += 256) {
    int r = idx >> 4, c = 80 + (idx & 15);
    Qs[r * 104 + c] = 0;
    Ks[r * 104 + c] = 0;
  }
  for (int idx = tid; idx < 80 * 64; idx += 256) {
    int d = idx >> 6, kt = idx & 63;
    Vt[d * 72 + kt] = base[(size_t)kt * 3840 + 2560 + d];
  }
  __syncthreads();

  const int lane = tid & 63, wv = tid >> 6;
  const int lr = lane & 15, lk = lane >> 4;
  const float sc = 0.11180339887498949f;  // 80^-0.5

  f32x4 sfrag[4];
  #pragma unroll
  for (int f = 0; f < 4; f++) { sfrag[f][0]=0.f; sfrag[f][1]=0.f; sfrag[f][2]=0.f; sfrag[f][3]=0.f; }
  bf16x8 aq[3];
  #pragma unroll
  for (int ks = 0; ks < 3; ks++) aq[ks] = *(const bf16x8*)&Qs[(wv * 16 + lr) * 104 + ks * 32 + lk * 8];
  #pragma unroll
  for (int fn = 0; fn < 4; fn++) {
    #pragma unroll
    for (int ks = 0; ks < 3; ks++) {
      bf16x8 bk = *(const bf16x8*)&Ks[(fn * 16 + lr) * 104 + ks * 32 + lk * 8];
      sfrag[fn] = __builtin_amdgcn_mfma_f32_16x16x32_bf16(aq[ks], bk, sfrag[fn], 0, 0, 0);
    }
  }

  float inv[4];
  #pragma unroll
  for (int j = 0; j < 4; j++) {
    float mx = -1e30f;
    #pragma unroll
    for (int fn = 0; fn < 4; fn++) mx = fmaxf(mx, sfrag[fn][j] * sc);
    #pragma unroll
    for (int d = 1; d < 16; d <<= 1) mx = fmaxf(mx, __shfl_xor(mx, d, 64));
    float sum = 0.f;
    #pragma unroll
    for (int fn = 0; fn < 4; fn++) {
      float e = __expf(sfrag[fn][j] * sc - mx);
      Ps[(wv * 16 + lk * 4 + j) * 72 + fn * 16 + lr] = f2bf(e);
      sum += e;
    }
    #pragma unroll
    for (int d = 1; d < 16; d <<= 1) sum += __shfl_xor(sum, d, 64);
    inv[j] = 1.0f / sum;
  }
  __syncthreads();

  bf16x8 ap[2];
  #pragma unroll
  for (int ks = 0; ks < 2; ks++) ap[ks] = *(const bf16x8*)&Ps[(wv * 16 + lr) * 72 + ks * 32 + lk * 8];
  f32x4 of[5];
  #pragma unroll
  for (int f = 0; f < 5; f++) { of[f][0]=0.f; of[f][1]=0.f; of[f][2]=0.f; of[f][3]=0.f; }
  #pragma unroll
  for (int fn2 = 0; fn2 < 5; fn2++) {
    #pragma unroll
    for (int ks = 0; ks < 2; ks++) {
      bf16x8 bv = *(const bf16x8*)&Vt[(fn2 * 16 + lr) * 72 + ks * 32 + lk * 8];
      of[fn2] = __builtin_amdgcn_mfma_f32_16x16x32_bf16(ap[ks], bv, of[fn2], 0, 0, 0);
    }
  }

  #pragma unroll
  for (int fn2 = 0; fn2 < 5; fn2++) {
    #pragma unroll
    for (int j = 0; j < 4; j++) {
      int q = wv * 16 + lk * 4 + j;
      int d = fn2 * 16 + lr;
      outO[((size_t)(w * 64 + q)) * 1280 + hd * 80 + d] = f2bf(of[fn2][j] * inv[j]);
    }
  }
}

// ---------------------------------------------------------------- host
extern "C" void kernel_launch(void* const* d_in, const int* in_sizes, int n_in,
                              void* d_out, int out_size, void* d_ws, size_t ws_size,
                              hipStream_t stream) {
  (void)in_sizes; (void)n_in; (void)out_size; (void)ws_size;
  const float* pv   = (const float*)d_in[0];
  const float* cosi = (const float*)d_in[1];
  const float* sini = (const float*)d_in[2];
  const int*   wi   = (const int*)d_in[3];
  const float* Wp   = (const float*)d_in[4];
  const float* n1w  = (const float*)d_in[5];
  const float* qkvw = (const float*)d_in[6];
  const float* qkvb = (const float*)d_in[7];
  const float* pw   = (const float*)d_in[8];
  const float* pb   = (const float*)d_in[9];
  const float* n2w  = (const float*)d_in[10];
  const float* gw   = (const float*)d_in[11];
  const float* gb   = (const float*)d_in[12];
  const float* uw   = (const float*)d_in[13];
  const float* ub   = (const float*)d_in[14];
  const float* dw   = (const float*)d_in[15];
  const float* db   = (const float*)d_in[16];
  const float* mnw  = (const float*)d_in[17];
  const float* ml1w = (const float*)d_in[18];
  const float* ml1b = (const float*)d_in[19];
  const float* ml2w = (const float*)d_in[20];
  const float* ml2b = (const float*)d_in[21];
  const float* dnw  = (const float*)d_in[22];
  const float* dl1w = (const float*)d_in[23];
  const float* dl1b = (const float*)d_in[24];
  const float* dl2w = (const float*)d_in[25];
  const float* dl2b = (const float*)d_in[26];
  float* outv = (float*)d_out;
  char* ws = (char*)d_ws;

  size_t off = 0;
  u16*  h     = (u16*)(ws + off);  off += (size_t)NTOK * HID_ * 2;       // 42MB (bf16 residual)
  float* cosr = (float*)(ws + off); off += (size_t)NTOK * 80 * 4;
  float* sinr = (float*)(ws + off); off += (size_t)NTOK * 80 * 4;
  u16*  xb    = (u16*)(ws + off);  off += (size_t)NTOK * HID_ * 2;       // 42MB
  u16*  bufA  = (u16*)(ws + off);  off += (size_t)NTOK * 3840 * 2;       // 126MB
  u16*  bufB  = (u16*)(ws + off);  off += (size_t)NTOK * INTER_ * 2;     // 113MB
  u16*  bufC  = (u16*)(ws + off);  off += (size_t)NTOK * HID_ * 2;       // 42MB
  u16*  Wt    = (u16*)(ws + off);  off += (size_t)BIGD * BIGD * 2;       // 52.5MB

  dim3 B256(256), B512(512);
  // supertile depth: SB=4 for K<=1536 (A panels small), else 2 (fits 4MB L2)
  #define SBOF(K_) (((K_) <= 1536) ? 4 : 2)
  #define TW(src, K_, N_) twt_k<<<dim3((N_) / 32, (K_) / 32), B256, 0, stream>>>((src), Wt, (K_), (N_))
  #define G8(MODE, TM_, Abuf, bias_, bias2_, out_, rmap_, M_, N_, K_)                     \
    gemm8_k<MODE, TM_><<<dim3(((M_) / (TM_)) * (((N_) + 255) / 256)), B512, 0, stream>>>( \
        (Abuf), Wt, (bias_), (bias2_), (out_), (rmap_), (((N_) + 255) / 256), SBOF(K_),   \
        (N_), (K_))

  // gather pixel rows + cos/sin
  gather_pv_k<<<(NTOK * 384 + 255) / 256, B256, 0, stream>>>(pv, wi, bufA);
  gather_cs_k<<<(NTOK * 20 + 255) / 256, B256, 0, stream>>>(cosi, sini, wi, cosr, sinr);

  // h = pv_g @ W_patch   (bf16 residual stream)
  TW(Wp, 1536, HID_);
  G8(0, 128, bufA, nullptr, nullptr, h, nullptr, NTOK, HID_, 1536);

  for (int i = 0; i < 6; i++) {
    // attn
    rmsnorm_k<<<NTOK, B256, 0, stream>>>(h, n1w + (size_t)i * HID_, xb, HID_);
    TW(qkvw + (size_t)i * HID_ * 3840, HID_, 3840);
    G8(0, 256, xb, qkvb + (size_t)i * 3840, nullptr, bufA, nullptr, NTOK, 3840, HID_);
    attn_k<<<dim3(256, 16), B256, 0, stream>>>(bufA, bufC, cosr, sinr);
    TW(pw + (size_t)i * HID_ * HID_, HID_, HID_);
    G8(7, 128, bufC, pb + (size_t)i * HID_, nullptr, h, nullptr, NTOK, HID_, HID_);
    // mlp: fused gate+up via interleaved weight columns (even=gate, odd=up)
    rmsnorm_k<<<NTOK, B256, 0, stream>>>(h, n2w + (size_t)i * HID_, xb, HID_);
    twt2_k<<<dim3(INTER_ / 32, HID_ / 32), B256, 0, stream>>>(
        gw + (size_t)i * HID_ * INTER_, Wt, HID_, INTER_, 0);
    twt2_k<<<dim3(INTER_ / 32, HID_ / 32), B256, 0, stream>>>(
        uw + (size_t)i * HID_ * INTER_, Wt, HID_, INTER_, 1);
    G8(6, 256, xb, gb + (size_t)i * INTER_, ub + (size_t)i * INTER_, bufA, nullptr,
       NTOK, 2 * INTER_, HID_);
    TW(dw + (size_t)i * INTER_ * HID_, INTER_, HID_);
    G8(7, 128, bufA, db + (size_t)i * HID_, nullptr, h, nullptr, NTOK, HID_, INTER_);
    // deepstack mergers after layers 2 and 4
    if (i == 2 || i == 4) {
      int j = (i == 2) ? 0 : 1;
      rmsnorm_k<<<NGRP, B256, 0, stream>>>(h, dnw + (size_t)j * BIGD, bufC, BIGD);
      TW(dl1w + (size_t)j * BIGD * BIGD, BIGD, BIGD);
      G8(3, 128, bufC, dl1b + (size_t)j * BIGD, nullptr, bufA, nullptr, NGRP, BIGD, BIGD);
      TW(dl2w + (size_t)j * BIGD * ODIM, BIGD, ODIM);
      G8(4, 128, bufA, dl2b + (size_t)j * ODIM, nullptr,
         outv + (size_t)(1 + j) * NGRP * ODIM, wi, NGRP, ODIM, BIGD);
    }
  }

  // final merger -> plane 0
  rmsnorm_k<<<NTOK, B256, 0, stream>>>(h, mnw, bufC, HID_);
  TW(ml1w, BIGD, BIGD);
  G8(3, 128, bufC, ml1b, nullptr, bufA, nullptr, NGRP, BIGD, BIGD);
  TW(ml2w, BIGD, ODIM);
  G8(4, 128, bufA, ml2b, nullptr, outv, wi, NGRP, ODIM, BIGD);
  #undef TW
  #undef G8
  #undef SBOF
}

// Round 22
// 6841.892 us; speedup vs baseline: 1.0327x; 1.0081x over previous
//
#include <hip/hip_runtime.h>
#include <hip/hip_bf16.h>

typedef unsigned short u16;
typedef __bf16 bf16x8 __attribute__((ext_vector_type(8)));
typedef float   f32x4 __attribute__((ext_vector_type(4)));
typedef unsigned short u16x8 __attribute__((ext_vector_type(8)));

#define NTOK  16384
#define HID_  1280
#define NHEAD 16
#define HD    80
#define INTER_ 3456
#define NGRP  4096
#define ODIM  2048
#define BIGD  5120

static __device__ __forceinline__ u16 f2bf(float f) {
  __hip_bfloat16 h = __float2bfloat16(f);
  return __builtin_bit_cast(u16, h);
}
static __device__ __forceinline__ float bf2f(u16 u) {
  return __bfloat162float(__builtin_bit_cast(__hip_bfloat16, u));
}
static __device__ __forceinline__ float gelu_tanh(float x) {
  float y = 0.7978845608028654f * (x + 0.044715f * x * x * x);
  float t = 1.0f - 2.0f / (1.0f + __expf(2.0f * y));   // tanh(y)
  return 0.5f * x * (1.0f + t);
}

// async global->LDS, 16B per lane, dest = wave-uniform base + lane*16
static __device__ __forceinline__ void gload_lds16(const u16* g, u16* l) {
  __builtin_amdgcn_global_load_lds(
      (const __attribute__((address_space(1))) unsigned int*)g,
      (__attribute__((address_space(3))) unsigned int*)l, 16, 0, 0);
}

// ---------------------------------------------------------------- gathers
__global__ __launch_bounds__(256) void gather_pv_k(
    const float* __restrict__ pv, const int* __restrict__ wi, u16* __restrict__ out) {
  int t = blockIdx.x * 256 + threadIdx.x;          // NTOK*384 float4 groups
  if (t >= NTOK * 384) return;
  int i = t / 384, c4 = t - i * 384;
  int s = wi[i >> 2] * 4 + (i & 3);
  float4 v = *(const float4*)(pv + (size_t)s * 1536 + c4 * 4);
  uint2 r;
  r.x = (unsigned)f2bf(v.x) | ((unsigned)f2bf(v.y) << 16);
  r.y = (unsigned)f2bf(v.z) | ((unsigned)f2bf(v.w) << 16);
  *(uint2*)(out + (size_t)i * 1536 + c4 * 4) = r;
}

__global__ __launch_bounds__(256) void gather_cs_k(
    const float* __restrict__ ci, const float* __restrict__ si,
    const int* __restrict__ wi, float* __restrict__ co, float* __restrict__ so) {
  int t = blockIdx.x * 256 + threadIdx.x;          // NTOK*20 float4 groups
  if (t >= NTOK * 20) return;
  int i = t / 20, c4 = t - i * 20;
  int s = wi[i >> 2] * 4 + (i & 3);
  *(float4*)(co + (size_t)i * 80 + c4 * 4) = *(const float4*)(ci + (size_t)s * 80 + c4 * 4);
  *(float4*)(so + (size_t)i * 80 + c4 * 4) = *(const float4*)(si + (size_t)s * 80 + c4 * 4);
}

// ---------------------------------------------------------------- weight f32[K][N] -> bf16[N][K]
__global__ __launch_bounds__(256) void twt_k(
    const float* __restrict__ W, u16* __restrict__ Wt, int K, int N) {
  __shared__ u16 t[32][33];
  int bn = blockIdx.x * 32, bk = blockIdx.y * 32;
  int tx = threadIdx.x & 31, ty = threadIdx.x >> 5;   // ty 0..7
  #pragma unroll
  for (int r = 0; r < 4; r++) {
    int k = bk + ty + r * 8;
    t[tx][ty + r * 8] = f2bf(W[(size_t)k * N + bn + tx]);
  }
  __syncthreads();
  #pragma unroll
  for (int r = 0; r < 4; r++) {
    int n = bn + ty + r * 8;
    Wt[(size_t)n * K + bk + tx] = t[ty + r * 8][tx];
  }
}

// weight f32[K][N] -> bf16 interleaved rows: Wt[(2n+ph)][K]
__global__ __launch_bounds__(256) void twt2_k(
    const float* __restrict__ W, u16* __restrict__ Wt, int K, int N, int ph) {
  __shared__ u16 t[32][33];
  int bn = blockIdx.x * 32, bk = blockIdx.y * 32;
  int tx = threadIdx.x & 31, ty = threadIdx.x >> 5;
  #pragma unroll
  for (int r = 0; r < 4; r++) {
    int k = bk + ty + r * 8;
    t[tx][ty + r * 8] = f2bf(W[(size_t)k * N + bn + tx]);
  }
  __syncthreads();
  #pragma unroll
  for (int r = 0; r < 4; r++) {
    int n = bn + ty + r * 8;
    Wt[(size_t)(2 * n + ph) * K + bk + tx] = t[ty + r * 8][tx];
  }
}

// ---------------------------------------------------------------- rmsnorm (bf16 in -> bf16 out), 8-wide vectorized
__global__ __launch_bounds__(256) void rmsnorm_k(
    const u16* __restrict__ x, const float* __restrict__ w, u16* __restrict__ out, int D) {
  int row = blockIdx.x;
  const uint4* xr = (const uint4*)(x + (size_t)row * D);   // 8 bf16 per uint4
  int D8 = D >> 3;
  float ss = 0.f;
  for (int c = threadIdx.x; c < D8; c += 256) {
    uint4 v = xr[c];
    const unsigned vv[4] = {v.x, v.y, v.z, v.w};
    #pragma unroll
    for (int e = 0; e < 4; e++) {
      float a = bf2f((u16)(vv[e] & 0xffff));
      float b = bf2f((u16)(vv[e] >> 16));
      ss += a * a + b * b;
    }
  }
  #pragma unroll
  for (int d = 1; d < 64; d <<= 1) ss += __shfl_xor(ss, d, 64);
  __shared__ float part[4];
  if ((threadIdx.x & 63) == 0) part[threadIdx.x >> 6] = ss;
  __syncthreads();
  float tot = part[0] + part[1] + part[2] + part[3];
  float scale = rsqrtf(tot / (float)D + 1e-6f);
  u16* orow = out + (size_t)row * D;
  const float4* wr = (const float4*)w;
  for (int c = threadIdx.x; c < D8; c += 256) {
    uint4 v = xr[c];
    float4 w0 = wr[c * 2], w1 = wr[c * 2 + 1];
    const unsigned vv[4] = {v.x, v.y, v.z, v.w};
    const float wf[8] = {w0.x, w0.y, w0.z, w0.w, w1.x, w1.y, w1.z, w1.w};
    uint4 r;
    unsigned rr[4];
    #pragma unroll
    for (int e = 0; e < 4; e++) {
      float a = bf2f((u16)(vv[e] & 0xffff)) * scale * wf[e * 2];
      float b = bf2f((u16)(vv[e] >> 16)) * scale * wf[e * 2 + 1];
      rr[e] = (unsigned)f2bf(a) | ((unsigned)f2bf(b) << 16);
    }
    r.x = rr[0]; r.y = rr[1]; r.z = rr[2]; r.w = rr[3];
    *(uint4*)(orow + c * 8) = r;
  }
}

// ---------------------------------------------------------------- 8-phase GEMM, tile TM x 256 (TM=256 or 128)
// C = A(bf16 [M][K]) @ Bt(bf16 [N][K])^T + bias. 512 threads, 8 waves (2M x 4N).
// FRAGMENT-READ DEDUP (r18 schedule); hoisted stage addressing (r20);
// SUPERTILE ordering (r21): id -> (super, bn, bmi), bm = super*SB + bmi.
// TM=256: 2 LDS buffers, 4 phases/K-tile; vmcnt {6,6,6,6}; BARRIER-LEAN (r22):
//   only SYNC1's barrier per phase (4 barriers/K-tile, was 8). WAR proof: every
//   read of buf(t-1) completes at its wave's lgkm0 inside its phase's SYNC1,
//   which precedes that wave reaching the next SYNC1 barrier; the overwriting
//   stage issues only after >=2 later SYNC1 barriers -> transitively ordered.
//   RAW unchanged (stage counts/order identical, vmcnt ledger identical).
// TM=128: 3 LDS buffers, lean 2 phases/K-tile (closing barrier KEPT — its WAR
//   proof depends on it).
// LDS: A/B XOR-swizzled 16B chunks; linear gload_lds dest + pre-swizzled source.
// MODE 0: bf16 store; 1: f32; 3: gelu->bf16; 4: f32 scatter rows;
// MODE 6: fused gate/up (interleaved B rows; silu(gate)*up -> bf16 out[R][N/2]);
// MODE 7: bf16 residual RMW: h[R][Cc] = bf16(bf2f(h) + v)
template <int MODE, int TM>
__global__ __launch_bounds__(512, 2) void gemm8_k(
    const u16* __restrict__ A, const u16* __restrict__ Bt, const float* __restrict__ bias,
    const float* __restrict__ bias2, void* __restrict__ outp, const int* __restrict__ rowmap,
    int nbn, int sb, int N, int K) {
  constexpr int MF = TM / 64;                 // A frags per half (4 or 2)
  constexpr unsigned ABUFSZ = (unsigned)TM * 128u;   // bytes per A buf
  constexpr int NBUF = (TM == 256) ? 2 : 3;
  constexpr unsigned BBASE = (unsigned)NBUF * ABUFSZ;
  __shared__ __align__(16) u16 LDS[(TM == 256) ? 65536 : 73728];
  const int tid = threadIdx.x;
  const int w = tid >> 6, lane = tid & 63;
  const int wm = w >> 2, wn = w & 3;
  const int lr = lane & 15, lk = lane >> 4, lrm = lr & 7;
  const int NT = K >> 6;
  const size_t Kb = (size_t)K * 2;
  const int l8 = lane >> 3, l7 = lane & 7;
  const int schunk = l7 ^ l8;                 // pre-swizzled source chunk

  // -------- bijective XCD-chunked tile decode (m204)
  const int nwg = gridDim.x;
  const int q8 = nwg >> 3, r8 = nwg & 7;
  const int xcd = blockIdx.x & 7, ord = blockIdx.x >> 3;
  const int id = (xcd < r8 ? xcd * (q8 + 1) : r8 * (q8 + 1) + (xcd - r8) * q8) + ord;
  // -------- supertile decode: (super, bn, bmi); bm = super*sb + bmi
  const int spt = sb * nbn;
  const int super = id / spt;
  const int rem = id - super * spt;
  const int bn = rem / sb;
  const int bm = super * sb + (rem - bn * sb);

  const unsigned wm16lr = (unsigned)(wm * 16 + lr) * 128u;
  const unsigned wn16lr = (unsigned)(wn * 16 + lr) * 128u;
  unsigned ch[2];
  ch[0] = (unsigned)(((lk) ^ lrm) << 4);
  ch[1] = (unsigned)(((4 + lk) ^ lrm) << 4);
  const char* LB = (const char*)&LDS[0];

  f32x4 acc[2 * MF][4];
  #pragma unroll
  for (int f = 0; f < 2 * MF; f++)
    #pragma unroll
    for (int n = 0; n < 4; n++) { acc[f][n][0]=0.f; acc[f][n][1]=0.f; acc[f][n][2]=0.f; acc[f][n][3]=0.f; }

  const char* Ab = (const char*)A;
  const char* Bb = (const char*)Bt;
  u16* LDSp = &LDS[0];

  // hoisted per-lane global base pointers (src = base + tt*128)
  const char* aSrc[2][2];
  const char* bSrc[2][2];
  #pragma unroll
  for (int half = 0; half < 2; half++) {
    if constexpr (TM == 256) {
      #pragma unroll
      for (int i = 0; i < 2; i++) {
        int gr = bm * 256 + half * 128 + i * 64 + w * 8 + l8;
        aSrc[half][i] = Ab + (size_t)gr * Kb + schunk * 16;
      }
    } else {
      int gr = bm * 128 + half * 64 + w * 8 + l8;
      aSrc[half][0] = Ab + (size_t)gr * Kb + schunk * 16;
      aSrc[half][1] = aSrc[half][0];
    }
    #pragma unroll
    for (int i = 0; i < 2; i++) {
      int gr = bn * 256 + half * 128 + i * 64 + w * 8 + l8;
      if (gr >= N) gr = N - 1;
      bSrc[half][i] = Bb + (size_t)gr * Kb + schunk * 16;
    }
  }

  // persistent fragment registers (dedup: each LDS fragment read once per K-tile)
  bf16x8 afE[MF][2], afO[MF][2], bfE[2][2], bfO[2][2];

  // stage one half-tile. isB: operand; half: 0/1; tt: K-tile; bb: lds buf
  auto STAGE = [&](int isB, int half, int tt, int bb) {
    long k0b = (long)tt * 128;
    if (!isB) {
      if constexpr (TM == 256) {
        #pragma unroll
        for (int i = 0; i < 2; i++) {
          int r0 = half * 128 + i * 64 + w * 8;
          unsigned dst = (unsigned)bb * ABUFSZ + (unsigned)r0 * 128u;
          gload_lds16((const u16*)(aSrc[half][i] + k0b), LDSp + dst / 2);
        }
      } else {
        int r0 = half * 64 + w * 8;
        unsigned dst = (unsigned)bb * ABUFSZ + (unsigned)r0 * 128u;
        gload_lds16((const u16*)(aSrc[half][0] + k0b), LDSp + dst / 2);
      }
    } else {
      #pragma unroll
      for (int i = 0; i < 2; i++) {
        int r0 = half * 128 + i * 64 + w * 8;
        unsigned dst = BBASE + (unsigned)bb * 32768u + (unsigned)r0 * 128u;
        gload_lds16((const u16*)(bSrc[half][i] + k0b), LDSp + dst / 2);
      }
    }
  };

#define QREAD_A(DST, MH, ABUF)                                                      \
    _Pragma("unroll") for (int f = 0; f < MF; f++) {                                \
      _Pragma("unroll") for (int kk = 0; kk < 2; kk++) {                            \
        unsigned ad = (ABUF) + (unsigned)((MH) * MF + f) * 4096u + wm16lr + ch[kk]; \
        DST[f][kk] = *(const bf16x8*)(LB + ad);                                     \
      }                                                                             \
    }

#define QREAD_B(DST, NH, BBUF)                                                      \
    _Pragma("unroll") for (int n = 0; n < 2; n++) {                                 \
      _Pragma("unroll") for (int kk = 0; kk < 2; kk++) {                            \
        unsigned ad = BBASE + (BBUF) + (unsigned)((NH) * 2 + n) * 8192u + wn16lr + ch[kk]; \
        DST[n][kk] = *(const bf16x8*)(LB + ad);                                     \
      }                                                                             \
    }

#define QMFMA(AF, BF, MH, NH)                                                       \
    __builtin_amdgcn_s_setprio(1);                                                  \
    _Pragma("unroll") for (int kk = 0; kk < 2; kk++) {                              \
      _Pragma("unroll") for (int f = 0; f < MF; f++) {                              \
        _Pragma("unroll") for (int n = 0; n < 2; n++) {                             \
          acc[(MH) * MF + f][(NH) * 2 + n] = __builtin_amdgcn_mfma_f32_16x16x32_bf16( \
              AF[f][kk], BF[n][kk], acc[(MH) * MF + f][(NH) * 2 + n], 0, 0, 0);     \
        }                                                                           \
      }                                                                             \
    }                                                                               \
    __builtin_amdgcn_s_setprio(0);

#define SYNC1(VM)                                                                   \
    asm volatile("s_waitcnt vmcnt(" #VM ")" ::: "memory");                          \
    __builtin_amdgcn_s_barrier();                                                   \
    asm volatile("s_waitcnt lgkmcnt(0)" ::: "memory");                              \
    __builtin_amdgcn_sched_barrier(0);

#define LGKM0                                                                       \
    asm volatile("s_waitcnt lgkmcnt(0)" ::: "memory");                              \
    __builtin_amdgcn_sched_barrier(0);

#define SBAR0 __builtin_amdgcn_sched_barrier(0);

#define SYNC2                                                                       \
    __builtin_amdgcn_s_barrier();                                                   \
    __builtin_amdgcn_sched_barrier(0);

  if constexpr (TM == 256) {
    // prologue: stage tile 0 fully into buf 0 (events: A0,B0,A1,B1)
    STAGE(0, 0, 0, 0);
    STAGE(1, 0, 0, 0);
    STAGE(0, 1, 0, 0);
    STAGE(1, 1, 0, 0);
    for (int t = 0; t < NT; t++) {
      const unsigned aob  = (unsigned)(t & 1) * ABUFSZ;
      const unsigned bob  = (unsigned)(t & 1) * 32768u;
      const int bb1 = (t + 1) & 1;
      const int tn = (t + 1 < NT) ? (t + 1) : 0;       // clamp dummy stage source
      // ---- phase 0: (A1,B1) of tile t-1 — no LDS reads
      {
        STAGE(0, 0, tn, bb1);
        SYNC1(6)
        if (t > 0) { QMFMA(afO, bfO, 1, 1) }
        SBAR0
      }
      // ---- phase 1: (A0,B0)
      {
        QREAD_A(afE, 0, aob)
        QREAD_B(bfE, 0, bob)
        STAGE(1, 0, tn, bb1);
        SYNC1(6)
        QMFMA(afE, bfE, 0, 0)
        SBAR0
      }
      // ---- phase 2: (A1,B0)
      {
        QREAD_A(afO, 1, aob)
        STAGE(0, 1, tn, bb1);
        SYNC1(6)
        QMFMA(afO, bfE, 1, 0)
        SBAR0
      }
      // ---- phase 3: (A0,B1)
      {
        QREAD_B(bfO, 1, bob)
        STAGE(1, 1, tn, bb1);
        SYNC1(6)
        QMFMA(afE, bfO, 0, 1)
        SBAR0
      }
    }
    // tail: (A1,B1) of tile NT-1
    QMFMA(afO, bfO, 1, 1)
  } else {
    // TM=128: 3-buffer rotation, lean 2-phase. Stage tile t+2 during tile t.
    // prologue: tile 0 -> buf 0, tile 1 -> buf 1 (12 loads); drain tile 0.
    STAGE(0, 0, 0, 0);
    STAGE(1, 0, 0, 0);
    STAGE(0, 1, 0, 0);
    STAGE(1, 1, 0, 0);
    STAGE(0, 0, 1, 1);
    STAGE(1, 0, 1, 1);
    STAGE(0, 1, 1, 1);
    STAGE(1, 1, 1, 1);
    asm volatile("s_waitcnt vmcnt(6)" ::: "memory");
    __builtin_amdgcn_s_barrier();
    __builtin_amdgcn_sched_barrier(0);
    int cb = 0;                                        // buf of tile t
    for (int t = 0; t < NT; t++) {
      const unsigned aob = (unsigned)cb * ABUFSZ;
      const unsigned bob = (unsigned)cb * 32768u;
      int sbuf = cb + 2; if (sbuf >= 3) sbuf -= 3;     // buf of tile t+2 (== buf of t-1)
      const int tn = (t + 2 < NT) ? (t + 2) : t;       // clamp dummy stage source
      // ---- phase A: read A0,A1,B0 of t; stage alpha(t+2); MFMA (A0+A1)xB0
      QREAD_A(afE, 0, aob)
      QREAD_A(afO, 1, aob)
      QREAD_B(bfE, 0, bob)
      STAGE(0, 0, tn, sbuf);
      STAGE(1, 0, tn, sbuf);
      LGKM0
      QMFMA(afE, bfE, 0, 0)
      QMFMA(afO, bfE, 1, 0)
      // ---- phase B: read B1 of t; stage beta(t+2); vmcnt(6); bar; MFMA (A0+A1)xB1
      QREAD_B(bfO, 1, bob)
      STAGE(0, 1, tn, sbuf);
      STAGE(1, 1, tn, sbuf);
      asm volatile("s_waitcnt vmcnt(6)" ::: "memory");
      __builtin_amdgcn_s_barrier();
      LGKM0
      QMFMA(afE, bfO, 0, 1)
      QMFMA(afO, bfO, 1, 1)
      SYNC2
      cb++; if (cb == 3) cb = 0;
    }
  }
#undef QREAD_A
#undef QREAD_B
#undef QMFMA
#undef SYNC1
#undef LGKM0
#undef SBAR0
#undef SYNC2

  // epilogue
  #pragma unroll
  for (int nf = 0; nf < 4; nf++) {
    int Cc = bn * 256 + nf * 64 + wn * 16 + lr;
    bool ok = (Cc < N);
    float bv = 0.f;
    if (MODE == 6) {
      bv = ((lr & 1) == 0) ? bias[Cc >> 1] : bias2[Cc >> 1];
    } else if (bias && ok) {
      bv = bias[Cc];
    }
    #pragma unroll
    for (int mf = 0; mf < 2 * MF; mf++) {
      #pragma unroll
      for (int j = 0; j < 4; j++) {
        int R = bm * TM + mf * 32 + wm * 16 + lk * 4 + j;
        float v = acc[mf][nf][j] + bv;
        if (MODE == 6) {
          float vp = __shfl_xor(v, 1, 64);   // partner column (Cc^1)
          if ((lr & 1) == 0) {
            float s = v / (1.f + __expf(-v));   // silu(gate)
            ((u16*)outp)[(size_t)R * (N >> 1) + (Cc >> 1)] = f2bf(s * vp);
          }
        } else if (ok) {
          if (MODE == 0) {
            ((u16*)outp)[(size_t)R * N + Cc] = f2bf(v);
          } else if (MODE == 1) {
            ((float*)outp)[(size_t)R * N + Cc] = v;
          } else if (MODE == 3) {
            ((u16*)outp)[(size_t)R * N + Cc] = f2bf(gelu_tanh(v));
          } else if (MODE == 4) {
            int orow = rowmap[R];
            ((float*)outp)[(size_t)orow * N + Cc] = v;
          } else if (MODE == 7) {
            u16* hp = (u16*)outp + (size_t)R * N + Cc;
            *hp = f2bf(bf2f(*hp) + v);
          }
        }
      }
    }
  }
}

// ---------------------------------------------------------------- windowed attention with fused RoPE
__global__ __launch_bounds__(256, 2) void attn_k(
    const u16* __restrict__ qkv, u16* __restrict__ outO,
    const float* __restrict__ cosr, const float* __restrict__ sinr) {
  __shared__ u16 Qs[64 * 104];
  __shared__ u16 Ks[64 * 104];
  __shared__ u16 Vt[80 * 72];
  __shared__ u16 Ps[64 * 72];
  const int w = blockIdx.x, hd = blockIdx.y;
  const int tid = threadIdx.x;
  const u16* base = qkv + (size_t)w * 64 * 3840 + hd * 80;

  // RoPE staging: one thread per (row, c<40) pair computes both rotated halves
  for (int idx = tid; idx < 64 * 40; idx += 256) {
    int r = idx / 40, c = idx - r * 40;
    int tokg = w * 64 + r;
    const float* cr = cosr + (size_t)tokg * 80;
    const float* sr = sinr + (size_t)tokg * 80;
    float c0 = cr[c], c1 = cr[c + 40], s0 = sr[c], s1 = sr[c + 40];
    const u16* rp = base + (size_t)r * 3840;
    float q0 = bf2f(rp[c]), q1 = bf2f(rp[c + 40]);
    float k0 = bf2f(rp[1280 + c]), k1 = bf2f(rp[1280 + c + 40]);
    Qs[r * 104 + c]      = f2bf(q0 * c0 - q1 * s0);
    Qs[r * 104 + c + 40] = f2bf(q1 * c1 + q0 * s1);
    Ks[r * 104 + c]      = f2bf(k0 * c0 - k1 * s0);
    Ks[r * 104 + c + 40] = f2bf(k1 * c1 + k0 * s1);
  }
  for (int idx = tid; idx < 64 * 16; idx += 256) {
    int r = idx >> 4, c = 80 + (idx & 15);
    Qs[r * 104 + c] = 0;
    Ks[r * 104 + c] = 0;
  }
  for (int idx = tid; idx < 80 * 64; idx += 256) {
    int d = idx >> 6, kt = idx & 63;
    Vt[d * 72 + kt] = base[(size_t)kt * 3840 + 2560 + d];
  }
  __syncthreads();

  const int lane = tid & 63, wv = tid >> 6;
  const int lr = lane & 15, lk = lane >> 4;
  const float sc = 0.11180339887498949f;  // 80^-0.5

  f32x4 sfrag[4];
  #pragma unroll
  for (int f = 0; f < 4; f++) { sfrag[f][0]=0.f; sfrag[f][1]=0.f; sfrag[f][2]=0.f; sfrag[f][3]=0.f; }
  bf16x8 aq[3];
  #pragma unroll
  for (int ks = 0; ks < 3; ks++) aq[ks] = *(const bf16x8*)&Qs[(wv * 16 + lr) * 104 + ks * 32 + lk * 8];
  #pragma unroll
  for (int fn = 0; fn < 4; fn++) {
    #pragma unroll
    for (int ks = 0; ks < 3; ks++) {
      bf16x8 bk = *(const bf16x8*)&Ks[(fn * 16 + lr) * 104 + ks * 32 + lk * 8];
      sfrag[fn] = __builtin_amdgcn_mfma_f32_16x16x32_bf16(aq[ks], bk, sfrag[fn], 0, 0, 0);
    }
  }

  float inv[4];
  #pragma unroll
  for (int j = 0; j < 4; j++) {
    float mx = -1e30f;
    #pragma unroll
    for (int fn = 0; fn < 4; fn++) mx = fmaxf(mx, sfrag[fn][j] * sc);
    #pragma unroll
    for (int d = 1; d < 16; d <<= 1) mx = fmaxf(mx, __shfl_xor(mx, d, 64));
    float sum = 0.f;
    #pragma unroll
    for (int fn = 0; fn < 4; fn++) {
      float e = __expf(sfrag[fn][j] * sc - mx);
      Ps[(wv * 16 + lk * 4 + j) * 72 + fn * 16 + lr] = f2bf(e);
      sum += e;
    }
    #pragma unroll
    for (int d = 1; d < 16; d <<= 1) sum += __shfl_xor(sum, d, 64);
    inv[j] = 1.0f / sum;
  }
  __syncthreads();

  bf16x8 ap[2];
  #pragma unroll
  for (int ks = 0; ks < 2; ks++) ap[ks] = *(const bf16x8*)&Ps[(wv * 16 + lr) * 72 + ks * 32 + lk * 8];
  f32x4 of[5];
  #pragma unroll
  for (int f = 0; f < 5; f++) { of[f][0]=0.f; of[f][1]=0.f; of[f][2]=0.f; of[f][3]=0.f; }
  #pragma unroll
  for (int fn2 = 0; fn2 < 5; fn2++) {
    #pragma unroll
    for (int ks = 0; ks < 2; ks++) {
      bf16x8 bv = *(const bf16x8*)&Vt[(fn2 * 16 + lr) * 72 + ks * 32 + lk * 8];
      of[fn2] = __builtin_amdgcn_mfma_f32_16x16x32_bf16(ap[ks], bv, of[fn2], 0, 0, 0);
    }
  }

  #pragma unroll
  for (int fn2 = 0; fn2 < 5; fn2++) {
    #pragma unroll
    for (int j = 0; j < 4; j++) {
      int q = wv * 16 + lk * 4 + j;
      int d = fn2 * 16 + lr;
      outO[((size_t)(w * 64 + q)) * 1280 + hd * 80 + d] = f2bf(of[fn2][j] * inv[j]);
    }
  }
}

// ---------------------------------------------------------------- host
extern "C" void kernel_launch(void* const* d_in, const int* in_sizes, int n_in,
                              void* d_out, int out_size, void* d_ws, size_t ws_size,
                              hipStream_t stream) {
  (void)in_sizes; (void)n_in; (void)out_size; (void)ws_size;
  const float* pv   = (const float*)d_in[0];
  const float* cosi = (const float*)d_in[1];
  const float* sini = (const float*)d_in[2];
  const int*   wi   = (const int*)d_in[3];
  const float* Wp   = (const float*)d_in[4];
  const float* n1w  = (const float*)d_in[5];
  const float* qkvw = (const float*)d_in[6];
  const float* qkvb = (const float*)d_in[7];
  const float* pw   = (const float*)d_in[8];
  const float* pb   = (const float*)d_in[9];
  const float* n2w  = (const float*)d_in[10];
  const float* gw   = (const float*)d_in[11];
  const float* gb   = (const float*)d_in[12];
  const float* uw   = (const float*)d_in[13];
  const float* ub   = (const float*)d_in[14];
  const float* dw   = (const float*)d_in[15];
  const float* db   = (const float*)d_in[16];
  const float* mnw  = (const float*)d_in[17];
  const float* ml1w = (const float*)d_in[18];
  const float* ml1b = (const float*)d_in[19];
  const float* ml2w = (const float*)d_in[20];
  const float* ml2b = (const float*)d_in[21];
  const float* dnw  = (const float*)d_in[22];
  const float* dl1w = (const float*)d_in[23];
  const float* dl1b = (const float*)d_in[24];
  const float* dl2w = (const float*)d_in[25];
  const float* dl2b = (const float*)d_in[26];
  float* outv = (float*)d_out;
  char* ws = (char*)d_ws;

  size_t off = 0;
  u16*  h     = (u16*)(ws + off);  off += (size_t)NTOK * HID_ * 2;       // 42MB (bf16 residual)
  float* cosr = (float*)(ws + off); off += (size_t)NTOK * 80 * 4;
  float* sinr = (float*)(ws + off); off += (size_t)NTOK * 80 * 4;
  u16*  xb    = (u16*)(ws + off);  off += (size_t)NTOK * HID_ * 2;       // 42MB
  u16*  bufA  = (u16*)(ws + off);  off += (size_t)NTOK * 3840 * 2;       // 126MB
  u16*  bufB  = (u16*)(ws + off);  off += (size_t)NTOK * INTER_ * 2;     // 113MB
  u16*  bufC  = (u16*)(ws + off);  off += (size_t)NTOK * HID_ * 2;       // 42MB
  u16*  Wt    = (u16*)(ws + off);  off += (size_t)BIGD * BIGD * 2;       // 52.5MB

  dim3 B256(256), B512(512);
  // supertile depth: SB=4 for K<=1536 (A panels small), else 2 (fits 4MB L2)
  #define SBOF(K_) (((K_) <= 1536) ? 4 : 2)
  #define TW(src, K_, N_) twt_k<<<dim3((N_) / 32, (K_) / 32), B256, 0, stream>>>((src), Wt, (K_), (N_))
  #define G8(MODE, TM_, Abuf, bias_, bias2_, out_, rmap_, M_, N_, K_)                     \
    gemm8_k<MODE, TM_><<<dim3(((M_) / (TM_)) * (((N_) + 255) / 256)), B512, 0, stream>>>( \
        (Abuf), Wt, (bias_), (bias2_), (out_), (rmap_), (((N_) + 255) / 256), SBOF(K_),   \
        (N_), (K_))

  // gather pixel rows + cos/sin
  gather_pv_k<<<(NTOK * 384 + 255) / 256, B256, 0, stream>>>(pv, wi, bufA);
  gather_cs_k<<<(NTOK * 20 + 255) / 256, B256, 0, stream>>>(cosi, sini, wi, cosr, sinr);

  // h = pv_g @ W_patch   (bf16 residual stream)
  TW(Wp, 1536, HID_);
  G8(0, 128, bufA, nullptr, nullptr, h, nullptr, NTOK, HID_, 1536);

  for (int i = 0; i < 6; i++) {
    // attn
    rmsnorm_k<<<NTOK, B256, 0, stream>>>(h, n1w + (size_t)i * HID_, xb, HID_);
    TW(qkvw + (size_t)i * HID_ * 3840, HID_, 3840);
    G8(0, 256, xb, qkvb + (size_t)i * 3840, nullptr, bufA, nullptr, NTOK, 3840, HID_);
    attn_k<<<dim3(256, 16), B256, 0, stream>>>(bufA, bufC, cosr, sinr);
    TW(pw + (size_t)i * HID_ * HID_, HID_, HID_);
    G8(7, 128, bufC, pb + (size_t)i * HID_, nullptr, h, nullptr, NTOK, HID_, HID_);
    // mlp: fused gate+up via interleaved weight columns (even=gate, odd=up)
    rmsnorm_k<<<NTOK, B256, 0, stream>>>(h, n2w + (size_t)i * HID_, xb, HID_);
    twt2_k<<<dim3(INTER_ / 32, HID_ / 32), B256, 0, stream>>>(
        gw + (size_t)i * HID_ * INTER_, Wt, HID_, INTER_, 0);
    twt2_k<<<dim3(INTER_ / 32, HID_ / 32), B256, 0, stream>>>(
        uw + (size_t)i * HID_ * INTER_, Wt, HID_, INTER_, 1);
    G8(6, 256, xb, gb + (size_t)i * INTER_, ub + (size_t)i * INTER_, bufA, nullptr,
       NTOK, 2 * INTER_, HID_);
    TW(dw + (size_t)i * INTER_ * HID_, INTER_, HID_);
    G8(7, 128, bufA, db + (size_t)i * HID_, nullptr, h, nullptr, NTOK, HID_, INTER_);
    // deepstack mergers after layers 2 and 4
    if (i == 2 || i == 4) {
      int j = (i == 2) ? 0 : 1;
      rmsnorm_k<<<NGRP, B256, 0, stream>>>(h, dnw + (size_t)j * BIGD, bufC, BIGD);
      TW(dl1w + (size_t)j * BIGD * BIGD, BIGD, BIGD);
      G8(3, 128, bufC, dl1b + (size_t)j * BIGD, nullptr, bufA, nullptr, NGRP, BIGD, BIGD);
      TW(dl2w + (size_t)j * BIGD * ODIM, BIGD, ODIM);
      G8(4, 128, bufA, dl2b + (size_t)j * ODIM, nullptr,
         outv + (size_t)(1 + j) * NGRP * ODIM, wi, NGRP, ODIM, BIGD);
    }
  }

  // final merger -> plane 0
  rmsnorm_k<<<NTOK, B256, 0, stream>>>(h, mnw, bufC, HID_);
  TW(ml1w, BIGD, BIGD);
  G8(3, 128, bufC, ml1b, nullptr, bufA, nullptr, NGRP, BIGD, BIGD);
  TW(ml2w, BIGD, ODIM);
  G8(4, 128, bufA, ml2b, nullptr, outv, wi, NGRP, ODIM, BIGD);
  #undef TW
  #undef G8
  #undef SBOF
}

// Round 23
// 6790.447 us; speedup vs baseline: 1.0406x; 1.0076x over previous
//
#include <hip/hip_runtime.h>
#include <hip/hip_bf16.h>

typedef unsigned short u16;
typedef __bf16 bf16x8 __attribute__((ext_vector_type(8)));
typedef float   f32x4 __attribute__((ext_vector_type(4)));
typedef unsigned short u16x8 __attribute__((ext_vector_type(8)));

#define NTOK  16384
#define HID_  1280
#define NHEAD 16
#define HD    80
#define INTER_ 3456
#define NGRP  4096
#define ODIM  2048
#define BIGD  5120

static __device__ __forceinline__ u16 f2bf(float f) {
  __hip_bfloat16 h = __float2bfloat16(f);
  return __builtin_bit_cast(u16, h);
}
static __device__ __forceinline__ float bf2f(u16 u) {
  return __bfloat162float(__builtin_bit_cast(__hip_bfloat16, u));
}
static __device__ __forceinline__ float gelu_tanh(float x) {
  float y = 0.7978845608028654f * (x + 0.044715f * x * x * x);
  float t = 1.0f - 2.0f / (1.0f + __expf(2.0f * y));   // tanh(y)
  return 0.5f * x * (1.0f + t);
}

// async global->LDS, 16B per lane, dest = wave-uniform base + lane*16
static __device__ __forceinline__ void gload_lds16(const u16* g, u16* l) {
  __builtin_amdgcn_global_load_lds(
      (const __attribute__((address_space(1))) unsigned int*)g,
      (__attribute__((address_space(3))) unsigned int*)l, 16, 0, 0);
}

// ---------------------------------------------------------------- gathers
__global__ __launch_bounds__(256) void gather_pv_k(
    const float* __restrict__ pv, const int* __restrict__ wi, u16* __restrict__ out) {
  int t = blockIdx.x * 256 + threadIdx.x;          // NTOK*384 float4 groups
  if (t >= NTOK * 384) return;
  int i = t / 384, c4 = t - i * 384;
  int s = wi[i >> 2] * 4 + (i & 3);
  float4 v = *(const float4*)(pv + (size_t)s * 1536 + c4 * 4);
  uint2 r;
  r.x = (unsigned)f2bf(v.x) | ((unsigned)f2bf(v.y) << 16);
  r.y = (unsigned)f2bf(v.z) | ((unsigned)f2bf(v.w) << 16);
  *(uint2*)(out + (size_t)i * 1536 + c4 * 4) = r;
}

__global__ __launch_bounds__(256) void gather_cs_k(
    const float* __restrict__ ci, const float* __restrict__ si,
    const int* __restrict__ wi, float* __restrict__ co, float* __restrict__ so) {
  int t = blockIdx.x * 256 + threadIdx.x;          // NTOK*20 float4 groups
  if (t >= NTOK * 20) return;
  int i = t / 20, c4 = t - i * 20;
  int s = wi[i >> 2] * 4 + (i & 3);
  *(float4*)(co + (size_t)i * 80 + c4 * 4) = *(const float4*)(ci + (size_t)s * 80 + c4 * 4);
  *(float4*)(so + (size_t)i * 80 + c4 * 4) = *(const float4*)(si + (size_t)s * 80 + c4 * 4);
}

// ---------------------------------------------------------------- weight f32[K][N] -> bf16[N][K]
__global__ __launch_bounds__(256) void twt_k(
    const float* __restrict__ W, u16* __restrict__ Wt, int K, int N) {
  __shared__ u16 t[32][33];
  int bn = blockIdx.x * 32, bk = blockIdx.y * 32;
  int tx = threadIdx.x & 31, ty = threadIdx.x >> 5;   // ty 0..7
  #pragma unroll
  for (int r = 0; r < 4; r++) {
    int k = bk + ty + r * 8;
    t[tx][ty + r * 8] = f2bf(W[(size_t)k * N + bn + tx]);
  }
  __syncthreads();
  #pragma unroll
  for (int r = 0; r < 4; r++) {
    int n = bn + ty + r * 8;
    Wt[(size_t)n * K + bk + tx] = t[ty + r * 8][tx];
  }
}

// batched per-layer transpose: 5 jobs in one launch.
// job0 qkv:  f32[1280][3840] -> oq[3840][1280]
// job1 proj: f32[1280][1280] -> op[1280][1280]
// job2 gate: f32[1280][3456] -> og[2n+0][1280]
// job3 up:   f32[1280][3456] -> og[2n+1][1280]
// job4 down: f32[3456][1280] -> od[1280][3456]
__global__ __launch_bounds__(256) void twtb_k(
    const float* __restrict__ q, const float* __restrict__ p, const float* __restrict__ g,
    const float* __restrict__ u, const float* __restrict__ d,
    u16* __restrict__ oq, u16* __restrict__ op, u16* __restrict__ og, u16* __restrict__ od) {
  __shared__ u16 t[32][33];
  const int job = blockIdx.y;
  const float* W; u16* O; int K, N, st, ph, nbn;
  if (job == 0)      { W = q; O = oq; K = 1280; N = 3840; st = 1; ph = 0; nbn = 120; }
  else if (job == 1) { W = p; O = op; K = 1280; N = 1280; st = 1; ph = 0; nbn = 40; }
  else if (job == 2) { W = g; O = og; K = 1280; N = 3456; st = 2; ph = 0; nbn = 108; }
  else if (job == 3) { W = u; O = og; K = 1280; N = 3456; st = 2; ph = 1; nbn = 108; }
  else               { W = d; O = od; K = 3456; N = 1280; st = 1; ph = 0; nbn = 40; }
  const int tIdx = blockIdx.x;
  const int bn = (tIdx % nbn) * 32;
  const int bk = (tIdx / nbn) * 32;
  if (bk >= K) return;
  const int tx = threadIdx.x & 31, ty = threadIdx.x >> 5;
  #pragma unroll
  for (int r = 0; r < 4; r++) {
    int k = bk + ty + r * 8;
    t[tx][ty + r * 8] = f2bf(W[(size_t)k * N + bn + tx]);
  }
  __syncthreads();
  #pragma unroll
  for (int r = 0; r < 4; r++) {
    int n = bn + ty + r * 8;
    O[(size_t)(n * st + ph) * K + bk + tx] = t[ty + r * 8][tx];
  }
}

// ---------------------------------------------------------------- rmsnorm (bf16 in -> bf16 out), 8-wide vectorized
__global__ __launch_bounds__(256) void rmsnorm_k(
    const u16* __restrict__ x, const float* __restrict__ w, u16* __restrict__ out, int D) {
  int row = blockIdx.x;
  const uint4* xr = (const uint4*)(x + (size_t)row * D);   // 8 bf16 per uint4
  int D8 = D >> 3;
  float ss = 0.f;
  for (int c = threadIdx.x; c < D8; c += 256) {
    uint4 v = xr[c];
    const unsigned vv[4] = {v.x, v.y, v.z, v.w};
    #pragma unroll
    for (int e = 0; e < 4; e++) {
      float a = bf2f((u16)(vv[e] & 0xffff));
      float b = bf2f((u16)(vv[e] >> 16));
      ss += a * a + b * b;
    }
  }
  #pragma unroll
  for (int d = 1; d < 64; d <<= 1) ss += __shfl_xor(ss, d, 64);
  __shared__ float part[4];
  if ((threadIdx.x & 63) == 0) part[threadIdx.x >> 6] = ss;
  __syncthreads();
  float tot = part[0] + part[1] + part[2] + part[3];
  float scale = rsqrtf(tot / (float)D + 1e-6f);
  u16* orow = out + (size_t)row * D;
  const float4* wr = (const float4*)w;
  for (int c = threadIdx.x; c < D8; c += 256) {
    uint4 v = xr[c];
    float4 w0 = wr[c * 2], w1 = wr[c * 2 + 1];
    const unsigned vv[4] = {v.x, v.y, v.z, v.w};
    const float wf[8] = {w0.x, w0.y, w0.z, w0.w, w1.x, w1.y, w1.z, w1.w};
    uint4 r;
    unsigned rr[4];
    #pragma unroll
    for (int e = 0; e < 4; e++) {
      float a = bf2f((u16)(vv[e] & 0xffff)) * scale * wf[e * 2];
      float b = bf2f((u16)(vv[e] >> 16)) * scale * wf[e * 2 + 1];
      rr[e] = (unsigned)f2bf(a) | ((unsigned)f2bf(b) << 16);
    }
    r.x = rr[0]; r.y = rr[1]; r.z = rr[2]; r.w = rr[3];
    *(uint4*)(orow + c * 8) = r;
  }
}

// ---------------------------------------------------------------- 8-phase GEMM, tile TM x 256 (TM=256 or 128)
// (r22 kernel, unchanged: dedup reads, hoisted addressing, supertile ordering,
//  barrier-lean TM=256 4-phase, lean TM=128 2-phase with 3 buffers.)
template <int MODE, int TM>
__global__ __launch_bounds__(512, 2) void gemm8_k(
    const u16* __restrict__ A, const u16* __restrict__ Bt, const float* __restrict__ bias,
    const float* __restrict__ bias2, void* __restrict__ outp, const int* __restrict__ rowmap,
    int nbn, int sb, int N, int K) {
  constexpr int MF = TM / 64;                 // A frags per half (4 or 2)
  constexpr unsigned ABUFSZ = (unsigned)TM * 128u;   // bytes per A buf
  constexpr int NBUF = (TM == 256) ? 2 : 3;
  constexpr unsigned BBASE = (unsigned)NBUF * ABUFSZ;
  __shared__ __align__(16) u16 LDS[(TM == 256) ? 65536 : 73728];
  const int tid = threadIdx.x;
  const int w = tid >> 6, lane = tid & 63;
  const int wm = w >> 2, wn = w & 3;
  const int lr = lane & 15, lk = lane >> 4, lrm = lr & 7;
  const int NT = K >> 6;
  const size_t Kb = (size_t)K * 2;
  const int l8 = lane >> 3, l7 = lane & 7;
  const int schunk = l7 ^ l8;                 // pre-swizzled source chunk

  // -------- bijective XCD-chunked tile decode (m204)
  const int nwg = gridDim.x;
  const int q8 = nwg >> 3, r8 = nwg & 7;
  const int xcd = blockIdx.x & 7, ord = blockIdx.x >> 3;
  const int id = (xcd < r8 ? xcd * (q8 + 1) : r8 * (q8 + 1) + (xcd - r8) * q8) + ord;
  // -------- supertile decode: (super, bn, bmi); bm = super*sb + bmi
  const int spt = sb * nbn;
  const int super = id / spt;
  const int rem = id - super * spt;
  const int bn = rem / sb;
  const int bm = super * sb + (rem - bn * sb);

  const unsigned wm16lr = (unsigned)(wm * 16 + lr) * 128u;
  const unsigned wn16lr = (unsigned)(wn * 16 + lr) * 128u;
  unsigned ch[2];
  ch[0] = (unsigned)(((lk) ^ lrm) << 4);
  ch[1] = (unsigned)(((4 + lk) ^ lrm) << 4);
  const char* LB = (const char*)&LDS[0];

  f32x4 acc[2 * MF][4];
  #pragma unroll
  for (int f = 0; f < 2 * MF; f++)
    #pragma unroll
    for (int n = 0; n < 4; n++) { acc[f][n][0]=0.f; acc[f][n][1]=0.f; acc[f][n][2]=0.f; acc[f][n][3]=0.f; }

  const char* Ab = (const char*)A;
  const char* Bb = (const char*)Bt;
  u16* LDSp = &LDS[0];

  // hoisted per-lane global base pointers (src = base + tt*128)
  const char* aSrc[2][2];
  const char* bSrc[2][2];
  #pragma unroll
  for (int half = 0; half < 2; half++) {
    if constexpr (TM == 256) {
      #pragma unroll
      for (int i = 0; i < 2; i++) {
        int gr = bm * 256 + half * 128 + i * 64 + w * 8 + l8;
        aSrc[half][i] = Ab + (size_t)gr * Kb + schunk * 16;
      }
    } else {
      int gr = bm * 128 + half * 64 + w * 8 + l8;
      aSrc[half][0] = Ab + (size_t)gr * Kb + schunk * 16;
      aSrc[half][1] = aSrc[half][0];
    }
    #pragma unroll
    for (int i = 0; i < 2; i++) {
      int gr = bn * 256 + half * 128 + i * 64 + w * 8 + l8;
      if (gr >= N) gr = N - 1;
      bSrc[half][i] = Bb + (size_t)gr * Kb + schunk * 16;
    }
  }

  // persistent fragment registers (dedup: each LDS fragment read once per K-tile)
  bf16x8 afE[MF][2], afO[MF][2], bfE[2][2], bfO[2][2];

  // stage one half-tile. isB: operand; half: 0/1; tt: K-tile; bb: lds buf
  auto STAGE = [&](int isB, int half, int tt, int bb) {
    long k0b = (long)tt * 128;
    if (!isB) {
      if constexpr (TM == 256) {
        #pragma unroll
        for (int i = 0; i < 2; i++) {
          int r0 = half * 128 + i * 64 + w * 8;
          unsigned dst = (unsigned)bb * ABUFSZ + (unsigned)r0 * 128u;
          gload_lds16((const u16*)(aSrc[half][i] + k0b), LDSp + dst / 2);
        }
      } else {
        int r0 = half * 64 + w * 8;
        unsigned dst = (unsigned)bb * ABUFSZ + (unsigned)r0 * 128u;
        gload_lds16((const u16*)(aSrc[half][0] + k0b), LDSp + dst / 2);
      }
    } else {
      #pragma unroll
      for (int i = 0; i < 2; i++) {
        int r0 = half * 128 + i * 64 + w * 8;
        unsigned dst = BBASE + (unsigned)bb * 32768u + (unsigned)r0 * 128u;
        gload_lds16((const u16*)(bSrc[half][i] + k0b), LDSp + dst / 2);
      }
    }
  };

#define QREAD_A(DST, MH, ABUF)                                                      \
    _Pragma("unroll") for (int f = 0; f < MF; f++) {                                \
      _Pragma("unroll") for (int kk = 0; kk < 2; kk++) {                            \
        unsigned ad = (ABUF) + (unsigned)((MH) * MF + f) * 4096u + wm16lr + ch[kk]; \
        DST[f][kk] = *(const bf16x8*)(LB + ad);                                     \
      }                                                                             \
    }

#define QREAD_B(DST, NH, BBUF)                                                      \
    _Pragma("unroll") for (int n = 0; n < 2; n++) {                                 \
      _Pragma("unroll") for (int kk = 0; kk < 2; kk++) {                            \
        unsigned ad = BBASE + (BBUF) + (unsigned)((NH) * 2 + n) * 8192u + wn16lr + ch[kk]; \
        DST[n][kk] = *(const bf16x8*)(LB + ad);                                     \
      }                                                                             \
    }

#define QMFMA(AF, BF, MH, NH)                                                       \
    __builtin_amdgcn_s_setprio(1);                                                  \
    _Pragma("unroll") for (int kk = 0; kk < 2; kk++) {                              \
      _Pragma("unroll") for (int f = 0; f < MF; f++) {                              \
        _Pragma("unroll") for (int n = 0; n < 2; n++) {                             \
          acc[(MH) * MF + f][(NH) * 2 + n] = __builtin_amdgcn_mfma_f32_16x16x32_bf16( \
              AF[f][kk], BF[n][kk], acc[(MH) * MF + f][(NH) * 2 + n], 0, 0, 0);     \
        }                                                                           \
      }                                                                             \
    }                                                                               \
    __builtin_amdgcn_s_setprio(0);

#define SYNC1(VM)                                                                   \
    asm volatile("s_waitcnt vmcnt(" #VM ")" ::: "memory");                          \
    __builtin_amdgcn_s_barrier();                                                   \
    asm volatile("s_waitcnt lgkmcnt(0)" ::: "memory");                              \
    __builtin_amdgcn_sched_barrier(0);

#define LGKM0                                                                       \
    asm volatile("s_waitcnt lgkmcnt(0)" ::: "memory");                              \
    __builtin_amdgcn_sched_barrier(0);

#define SBAR0 __builtin_amdgcn_sched_barrier(0);

#define SYNC2                                                                       \
    __builtin_amdgcn_s_barrier();                                                   \
    __builtin_amdgcn_sched_barrier(0);

  if constexpr (TM == 256) {
    // prologue: stage tile 0 fully into buf 0 (events: A0,B0,A1,B1)
    STAGE(0, 0, 0, 0);
    STAGE(1, 0, 0, 0);
    STAGE(0, 1, 0, 0);
    STAGE(1, 1, 0, 0);
    for (int t = 0; t < NT; t++) {
      const unsigned aob  = (unsigned)(t & 1) * ABUFSZ;
      const unsigned bob  = (unsigned)(t & 1) * 32768u;
      const int bb1 = (t + 1) & 1;
      const int tn = (t + 1 < NT) ? (t + 1) : 0;       // clamp dummy stage source
      // ---- phase 0: (A1,B1) of tile t-1 — no LDS reads
      {
        STAGE(0, 0, tn, bb1);
        SYNC1(6)
        if (t > 0) { QMFMA(afO, bfO, 1, 1) }
        SBAR0
      }
      // ---- phase 1: (A0,B0)
      {
        QREAD_A(afE, 0, aob)
        QREAD_B(bfE, 0, bob)
        STAGE(1, 0, tn, bb1);
        SYNC1(6)
        QMFMA(afE, bfE, 0, 0)
        SBAR0
      }
      // ---- phase 2: (A1,B0)
      {
        QREAD_A(afO, 1, aob)
        STAGE(0, 1, tn, bb1);
        SYNC1(6)
        QMFMA(afO, bfE, 1, 0)
        SBAR0
      }
      // ---- phase 3: (A0,B1)
      {
        QREAD_B(bfO, 1, bob)
        STAGE(1, 1, tn, bb1);
        SYNC1(6)
        QMFMA(afE, bfO, 0, 1)
        SBAR0
      }
    }
    // tail: (A1,B1) of tile NT-1
    QMFMA(afO, bfO, 1, 1)
  } else {
    // TM=128: 3-buffer rotation, lean 2-phase. Stage tile t+2 during tile t.
    // prologue: tile 0 -> buf 0, tile 1 -> buf 1 (12 loads); drain tile 0.
    STAGE(0, 0, 0, 0);
    STAGE(1, 0, 0, 0);
    STAGE(0, 1, 0, 0);
    STAGE(1, 1, 0, 0);
    STAGE(0, 0, 1, 1);
    STAGE(1, 0, 1, 1);
    STAGE(0, 1, 1, 1);
    STAGE(1, 1, 1, 1);
    asm volatile("s_waitcnt vmcnt(6)" ::: "memory");
    __builtin_amdgcn_s_barrier();
    __builtin_amdgcn_sched_barrier(0);
    int cb = 0;                                        // buf of tile t
    for (int t = 0; t < NT; t++) {
      const unsigned aob = (unsigned)cb * ABUFSZ;
      const unsigned bob = (unsigned)cb * 32768u;
      int sbuf = cb + 2; if (sbuf >= 3) sbuf -= 3;     // buf of tile t+2 (== buf of t-1)
      const int tn = (t + 2 < NT) ? (t + 2) : t;       // clamp dummy stage source
      // ---- phase A: read A0,A1,B0 of t; stage alpha(t+2); MFMA (A0+A1)xB0
      QREAD_A(afE, 0, aob)
      QREAD_A(afO, 1, aob)
      QREAD_B(bfE, 0, bob)
      STAGE(0, 0, tn, sbuf);
      STAGE(1, 0, tn, sbuf);
      LGKM0
      QMFMA(afE, bfE, 0, 0)
      QMFMA(afO, bfE, 1, 0)
      // ---- phase B: read B1 of t; stage beta(t+2); vmcnt(6); bar; MFMA (A0+A1)xB1
      QREAD_B(bfO, 1, bob)
      STAGE(0, 1, tn, sbuf);
      STAGE(1, 1, tn, sbuf);
      asm volatile("s_waitcnt vmcnt(6)" ::: "memory");
      __builtin_amdgcn_s_barrier();
      LGKM0
      QMFMA(afE, bfO, 0, 1)
      QMFMA(afO, bfO, 1, 1)
      SYNC2
      cb++; if (cb == 3) cb = 0;
    }
  }
#undef QREAD_A
#undef QREAD_B
#undef QMFMA
#undef SYNC1
#undef LGKM0
#undef SBAR0
#undef SYNC2

  // epilogue
  #pragma unroll
  for (int nf = 0; nf < 4; nf++) {
    int Cc = bn * 256 + nf * 64 + wn * 16 + lr;
    bool ok = (Cc < N);
    float bv = 0.f;
    if (MODE == 6) {
      bv = ((lr & 1) == 0) ? bias[Cc >> 1] : bias2[Cc >> 1];
    } else if (bias && ok) {
      bv = bias[Cc];
    }
    #pragma unroll
    for (int mf = 0; mf < 2 * MF; mf++) {
      #pragma unroll
      for (int j = 0; j < 4; j++) {
        int R = bm * TM + mf * 32 + wm * 16 + lk * 4 + j;
        float v = acc[mf][nf][j] + bv;
        if (MODE == 6) {
          float vp = __shfl_xor(v, 1, 64);   // partner column (Cc^1)
          if ((lr & 1) == 0) {
            float s = v / (1.f + __expf(-v));   // silu(gate)
            ((u16*)outp)[(size_t)R * (N >> 1) + (Cc >> 1)] = f2bf(s * vp);
          }
        } else if (ok) {
          if (MODE == 0) {
            ((u16*)outp)[(size_t)R * N + Cc] = f2bf(v);
          } else if (MODE == 1) {
            ((float*)outp)[(size_t)R * N + Cc] = v;
          } else if (MODE == 3) {
            ((u16*)outp)[(size_t)R * N + Cc] = f2bf(gelu_tanh(v));
          } else if (MODE == 4) {
            int orow = rowmap[R];
            ((float*)outp)[(size_t)orow * N + Cc] = v;
          } else if (MODE == 7) {
            u16* hp = (u16*)outp + (size_t)R * N + Cc;
            *hp = f2bf(bf2f(*hp) + v);
          }
        }
      }
    }
  }
}

// ---------------------------------------------------------------- windowed attention with fused RoPE
__global__ __launch_bounds__(256, 2) void attn_k(
    const u16* __restrict__ qkv, u16* __restrict__ outO,
    const float* __restrict__ cosr, const float* __restrict__ sinr) {
  __shared__ u16 Qs[64 * 104];
  __shared__ u16 Ks[64 * 104];
  __shared__ u16 Vt[80 * 72];
  __shared__ u16 Ps[64 * 72];
  const int w = blockIdx.x, hd = blockIdx.y;
  const int tid = threadIdx.x;
  const u16* base = qkv + (size_t)w * 64 * 3840 + hd * 80;

  // RoPE staging: one thread per (row, c<40) pair computes both rotated halves
  for (int idx = tid; idx < 64 * 40; idx += 256) {
    int r = idx / 40, c = idx - r * 40;
    int tokg = w * 64 + r;
    const float* cr = cosr + (size_t)tokg * 80;
    const float* sr = sinr + (size_t)tokg * 80;
    float c0 = cr[c], c1 = cr[c + 40], s0 = sr[c], s1 = sr[c + 40];
    const u16* rp = base + (size_t)r * 3840;
    float q0 = bf2f(rp[c]), q1 = bf2f(rp[c + 40]);
    float k0 = bf2f(rp[1280 + c]), k1 = bf2f(rp[1280 + c + 40]);
    Qs[r * 104 + c]      = f2bf(q0 * c0 - q1 * s0);
    Qs[r * 104 + c + 40] = f2bf(q1 * c1 + q0 * s1);
    Ks[r * 104 + c]      = f2bf(k0 * c0 - k1 * s0);
    Ks[r * 104 + c + 40] = f2bf(k1 * c1 + k0 * s1);
  }
  for (int idx = tid; idx < 64 * 16; idx += 256) {
    int r = idx >> 4, c = 80 + (idx & 15);
    Qs[r * 104 + c] = 0;
    Ks[r * 104 + c] = 0;
  }
  for (int idx = tid; idx < 80 * 64; idx += 256) {
    int d = idx >> 6, kt = idx & 63;
    Vt[d * 72 + kt] = base[(size_t)kt * 3840 + 2560 + d];
  }
  __syncthreads();

  const int lane = tid & 63, wv = tid >> 6;
  const int lr = lane & 15, lk = lane >> 4;
  const float sc = 0.11180339887498949f;  // 80^-0.5

  f32x4 sfrag[4];
  #pragma unroll
  for (int f = 0; f < 4; f++) { sfrag[f][0]=0.f; sfrag[f][1]=0.f; sfrag[f][2]=0.f; sfrag[f][3]=0.f; }
  bf16x8 aq[3];
  #pragma unroll
  for (int ks = 0; ks < 3; ks++) aq[ks] = *(const bf16x8*)&Qs[(wv * 16 + lr) * 104 + ks * 32 + lk * 8];
  #pragma unroll
  for (int fn = 0; fn < 4; fn++) {
    #pragma unroll
    for (int ks = 0; ks < 3; ks++) {
      bf16x8 bk = *(const bf16x8*)&Ks[(fn * 16 + lr) * 104 + ks * 32 + lk * 8];
      sfrag[fn] = __builtin_amdgcn_mfma_f32_16x16x32_bf16(aq[ks], bk, sfrag[fn], 0, 0, 0);
    }
  }

  float inv[4];
  #pragma unroll
  for (int j = 0; j < 4; j++) {
    float mx = -1e30f;
    #pragma unroll
    for (int fn = 0; fn < 4; fn++) mx = fmaxf(mx, sfrag[fn][j] * sc);
    #pragma unroll
    for (int d = 1; d < 16; d <<= 1) mx = fmaxf(mx, __shfl_xor(mx, d, 64));
    float sum = 0.f;
    #pragma unroll
    for (int fn = 0; fn < 4; fn++) {
      float e = __expf(sfrag[fn][j] * sc - mx);
      Ps[(wv * 16 + lk * 4 + j) * 72 + fn * 16 + lr] = f2bf(e);
      sum += e;
    }
    #pragma unroll
    for (int d = 1; d < 16; d <<= 1) sum += __shfl_xor(sum, d, 64);
    inv[j] = 1.0f / sum;
  }
  __syncthreads();

  bf16x8 ap[2];
  #pragma unroll
  for (int ks = 0; ks < 2; ks++) ap[ks] = *(const bf16x8*)&Ps[(wv * 16 + lr) * 72 + ks * 32 + lk * 8];
  f32x4 of[5];
  #pragma unroll
  for (int f = 0; f < 5; f++) { of[f][0]=0.f; of[f][1]=0.f; of[f][2]=0.f; of[f][3]=0.f; }
  #pragma unroll
  for (int fn2 = 0; fn2 < 5; fn2++) {
    #pragma unroll
    for (int ks = 0; ks < 2; ks++) {
      bf16x8 bv = *(const bf16x8*)&Vt[(fn2 * 16 + lr) * 72 + ks * 32 + lk * 8];
      of[fn2] = __builtin_amdgcn_mfma_f32_16x16x32_bf16(ap[ks], bv, of[fn2], 0, 0, 0);
    }
  }

  #pragma unroll
  for (int fn2 = 0; fn2 < 5; fn2++) {
    #pragma unroll
    for (int j = 0; j < 4; j++) {
      int q = wv * 16 + lk * 4 + j;
      int d = fn2 * 16 + lr;
      outO[((size_t)(w * 64 + q)) * 1280 + hd * 80 + d] = f2bf(of[fn2][j] * inv[j]);
    }
  }
}

// ---------------------------------------------------------------- host
extern "C" void kernel_launch(void* const* d_in, const int* in_sizes, int n_in,
                              void* d_out, int out_size, void* d_ws, size_t ws_size,
                              hipStream_t stream) {
  (void)in_sizes; (void)n_in; (void)out_size; (void)ws_size;
  const float* pv   = (const float*)d_in[0];
  const float* cosi = (const float*)d_in[1];
  const float* sini = (const float*)d_in[2];
  const int*   wi   = (const int*)d_in[3];
  const float* Wp   = (const float*)d_in[4];
  const float* n1w  = (const float*)d_in[5];
  const float* qkvw = (const float*)d_in[6];
  const float* qkvb = (const float*)d_in[7];
  const float* pw   = (const float*)d_in[8];
  const float* pb   = (const float*)d_in[9];
  const float* n2w  = (const float*)d_in[10];
  const float* gw   = (const float*)d_in[11];
  const float* gb   = (const float*)d_in[12];
  const float* uw   = (const float*)d_in[13];
  const float* ub   = (const float*)d_in[14];
  const float* dw   = (const float*)d_in[15];
  const float* db   = (const float*)d_in[16];
  const float* mnw  = (const float*)d_in[17];
  const float* ml1w = (const float*)d_in[18];
  const float* ml1b = (const float*)d_in[19];
  const float* ml2w = (const float*)d_in[20];
  const float* ml2b = (const float*)d_in[21];
  const float* dnw  = (const float*)d_in[22];
  const float* dl1w = (const float*)d_in[23];
  const float* dl1b = (const float*)d_in[24];
  const float* dl2w = (const float*)d_in[25];
  const float* dl2b = (const float*)d_in[26];
  float* outv = (float*)d_out;
  char* ws = (char*)d_ws;

  size_t off = 0;
  u16*  h     = (u16*)(ws + off);  off += (size_t)NTOK * HID_ * 2;       // 42MB (bf16 residual)
  float* cosr = (float*)(ws + off); off += (size_t)NTOK * 80 * 4;
  float* sinr = (float*)(ws + off); off += (size_t)NTOK * 80 * 4;
  u16*  xb    = (u16*)(ws + off);  off += (size_t)NTOK * HID_ * 2;       // 42MB
  u16*  bufA  = (u16*)(ws + off);  off += (size_t)NTOK * 3840 * 2;       // 126MB
  u16*  WtQ   = (u16*)(ws + off);  off += (size_t)3840 * HID_ * 2;       // 9.8MB
  u16*  WtP   = (u16*)(ws + off);  off += (size_t)HID_ * HID_ * 2;       // 3.3MB
  u16*  WtG   = (u16*)(ws + off);  off += (size_t)2 * INTER_ * HID_ * 2; // 17.7MB
  u16*  WtD   = (u16*)(ws + off);  off += (size_t)HID_ * INTER_ * 2;     // 8.8MB
  u16*  bufC  = (u16*)(ws + off);  off += (size_t)NTOK * HID_ * 2;       // 42MB
  u16*  Wt    = (u16*)(ws + off);  off += (size_t)BIGD * BIGD * 2;       // 52.5MB

  dim3 B256(256), B512(512);
  // supertile depth: SB=4 for K<=1536 (A panels small), else 2 (fits 4MB L2)
  #define SBOF(K_) (((K_) <= 1536) ? 4 : 2)
  #define TW(src, K_, N_) twt_k<<<dim3((N_) / 32, (K_) / 32), B256, 0, stream>>>((src), Wt, (K_), (N_))
  #define G8(MODE, TM_, Abuf, Bt_, bias_, bias2_, out_, rmap_, M_, N_, K_)                \
    gemm8_k<MODE, TM_><<<dim3(((M_) / (TM_)) * (((N_) + 255) / 256)), B512, 0, stream>>>( \
        (Abuf), (Bt_), (bias_), (bias2_), (out_), (rmap_), (((N_) + 255) / 256),          \
        SBOF(K_), (N_), (K_))

  // gather pixel rows + cos/sin
  gather_pv_k<<<(NTOK * 384 + 255) / 256, B256, 0, stream>>>(pv, wi, bufA);
  gather_cs_k<<<(NTOK * 20 + 255) / 256, B256, 0, stream>>>(cosi, sini, wi, cosr, sinr);

  // h = pv_g @ W_patch   (bf16 residual stream)
  TW(Wp, 1536, HID_);
  G8(0, 128, bufA, Wt, nullptr, nullptr, h, nullptr, NTOK, HID_, 1536);

  for (int i = 0; i < 6; i++) {
    // batched transpose of all 5 layer weights (one launch)
    twtb_k<<<dim3(4800, 5), B256, 0, stream>>>(
        qkvw + (size_t)i * HID_ * 3840, pw + (size_t)i * HID_ * HID_,
        gw + (size_t)i * HID_ * INTER_, uw + (size_t)i * HID_ * INTER_,
        dw + (size_t)i * INTER_ * HID_, WtQ, WtP, WtG, WtD);
    // attn
    rmsnorm_k<<<NTOK, B256, 0, stream>>>(h, n1w + (size_t)i * HID_, xb, HID_);
    G8(0, 256, xb, WtQ, qkvb + (size_t)i * 3840, nullptr, bufA, nullptr, NTOK, 3840, HID_);
    attn_k<<<dim3(256, 16), B256, 0, stream>>>(bufA, bufC, cosr, sinr);
    G8(7, 128, bufC, WtP, pb + (size_t)i * HID_, nullptr, h, nullptr, NTOK, HID_, HID_);
    // mlp: fused gate+up via interleaved weight columns (even=gate, odd=up)
    rmsnorm_k<<<NTOK, B256, 0, stream>>>(h, n2w + (size_t)i * HID_, xb, HID_);
    G8(6, 256, xb, WtG, gb + (size_t)i * INTER_, ub + (size_t)i * INTER_, bufA, nullptr,
       NTOK, 2 * INTER_, HID_);
    G8(7, 128, bufA, WtD, db + (size_t)i * HID_, nullptr, h, nullptr, NTOK, HID_, INTER_);
    // deepstack mergers after layers 2 and 4
    if (i == 2 || i == 4) {
      int j = (i == 2) ? 0 : 1;
      rmsnorm_k<<<NGRP, B256, 0, stream>>>(h, dnw + (size_t)j * BIGD, bufC, BIGD);
      TW(dl1w + (size_t)j * BIGD * BIGD, BIGD, BIGD);
      G8(3, 128, bufC, Wt, dl1b + (size_t)j * BIGD, nullptr, bufA, nullptr, NGRP, BIGD, BIGD);
      TW(dl2w + (size_t)j * BIGD * ODIM, BIGD, ODIM);
      G8(4, 128, bufA, Wt, dl2b + (size_t)j * ODIM, nullptr,
         outv + (size_t)(1 + j) * NGRP * ODIM, wi, NGRP, ODIM, BIGD);
    }
  }

  // final merger -> plane 0
  rmsnorm_k<<<NTOK, B256, 0, stream>>>(h, mnw, bufC, HID_);
  TW(ml1w, BIGD, BIGD);
  G8(3, 128, bufC, Wt, ml1b, nullptr, bufA, nullptr, NGRP, BIGD, BIGD);
  TW(ml2w, BIGD, ODIM);
  G8(4, 128, bufA, Wt, ml2b, nullptr, outv, wi, NGRP, ODIM, BIGD);
  #undef TW
  #undef G8
  #undef SBOF
}

// Round 24
// 6622.910 us; speedup vs baseline: 1.0669x; 1.0253x over previous
//
#include <hip/hip_runtime.h>
#include <hip/hip_bf16.h>

typedef unsigned short u16;
typedef __bf16 bf16x8 __attribute__((ext_vector_type(8)));
typedef float   f32x4 __attribute__((ext_vector_type(4)));
typedef unsigned short u16x8 __attribute__((ext_vector_type(8)));

#define NTOK  16384
#define HID_  1280
#define NHEAD 16
#define HD    80
#define INTER_ 3456
#define NGRP  4096
#define ODIM  2048
#define BIGD  5120

static __device__ __forceinline__ u16 f2bf(float f) {
  __hip_bfloat16 h = __float2bfloat16(f);
  return __builtin_bit_cast(u16, h);
}
static __device__ __forceinline__ float bf2f(u16 u) {
  return __bfloat162float(__builtin_bit_cast(__hip_bfloat16, u));
}
static __device__ __forceinline__ float gelu_tanh(float x) {
  float y = 0.7978845608028654f * (x + 0.044715f * x * x * x);
  float t = 1.0f - 2.0f / (1.0f + __expf(2.0f * y));   // tanh(y)
  return 0.5f * x * (1.0f + t);
}

// async global->LDS, 16B per lane, dest = wave-uniform base + lane*16
static __device__ __forceinline__ void gload_lds16(const u16* g, u16* l) {
  __builtin_amdgcn_global_load_lds(
      (const __attribute__((address_space(1))) unsigned int*)g,
      (__attribute__((address_space(3))) unsigned int*)l, 16, 0, 0);
}

// ---------------------------------------------------------------- gathers
__global__ __launch_bounds__(256) void gather_pv_k(
    const float* __restrict__ pv, const int* __restrict__ wi, u16* __restrict__ out) {
  int t = blockIdx.x * 256 + threadIdx.x;          // NTOK*384 float4 groups
  if (t >= NTOK * 384) return;
  int i = t / 384, c4 = t - i * 384;
  int s = wi[i >> 2] * 4 + (i & 3);
  float4 v = *(const float4*)(pv + (size_t)s * 1536 + c4 * 4);
  uint2 r;
  r.x = (unsigned)f2bf(v.x) | ((unsigned)f2bf(v.y) << 16);
  r.y = (unsigned)f2bf(v.z) | ((unsigned)f2bf(v.w) << 16);
  *(uint2*)(out + (size_t)i * 1536 + c4 * 4) = r;
}

__global__ __launch_bounds__(256) void gather_cs_k(
    const float* __restrict__ ci, const float* __restrict__ si,
    const int* __restrict__ wi, float* __restrict__ co, float* __restrict__ so) {
  int t = blockIdx.x * 256 + threadIdx.x;          // NTOK*20 float4 groups
  if (t >= NTOK * 20) return;
  int i = t / 20, c4 = t - i * 20;
  int s = wi[i >> 2] * 4 + (i & 3);
  *(float4*)(co + (size_t)i * 80 + c4 * 4) = *(const float4*)(ci + (size_t)s * 80 + c4 * 4);
  *(float4*)(so + (size_t)i * 80 + c4 * 4) = *(const float4*)(si + (size_t)s * 80 + c4 * 4);
}

// ---------------------------------------------------------------- weight f32[K][N] -> bf16[N][K]
__global__ __launch_bounds__(256) void twt_k(
    const float* __restrict__ W, u16* __restrict__ Wt, int K, int N) {
  __shared__ u16 t[32][33];
  int bn = blockIdx.x * 32, bk = blockIdx.y * 32;
  int tx = threadIdx.x & 31, ty = threadIdx.x >> 5;   // ty 0..7
  #pragma unroll
  for (int r = 0; r < 4; r++) {
    int k = bk + ty + r * 8;
    t[tx][ty + r * 8] = f2bf(W[(size_t)k * N + bn + tx]);
  }
  __syncthreads();
  #pragma unroll
  for (int r = 0; r < 4; r++) {
    int n = bn + ty + r * 8;
    Wt[(size_t)n * K + bk + tx] = t[ty + r * 8][tx];
  }
}

// batched per-layer transpose: 5 jobs in one launch.
__global__ __launch_bounds__(256) void twtb_k(
    const float* __restrict__ q, const float* __restrict__ p, const float* __restrict__ g,
    const float* __restrict__ u, const float* __restrict__ d,
    u16* __restrict__ oq, u16* __restrict__ op, u16* __restrict__ og, u16* __restrict__ od) {
  __shared__ u16 t[32][33];
  const int job = blockIdx.y;
  const float* W; u16* O; int K, N, st, ph, nbn;
  if (job == 0)      { W = q; O = oq; K = 1280; N = 3840; st = 1; ph = 0; nbn = 120; }
  else if (job == 1) { W = p; O = op; K = 1280; N = 1280; st = 1; ph = 0; nbn = 40; }
  else if (job == 2) { W = g; O = og; K = 1280; N = 3456; st = 2; ph = 0; nbn = 108; }
  else if (job == 3) { W = u; O = og; K = 1280; N = 3456; st = 2; ph = 1; nbn = 108; }
  else               { W = d; O = od; K = 3456; N = 1280; st = 1; ph = 0; nbn = 40; }
  const int tIdx = blockIdx.x;
  const int bn = (tIdx % nbn) * 32;
  const int bk = (tIdx / nbn) * 32;
  if (bk >= K) return;
  const int tx = threadIdx.x & 31, ty = threadIdx.x >> 5;
  #pragma unroll
  for (int r = 0; r < 4; r++) {
    int k = bk + ty + r * 8;
    t[tx][ty + r * 8] = f2bf(W[(size_t)k * N + bn + tx]);
  }
  __syncthreads();
  #pragma unroll
  for (int r = 0; r < 4; r++) {
    int n = bn + ty + r * 8;
    O[(size_t)(n * st + ph) * K + bk + tx] = t[ty + r * 8][tx];
  }
}

// ---------------------------------------------------------------- rmsnorm (bf16 in -> bf16 out), 8-wide vectorized
__global__ __launch_bounds__(256) void rmsnorm_k(
    const u16* __restrict__ x, const float* __restrict__ w, u16* __restrict__ out, int D) {
  int row = blockIdx.x;
  const uint4* xr = (const uint4*)(x + (size_t)row * D);   // 8 bf16 per uint4
  int D8 = D >> 3;
  float ss = 0.f;
  for (int c = threadIdx.x; c < D8; c += 256) {
    uint4 v = xr[c];
    const unsigned vv[4] = {v.x, v.y, v.z, v.w};
    #pragma unroll
    for (int e = 0; e < 4; e++) {
      float a = bf2f((u16)(vv[e] & 0xffff));
      float b = bf2f((u16)(vv[e] >> 16));
      ss += a * a + b * b;
    }
  }
  #pragma unroll
  for (int d = 1; d < 64; d <<= 1) ss += __shfl_xor(ss, d, 64);
  __shared__ float part[4];
  if ((threadIdx.x & 63) == 0) part[threadIdx.x >> 6] = ss;
  __syncthreads();
  float tot = part[0] + part[1] + part[2] + part[3];
  float scale = rsqrtf(tot / (float)D + 1e-6f);
  u16* orow = out + (size_t)row * D;
  const float4* wr = (const float4*)w;
  for (int c = threadIdx.x; c < D8; c += 256) {
    uint4 v = xr[c];
    float4 w0 = wr[c * 2], w1 = wr[c * 2 + 1];
    const unsigned vv[4] = {v.x, v.y, v.z, v.w};
    const float wf[8] = {w0.x, w0.y, w0.z, w0.w, w1.x, w1.y, w1.z, w1.w};
    uint4 r;
    unsigned rr[4];
    #pragma unroll
    for (int e = 0; e < 4; e++) {
      float a = bf2f((u16)(vv[e] & 0xffff)) * scale * wf[e * 2];
      float b = bf2f((u16)(vv[e] >> 16)) * scale * wf[e * 2 + 1];
      rr[e] = (unsigned)f2bf(a) | ((unsigned)f2bf(b) << 16);
    }
    r.x = rr[0]; r.y = rr[1]; r.z = rr[2]; r.w = rr[3];
    *(uint4*)(orow + c * 8) = r;
  }
}

// ---------------------------------------------------------------- 8-phase GEMM, tile TM x 256 (TM=256 or 128)
// (r22 kernel, unchanged: dedup reads, hoisted addressing, supertile ordering,
//  barrier-lean TM=256 4-phase, lean TM=128 2-phase with 3 buffers.)
template <int MODE, int TM>
__global__ __launch_bounds__(512, 2) void gemm8_k(
    const u16* __restrict__ A, const u16* __restrict__ Bt, const float* __restrict__ bias,
    const float* __restrict__ bias2, void* __restrict__ outp, const int* __restrict__ rowmap,
    int nbn, int sb, int N, int K) {
  constexpr int MF = TM / 64;                 // A frags per half (4 or 2)
  constexpr unsigned ABUFSZ = (unsigned)TM * 128u;   // bytes per A buf
  constexpr int NBUF = (TM == 256) ? 2 : 3;
  constexpr unsigned BBASE = (unsigned)NBUF * ABUFSZ;
  __shared__ __align__(16) u16 LDS[(TM == 256) ? 65536 : 73728];
  const int tid = threadIdx.x;
  const int w = tid >> 6, lane = tid & 63;
  const int wm = w >> 2, wn = w & 3;
  const int lr = lane & 15, lk = lane >> 4, lrm = lr & 7;
  const int NT = K >> 6;
  const size_t Kb = (size_t)K * 2;
  const int l8 = lane >> 3, l7 = lane & 7;
  const int schunk = l7 ^ l8;                 // pre-swizzled source chunk

  // -------- bijective XCD-chunked tile decode (m204)
  const int nwg = gridDim.x;
  const int q8 = nwg >> 3, r8 = nwg & 7;
  const int xcd = blockIdx.x & 7, ord = blockIdx.x >> 3;
  const int id = (xcd < r8 ? xcd * (q8 + 1) : r8 * (q8 + 1) + (xcd - r8) * q8) + ord;
  // -------- supertile decode: (super, bn, bmi); bm = super*sb + bmi
  const int spt = sb * nbn;
  const int super = id / spt;
  const int rem = id - super * spt;
  const int bn = rem / sb;
  const int bm = super * sb + (rem - bn * sb);

  const unsigned wm16lr = (unsigned)(wm * 16 + lr) * 128u;
  const unsigned wn16lr = (unsigned)(wn * 16 + lr) * 128u;
  unsigned ch[2];
  ch[0] = (unsigned)(((lk) ^ lrm) << 4);
  ch[1] = (unsigned)(((4 + lk) ^ lrm) << 4);
  const char* LB = (const char*)&LDS[0];

  f32x4 acc[2 * MF][4];
  #pragma unroll
  for (int f = 0; f < 2 * MF; f++)
    #pragma unroll
    for (int n = 0; n < 4; n++) { acc[f][n][0]=0.f; acc[f][n][1]=0.f; acc[f][n][2]=0.f; acc[f][n][3]=0.f; }

  const char* Ab = (const char*)A;
  const char* Bb = (const char*)Bt;
  u16* LDSp = &LDS[0];

  // hoisted per-lane global base pointers (src = base + tt*128)
  const char* aSrc[2][2];
  const char* bSrc[2][2];
  #pragma unroll
  for (int half = 0; half < 2; half++) {
    if constexpr (TM == 256) {
      #pragma unroll
      for (int i = 0; i < 2; i++) {
        int gr = bm * 256 + half * 128 + i * 64 + w * 8 + l8;
        aSrc[half][i] = Ab + (size_t)gr * Kb + schunk * 16;
      }
    } else {
      int gr = bm * 128 + half * 64 + w * 8 + l8;
      aSrc[half][0] = Ab + (size_t)gr * Kb + schunk * 16;
      aSrc[half][1] = aSrc[half][0];
    }
    #pragma unroll
    for (int i = 0; i < 2; i++) {
      int gr = bn * 256 + half * 128 + i * 64 + w * 8 + l8;
      if (gr >= N) gr = N - 1;
      bSrc[half][i] = Bb + (size_t)gr * Kb + schunk * 16;
    }
  }

  // persistent fragment registers (dedup: each LDS fragment read once per K-tile)
  bf16x8 afE[MF][2], afO[MF][2], bfE[2][2], bfO[2][2];

  // stage one half-tile. isB: operand; half: 0/1; tt: K-tile; bb: lds buf
  auto STAGE = [&](int isB, int half, int tt, int bb) {
    long k0b = (long)tt * 128;
    if (!isB) {
      if constexpr (TM == 256) {
        #pragma unroll
        for (int i = 0; i < 2; i++) {
          int r0 = half * 128 + i * 64 + w * 8;
          unsigned dst = (unsigned)bb * ABUFSZ + (unsigned)r0 * 128u;
          gload_lds16((const u16*)(aSrc[half][i] + k0b), LDSp + dst / 2);
        }
      } else {
        int r0 = half * 64 + w * 8;
        unsigned dst = (unsigned)bb * ABUFSZ + (unsigned)r0 * 128u;
        gload_lds16((const u16*)(aSrc[half][0] + k0b), LDSp + dst / 2);
      }
    } else {
      #pragma unroll
      for (int i = 0; i < 2; i++) {
        int r0 = half * 128 + i * 64 + w * 8;
        unsigned dst = BBASE + (unsigned)bb * 32768u + (unsigned)r0 * 128u;
        gload_lds16((const u16*)(bSrc[half][i] + k0b), LDSp + dst / 2);
      }
    }
  };

#define QREAD_A(DST, MH, ABUF)                                                      \
    _Pragma("unroll") for (int f = 0; f < MF; f++) {                                \
      _Pragma("unroll") for (int kk = 0; kk < 2; kk++) {                            \
        unsigned ad = (ABUF) + (unsigned)((MH) * MF + f) * 4096u + wm16lr + ch[kk]; \
        DST[f][kk] = *(const bf16x8*)(LB + ad);                                     \
      }                                                                             \
    }

#define QREAD_B(DST, NH, BBUF)                                                      \
    _Pragma("unroll") for (int n = 0; n < 2; n++) {                                 \
      _Pragma("unroll") for (int kk = 0; kk < 2; kk++) {                            \
        unsigned ad = BBASE + (BBUF) + (unsigned)((NH) * 2 + n) * 8192u + wn16lr + ch[kk]; \
        DST[n][kk] = *(const bf16x8*)(LB + ad);                                     \
      }                                                                             \
    }

#define QMFMA(AF, BF, MH, NH)                                                       \
    __builtin_amdgcn_s_setprio(1);                                                  \
    _Pragma("unroll") for (int kk = 0; kk < 2; kk++) {                              \
      _Pragma("unroll") for (int f = 0; f < MF; f++) {                              \
        _Pragma("unroll") for (int n = 0; n < 2; n++) {                             \
          acc[(MH) * MF + f][(NH) * 2 + n] = __builtin_amdgcn_mfma_f32_16x16x32_bf16( \
              AF[f][kk], BF[n][kk], acc[(MH) * MF + f][(NH) * 2 + n], 0, 0, 0);     \
        }                                                                           \
      }                                                                             \
    }                                                                               \
    __builtin_amdgcn_s_setprio(0);

#define SYNC1(VM)                                                                   \
    asm volatile("s_waitcnt vmcnt(" #VM ")" ::: "memory");                          \
    __builtin_amdgcn_s_barrier();                                                   \
    asm volatile("s_waitcnt lgkmcnt(0)" ::: "memory");                              \
    __builtin_amdgcn_sched_barrier(0);

#define LGKM0                                                                       \
    asm volatile("s_waitcnt lgkmcnt(0)" ::: "memory");                              \
    __builtin_amdgcn_sched_barrier(0);

#define SBAR0 __builtin_amdgcn_sched_barrier(0);

#define SYNC2                                                                       \
    __builtin_amdgcn_s_barrier();                                                   \
    __builtin_amdgcn_sched_barrier(0);

  if constexpr (TM == 256) {
    // prologue: stage tile 0 fully into buf 0 (events: A0,B0,A1,B1)
    STAGE(0, 0, 0, 0);
    STAGE(1, 0, 0, 0);
    STAGE(0, 1, 0, 0);
    STAGE(1, 1, 0, 0);
    for (int t = 0; t < NT; t++) {
      const unsigned aob  = (unsigned)(t & 1) * ABUFSZ;
      const unsigned bob  = (unsigned)(t & 1) * 32768u;
      const int bb1 = (t + 1) & 1;
      const int tn = (t + 1 < NT) ? (t + 1) : 0;       // clamp dummy stage source
      // ---- phase 0: (A1,B1) of tile t-1 — no LDS reads
      {
        STAGE(0, 0, tn, bb1);
        SYNC1(6)
        if (t > 0) { QMFMA(afO, bfO, 1, 1) }
        SBAR0
      }
      // ---- phase 1: (A0,B0)
      {
        QREAD_A(afE, 0, aob)
        QREAD_B(bfE, 0, bob)
        STAGE(1, 0, tn, bb1);
        SYNC1(6)
        QMFMA(afE, bfE, 0, 0)
        SBAR0
      }
      // ---- phase 2: (A1,B0)
      {
        QREAD_A(afO, 1, aob)
        STAGE(0, 1, tn, bb1);
        SYNC1(6)
        QMFMA(afO, bfE, 1, 0)
        SBAR0
      }
      // ---- phase 3: (A0,B1)
      {
        QREAD_B(bfO, 1, bob)
        STAGE(1, 1, tn, bb1);
        SYNC1(6)
        QMFMA(afE, bfO, 0, 1)
        SBAR0
      }
    }
    // tail: (A1,B1) of tile NT-1
    QMFMA(afO, bfO, 1, 1)
  } else {
    // TM=128: 3-buffer rotation, lean 2-phase. Stage tile t+2 during tile t.
    // prologue: tile 0 -> buf 0, tile 1 -> buf 1 (12 loads); drain tile 0.
    STAGE(0, 0, 0, 0);
    STAGE(1, 0, 0, 0);
    STAGE(0, 1, 0, 0);
    STAGE(1, 1, 0, 0);
    STAGE(0, 0, 1, 1);
    STAGE(1, 0, 1, 1);
    STAGE(0, 1, 1, 1);
    STAGE(1, 1, 1, 1);
    asm volatile("s_waitcnt vmcnt(6)" ::: "memory");
    __builtin_amdgcn_s_barrier();
    __builtin_amdgcn_sched_barrier(0);
    int cb = 0;                                        // buf of tile t
    for (int t = 0; t < NT; t++) {
      const unsigned aob = (unsigned)cb * ABUFSZ;
      const unsigned bob = (unsigned)cb * 32768u;
      int sbuf = cb + 2; if (sbuf >= 3) sbuf -= 3;     // buf of tile t+2 (== buf of t-1)
      const int tn = (t + 2 < NT) ? (t + 2) : t;       // clamp dummy stage source
      // ---- phase A: read A0,A1,B0 of t; stage alpha(t+2); MFMA (A0+A1)xB0
      QREAD_A(afE, 0, aob)
      QREAD_A(afO, 1, aob)
      QREAD_B(bfE, 0, bob)
      STAGE(0, 0, tn, sbuf);
      STAGE(1, 0, tn, sbuf);
      LGKM0
      QMFMA(afE, bfE, 0, 0)
      QMFMA(afO, bfE, 1, 0)
      // ---- phase B: read B1 of t; stage beta(t+2); vmcnt(6); bar; MFMA (A0+A1)xB1
      QREAD_B(bfO, 1, bob)
      STAGE(0, 1, tn, sbuf);
      STAGE(1, 1, tn, sbuf);
      asm volatile("s_waitcnt vmcnt(6)" ::: "memory");
      __builtin_amdgcn_s_barrier();
      LGKM0
      QMFMA(afE, bfO, 0, 1)
      QMFMA(afO, bfO, 1, 1)
      SYNC2
      cb++; if (cb == 3) cb = 0;
    }
  }
#undef QREAD_A
#undef QREAD_B
#undef QMFMA
#undef SYNC1
#undef LGKM0
#undef SBAR0
#undef SYNC2

  // epilogue
  #pragma unroll
  for (int nf = 0; nf < 4; nf++) {
    int Cc = bn * 256 + nf * 64 + wn * 16 + lr;
    bool ok = (Cc < N);
    float bv = 0.f;
    if (MODE == 6) {
      bv = ((lr & 1) == 0) ? bias[Cc >> 1] : bias2[Cc >> 1];
    } else if (bias && ok) {
      bv = bias[Cc];
    }
    #pragma unroll
    for (int mf = 0; mf < 2 * MF; mf++) {
      #pragma unroll
      for (int j = 0; j < 4; j++) {
        int R = bm * TM + mf * 32 + wm * 16 + lk * 4 + j;
        float v = acc[mf][nf][j] + bv;
        if (MODE == 6) {
          float vp = __shfl_xor(v, 1, 64);   // partner column (Cc^1)
          if ((lr & 1) == 0) {
            float s = v / (1.f + __expf(-v));   // silu(gate)
            ((u16*)outp)[(size_t)R * (N >> 1) + (Cc >> 1)] = f2bf(s * vp);
          }
        } else if (ok) {
          if (MODE == 0) {
            ((u16*)outp)[(size_t)R * N + Cc] = f2bf(v);
          } else if (MODE == 1) {
            ((float*)outp)[(size_t)R * N + Cc] = v;
          } else if (MODE == 3) {
            ((u16*)outp)[(size_t)R * N + Cc] = f2bf(gelu_tanh(v));
          } else if (MODE == 4) {
            int orow = rowmap[R];
            ((float*)outp)[(size_t)orow * N + Cc] = v;
          } else if (MODE == 7) {
            u16* hp = (u16*)outp + (size_t)R * N + Cc;
            *hp = f2bf(bf2f(*hp) + v);
          }
        }
      }
    }
  }
}

// ---------------------------------------------------------------- windowed attention with fused RoPE
// staging vectorized (r24): RoPE via uint2/float4 groups; V via uint4 loads.
__global__ __launch_bounds__(256, 2) void attn_k(
    const u16* __restrict__ qkv, u16* __restrict__ outO,
    const float* __restrict__ cosr, const float* __restrict__ sinr) {
  __shared__ u16 Qs[64 * 104];
  __shared__ u16 Ks[64 * 104];
  __shared__ u16 Vt[80 * 72];
  __shared__ u16 Ps[64 * 72];
  const int w = blockIdx.x, hd = blockIdx.y;
  const int tid = threadIdx.x;
  const u16* base = qkv + (size_t)w * 64 * 3840 + hd * 80;

  // RoPE staging: one task per (row, 4-col group), 64x10 tasks
  for (int idx = tid; idx < 640; idx += 256) {
    int r = idx / 10, c0 = (idx - r * 10) * 4;
    int tokg = w * 64 + r;
    const float* cr = cosr + (size_t)tokg * 80;
    const float* sr = sinr + (size_t)tokg * 80;
    float4 cl = *(const float4*)(cr + c0);
    float4 chh = *(const float4*)(cr + 40 + c0);
    float4 sl = *(const float4*)(sr + c0);
    float4 shh = *(const float4*)(sr + 40 + c0);
    const u16* rp = base + (size_t)r * 3840;
    uint2 qlo = *(const uint2*)(rp + c0);
    uint2 qhi = *(const uint2*)(rp + c0 + 40);
    uint2 klo = *(const uint2*)(rp + 1280 + c0);
    uint2 khi = *(const uint2*)(rp + 1280 + c0 + 40);
    const float q0a[4] = {bf2f((u16)(qlo.x & 0xffff)), bf2f((u16)(qlo.x >> 16)),
                          bf2f((u16)(qlo.y & 0xffff)), bf2f((u16)(qlo.y >> 16))};
    const float q1a[4] = {bf2f((u16)(qhi.x & 0xffff)), bf2f((u16)(qhi.x >> 16)),
                          bf2f((u16)(qhi.y & 0xffff)), bf2f((u16)(qhi.y >> 16))};
    const float k0a[4] = {bf2f((u16)(klo.x & 0xffff)), bf2f((u16)(klo.x >> 16)),
                          bf2f((u16)(klo.y & 0xffff)), bf2f((u16)(klo.y >> 16))};
    const float k1a[4] = {bf2f((u16)(khi.x & 0xffff)), bf2f((u16)(khi.x >> 16)),
                          bf2f((u16)(khi.y & 0xffff)), bf2f((u16)(khi.y >> 16))};
    const float cla[4] = {cl.x, cl.y, cl.z, cl.w};
    const float cha[4] = {chh.x, chh.y, chh.z, chh.w};
    const float sla[4] = {sl.x, sl.y, sl.z, sl.w};
    const float sha[4] = {shh.x, shh.y, shh.z, shh.w};
    unsigned oql[2], oqh[2], okl[2], okh[2];
    #pragma unroll
    for (int p = 0; p < 2; p++) {
      int e0 = p * 2, e1 = p * 2 + 1;
      oql[p] = (unsigned)f2bf(q0a[e0] * cla[e0] - q1a[e0] * sla[e0]) |
               ((unsigned)f2bf(q0a[e1] * cla[e1] - q1a[e1] * sla[e1]) << 16);
      oqh[p] = (unsigned)f2bf(q1a[e0] * cha[e0] + q0a[e0] * sha[e0]) |
               ((unsigned)f2bf(q1a[e1] * cha[e1] + q0a[e1] * sha[e1]) << 16);
      okl[p] = (unsigned)f2bf(k0a[e0] * cla[e0] - k1a[e0] * sla[e0]) |
               ((unsigned)f2bf(k0a[e1] * cla[e1] - k1a[e1] * sla[e1]) << 16);
      okh[p] = (unsigned)f2bf(k1a[e0] * cha[e0] + k0a[e0] * sha[e0]) |
               ((unsigned)f2bf(k1a[e1] * cha[e1] + k0a[e1] * sha[e1]) << 16);
    }
    *(uint2*)&Qs[r * 104 + c0]      = make_uint2(oql[0], oql[1]);
    *(uint2*)&Qs[r * 104 + 40 + c0] = make_uint2(oqh[0], oqh[1]);
    *(uint2*)&Ks[r * 104 + c0]      = make_uint2(okl[0], okl[1]);
    *(uint2*)&Ks[r * 104 + 40 + c0] = make_uint2(okh[0], okh[1]);
  }
  for (int idx = tid; idx < 64 * 16; idx += 256) {
    int r = idx >> 4, c = 80 + (idx & 15);
    Qs[r * 104 + c] = 0;
    Ks[r * 104 + c] = 0;
  }
  // V staging: one task per (kt, 8-d group): coalesced uint4 load, scalar LDS writes
  for (int idx = tid; idx < 640; idx += 256) {
    int kt = idx / 10, d0 = (idx - kt * 10) * 8;
    uint4 v = *(const uint4*)(base + (size_t)kt * 3840 + 2560 + d0);
    const unsigned vv[4] = {v.x, v.y, v.z, v.w};
    #pragma unroll
    for (int e = 0; e < 4; e++) {
      Vt[(d0 + 2 * e) * 72 + kt]     = (u16)(vv[e] & 0xffff);
      Vt[(d0 + 2 * e + 1) * 72 + kt] = (u16)(vv[e] >> 16);
    }
  }
  __syncthreads();

  const int lane = tid & 63, wv = tid >> 6;
  const int lr = lane & 15, lk = lane >> 4;
  const float sc = 0.11180339887498949f;  // 80^-0.5

  f32x4 sfrag[4];
  #pragma unroll
  for (int f = 0; f < 4; f++) { sfrag[f][0]=0.f; sfrag[f][1]=0.f; sfrag[f][2]=0.f; sfrag[f][3]=0.f; }
  bf16x8 aq[3];
  #pragma unroll
  for (int ks = 0; ks < 3; ks++) aq[ks] = *(const bf16x8*)&Qs[(wv * 16 + lr) * 104 + ks * 32 + lk * 8];
  #pragma unroll
  for (int fn = 0; fn < 4; fn++) {
    #pragma unroll
    for (int ks = 0; ks < 3; ks++) {
      bf16x8 bk = *(const bf16x8*)&Ks[(fn * 16 + lr) * 104 + ks * 32 + lk * 8];
      sfrag[fn] = __builtin_amdgcn_mfma_f32_16x16x32_bf16(aq[ks], bk, sfrag[fn], 0, 0, 0);
    }
  }

  float inv[4];
  #pragma unroll
  for (int j = 0; j < 4; j++) {
    float mx = -1e30f;
    #pragma unroll
    for (int fn = 0; fn < 4; fn++) mx = fmaxf(mx, sfrag[fn][j] * sc);
    #pragma unroll
    for (int d = 1; d < 16; d <<= 1) mx = fmaxf(mx, __shfl_xor(mx, d, 64));
    float sum = 0.f;
    #pragma unroll
    for (int fn = 0; fn < 4; fn++) {
      float e = __expf(sfrag[fn][j] * sc - mx);
      Ps[(wv * 16 + lk * 4 + j) * 72 + fn * 16 + lr] = f2bf(e);
      sum += e;
    }
    #pragma unroll
    for (int d = 1; d < 16; d <<= 1) sum += __shfl_xor(sum, d, 64);
    inv[j] = 1.0f / sum;
  }
  __syncthreads();

  bf16x8 ap[2];
  #pragma unroll
  for (int ks = 0; ks < 2; ks++) ap[ks] = *(const bf16x8*)&Ps[(wv * 16 + lr) * 72 + ks * 32 + lk * 8];
  f32x4 of[5];
  #pragma unroll
  for (int f = 0; f < 5; f++) { of[f][0]=0.f; of[f][1]=0.f; of[f][2]=0.f; of[f][3]=0.f; }
  #pragma unroll
  for (int fn2 = 0; fn2 < 5; fn2++) {
    #pragma unroll
    for (int ks = 0; ks < 2; ks++) {
      bf16x8 bv = *(const bf16x8*)&Vt[(fn2 * 16 + lr) * 72 + ks * 32 + lk * 8];
      of[fn2] = __builtin_amdgcn_mfma_f32_16x16x32_bf16(ap[ks], bv, of[fn2], 0, 0, 0);
    }
  }

  #pragma unroll
  for (int fn2 = 0; fn2 < 5; fn2++) {
    #pragma unroll
    for (int j = 0; j < 4; j++) {
      int q = wv * 16 + lk * 4 + j;
      int d = fn2 * 16 + lr;
      outO[((size_t)(w * 64 + q)) * 1280 + hd * 80 + d] = f2bf(of[fn2][j] * inv[j]);
    }
  }
}

// ---------------------------------------------------------------- host
extern "C" void kernel_launch(void* const* d_in, const int* in_sizes, int n_in,
                              void* d_out, int out_size, void* d_ws, size_t ws_size,
                              hipStream_t stream) {
  (void)in_sizes; (void)n_in; (void)out_size; (void)ws_size;
  const float* pv   = (const float*)d_in[0];
  const float* cosi = (const float*)d_in[1];
  const float* sini = (const float*)d_in[2];
  const int*   wi   = (const int*)d_in[3];
  const float* Wp   = (const float*)d_in[4];
  const float* n1w  = (const float*)d_in[5];
  const float* qkvw = (const float*)d_in[6];
  const float* qkvb = (const float*)d_in[7];
  const float* pw   = (const float*)d_in[8];
  const float* pb   = (const float*)d_in[9];
  const float* n2w  = (const float*)d_in[10];
  const float* gw   = (const float*)d_in[11];
  const float* gb   = (const float*)d_in[12];
  const float* uw   = (const float*)d_in[13];
  const float* ub   = (const float*)d_in[14];
  const float* dw   = (const float*)d_in[15];
  const float* db   = (const float*)d_in[16];
  const float* mnw  = (const float*)d_in[17];
  const float* ml1w = (const float*)d_in[18];
  const float* ml1b = (const float*)d_in[19];
  const float* ml2w = (const float*)d_in[20];
  const float* ml2b = (const float*)d_in[21];
  const float* dnw  = (const float*)d_in[22];
  const float* dl1w = (const float*)d_in[23];
  const float* dl1b = (const float*)d_in[24];
  const float* dl2w = (const float*)d_in[25];
  const float* dl2b = (const float*)d_in[26];
  float* outv = (float*)d_out;
  char* ws = (char*)d_ws;

  size_t off = 0;
  u16*  h     = (u16*)(ws + off);  off += (size_t)NTOK * HID_ * 2;       // 42MB (bf16 residual)
  float* cosr = (float*)(ws + off); off += (size_t)NTOK * 80 * 4;
  float* sinr = (float*)(ws + off); off += (size_t)NTOK * 80 * 4;
  u16*  xb    = (u16*)(ws + off);  off += (size_t)NTOK * HID_ * 2;       // 42MB
  u16*  bufA  = (u16*)(ws + off);  off += (size_t)NTOK * 3840 * 2;       // 126MB
  u16*  WtQ   = (u16*)(ws + off);  off += (size_t)3840 * HID_ * 2;       // 9.8MB
  u16*  WtP   = (u16*)(ws + off);  off += (size_t)HID_ * HID_ * 2;       // 3.3MB
  u16*  WtG   = (u16*)(ws + off);  off += (size_t)2 * INTER_ * HID_ * 2; // 17.7MB
  u16*  WtD   = (u16*)(ws + off);  off += (size_t)HID_ * INTER_ * 2;     // 8.8MB
  u16*  bufC  = (u16*)(ws + off);  off += (size_t)NTOK * HID_ * 2;       // 42MB
  u16*  Wt    = (u16*)(ws + off);  off += (size_t)BIGD * BIGD * 2;       // 52.5MB

  dim3 B256(256), B512(512);
  // supertile depth: SB=4 for K<=1536 (A panels small), else 2 (fits 4MB L2)
  #define SBOF(K_) (((K_) <= 1536) ? 4 : 2)
  #define TW(src, K_, N_) twt_k<<<dim3((N_) / 32, (K_) / 32), B256, 0, stream>>>((src), Wt, (K_), (N_))
  #define G8(MODE, TM_, Abuf, Bt_, bias_, bias2_, out_, rmap_, M_, N_, K_)                \
    gemm8_k<MODE, TM_><<<dim3(((M_) / (TM_)) * (((N_) + 255) / 256)), B512, 0, stream>>>( \
        (Abuf), (Bt_), (bias_), (bias2_), (out_), (rmap_), (((N_) + 255) / 256),          \
        SBOF(K_), (N_), (K_))

  // gather pixel rows + cos/sin
  gather_pv_k<<<(NTOK * 384 + 255) / 256, B256, 0, stream>>>(pv, wi, bufA);
  gather_cs_k<<<(NTOK * 20 + 255) / 256, B256, 0, stream>>>(cosi, sini, wi, cosr, sinr);

  // h = pv_g @ W_patch   (bf16 residual stream)
  TW(Wp, 1536, HID_);
  G8(0, 128, bufA, Wt, nullptr, nullptr, h, nullptr, NTOK, HID_, 1536);

  for (int i = 0; i < 6; i++) {
    // batched transpose of all 5 layer weights (one launch)
    twtb_k<<<dim3(4800, 5), B256, 0, stream>>>(
        qkvw + (size_t)i * HID_ * 3840, pw + (size_t)i * HID_ * HID_,
        gw + (size_t)i * HID_ * INTER_, uw + (size_t)i * HID_ * INTER_,
        dw + (size_t)i * INTER_ * HID_, WtQ, WtP, WtG, WtD);
    // attn
    rmsnorm_k<<<NTOK, B256, 0, stream>>>(h, n1w + (size_t)i * HID_, xb, HID_);
    G8(0, 256, xb, WtQ, qkvb + (size_t)i * 3840, nullptr, bufA, nullptr, NTOK, 3840, HID_);
    attn_k<<<dim3(256, 16), B256, 0, stream>>>(bufA, bufC, cosr, sinr);
    G8(7, 128, bufC, WtP, pb + (size_t)i * HID_, nullptr, h, nullptr, NTOK, HID_, HID_);
    // mlp: fused gate+up via interleaved weight columns (even=gate, odd=up)
    rmsnorm_k<<<NTOK, B256, 0, stream>>>(h, n2w + (size_t)i * HID_, xb, HID_);
    G8(6, 256, xb, WtG, gb + (size_t)i * INTER_, ub + (size_t)i * INTER_, bufA, nullptr,
       NTOK, 2 * INTER_, HID_);
    G8(7, 128, bufA, WtD, db + (size_t)i * HID_, nullptr, h, nullptr, NTOK, HID_, INTER_);
    // deepstack mergers after layers 2 and 4
    if (i == 2 || i == 4) {
      int j = (i == 2) ? 0 : 1;
      rmsnorm_k<<<NGRP, B256, 0, stream>>>(h, dnw + (size_t)j * BIGD, bufC, BIGD);
      TW(dl1w + (size_t)j * BIGD * BIGD, BIGD, BIGD);
      G8(3, 128, bufC, Wt, dl1b + (size_t)j * BIGD, nullptr, bufA, nullptr, NGRP, BIGD, BIGD);
      TW(dl2w + (size_t)j * BIGD * ODIM, BIGD, ODIM);
      G8(4, 128, bufA, Wt, dl2b + (size_t)j * ODIM, nullptr,
         outv + (size_t)(1 + j) * NGRP * ODIM, wi, NGRP, ODIM, BIGD);
    }
  }

  // final merger -> plane 0
  rmsnorm_k<<<NTOK, B256, 0, stream>>>(h, mnw, bufC, HID_);
  TW(ml1w, BIGD, BIGD);
  G8(3, 128, bufC, Wt, ml1b, nullptr, bufA, nullptr, NGRP, BIGD, BIGD);
  TW(ml2w, BIGD, ODIM);
  G8(4, 128, bufA, Wt, ml2b, nullptr, outv, wi, NGRP, ODIM, BIGD);
  #undef TW
  #undef G8
  #undef SBOF
}